// Round 1
// baseline (1243.248 us; speedup 1.0000x reference)
//
#include <hip/hip_runtime.h>
#include <cstdint>
#include <cstddef>

#define N_HEADS 16
#define HEAD_DIM 64

// ---------------------------------------------------------------------------
// GEMM: C[M,N] = A[M,K] * W[N,K]^T   (fp32, row-major, all dims % 64 == 0,
// K % 32 == 0). Block 256 threads = 16x16, each thread computes 4x4.
// ---------------------------------------------------------------------------
__global__ __launch_bounds__(256) void gemm_awt(const float* __restrict__ A,
                                                const float* __restrict__ W,
                                                float* __restrict__ C,
                                                int M, int N, int K) {
    const int BK = 32;
    __shared__ float As[32][68];  // [k][m], padded
    __shared__ float Ws[32][68];  // [k][n], padded

    const int tid = threadIdx.x;
    const int tx = tid & 15;         // 0..15 -> n
    const int ty = tid >> 4;         // 0..15 -> m
    const int n0 = blockIdx.x * 64;
    const int m0 = blockIdx.y * 64;

    float acc[4][4] = {};

    for (int k0 = 0; k0 < K; k0 += BK) {
        // Stage A and W tiles: 64 rows x 32 k each = 512 float4 per matrix.
        #pragma unroll
        for (int idx4 = tid; idx4 < 512; idx4 += 256) {
            const int m  = idx4 >> 3;            // 0..63
            const int k4 = (idx4 & 7) << 2;      // 0,4,...,28
            const float4 av = *reinterpret_cast<const float4*>(
                &A[(size_t)(m0 + m) * K + k0 + k4]);
            const float4 wv = *reinterpret_cast<const float4*>(
                &W[(size_t)(n0 + m) * K + k0 + k4]);
            As[k4 + 0][m] = av.x; As[k4 + 1][m] = av.y;
            As[k4 + 2][m] = av.z; As[k4 + 3][m] = av.w;
            Ws[k4 + 0][m] = wv.x; Ws[k4 + 1][m] = wv.y;
            Ws[k4 + 2][m] = wv.z; Ws[k4 + 3][m] = wv.w;
        }
        __syncthreads();

        #pragma unroll
        for (int k = 0; k < BK; ++k) {
            const float4 a4 = *reinterpret_cast<const float4*>(&As[k][ty * 4]);
            const float4 b4 = *reinterpret_cast<const float4*>(&Ws[k][tx * 4]);
            const float a[4] = {a4.x, a4.y, a4.z, a4.w};
            const float b[4] = {b4.x, b4.y, b4.z, b4.w};
            #pragma unroll
            for (int i = 0; i < 4; ++i)
                #pragma unroll
                for (int j = 0; j < 4; ++j)
                    acc[i][j] += a[i] * b[j];
        }
        __syncthreads();
    }

    #pragma unroll
    for (int i = 0; i < 4; ++i) {
        float4 cv = make_float4(acc[i][0], acc[i][1], acc[i][2], acc[i][3]);
        *reinterpret_cast<float4*>(
            &C[(size_t)(m0 + ty * 4 + i) * N + n0 + tx * 4]) = cv;
    }
}

// ---------------------------------------------------------------------------
// Flash-style attention, fp32. Q/K/V/O layout: [B][T or S][H][HEAD_DIM].
// Block: 256 threads (16x16), 64 query rows per block, S-tiles of 64.
// grid.x = B*H, grid.y = T/64.
// ---------------------------------------------------------------------------
__global__ __launch_bounds__(256) void attn_fwd(const float* __restrict__ Q,
                                                const float* __restrict__ K,
                                                const float* __restrict__ V,
                                                float* __restrict__ O,
                                                int T, int S) {
    __shared__ float Qs[HEAD_DIM][68];   // [d][r]
    __shared__ float Ks[HEAD_DIM][68];   // [d][s]
    __shared__ float Vs[64][68];         // [s][d]
    __shared__ float Ps[64][68];         // [s][r]
    __shared__ float red[64][17];
    __shared__ float mrow[64], lrow[64], srow[64];

    const int bh = blockIdx.x;
    const int b  = bh / N_HEADS;
    const int h  = bh % N_HEADS;
    const int t0 = blockIdx.y * 64;

    const int tid = threadIdx.x;
    const int tx = tid & 15;
    const int ty = tid >> 4;
    const float scale = 0.125f;  // HEAD_DIM^-0.5

    // Load Q tile transposed: Qs[d][r].
    #pragma unroll
    for (int idx4 = tid; idx4 < 64 * HEAD_DIM / 4; idx4 += 256) {
        const int r  = idx4 >> 4;            // 0..63
        const int d4 = (idx4 & 15) << 2;     // 0..60
        const float4 qv = *reinterpret_cast<const float4*>(
            &Q[(((size_t)b * T + t0 + r) * N_HEADS + h) * HEAD_DIM + d4]);
        Qs[d4 + 0][r] = qv.x; Qs[d4 + 1][r] = qv.y;
        Qs[d4 + 2][r] = qv.z; Qs[d4 + 3][r] = qv.w;
    }
    if (tid < 64) { mrow[tid] = -1e30f; lrow[tid] = 0.0f; }

    float o[4][4] = {};
    __syncthreads();

    for (int s0 = 0; s0 < S; s0 += 64) {
        // Stage K (transposed) and V tiles.
        #pragma unroll
        for (int idx4 = tid; idx4 < 64 * HEAD_DIM / 4; idx4 += 256) {
            const int s  = idx4 >> 4;
            const int d4 = (idx4 & 15) << 2;
            const size_t base =
                (((size_t)b * S + s0 + s) * N_HEADS + h) * HEAD_DIM + d4;
            const float4 kv = *reinterpret_cast<const float4*>(&K[base]);
            const float4 vv = *reinterpret_cast<const float4*>(&V[base]);
            Ks[d4 + 0][s] = kv.x; Ks[d4 + 1][s] = kv.y;
            Ks[d4 + 2][s] = kv.z; Ks[d4 + 3][s] = kv.w;
            Vs[s][d4 + 0] = vv.x; Vs[s][d4 + 1] = vv.y;
            Vs[s][d4 + 2] = vv.z; Vs[s][d4 + 3] = vv.w;
        }
        __syncthreads();

        // Logits: rows r = ty*4+i, cols s = tx*4+j.
        float sreg[4][4] = {};
        #pragma unroll
        for (int k = 0; k < HEAD_DIM; ++k) {
            const float4 a4 = *reinterpret_cast<const float4*>(&Qs[k][ty * 4]);
            const float4 b4 = *reinterpret_cast<const float4*>(&Ks[k][tx * 4]);
            const float a[4] = {a4.x, a4.y, a4.z, a4.w};
            const float bb[4] = {b4.x, b4.y, b4.z, b4.w};
            #pragma unroll
            for (int i = 0; i < 4; ++i)
                #pragma unroll
                for (int j = 0; j < 4; ++j)
                    sreg[i][j] += a[i] * bb[j];
        }
        #pragma unroll
        for (int i = 0; i < 4; ++i)
            #pragma unroll
            for (int j = 0; j < 4; ++j)
                sreg[i][j] *= scale;

        // Row-max partial reduce.
        #pragma unroll
        for (int i = 0; i < 4; ++i) {
            float mx = fmaxf(fmaxf(sreg[i][0], sreg[i][1]),
                             fmaxf(sreg[i][2], sreg[i][3]));
            red[ty * 4 + i][tx] = mx;
        }
        __syncthreads();

        if (tid < 64) {
            float mx = mrow[tid];
            #pragma unroll
            for (int x = 0; x < 16; ++x) mx = fmaxf(mx, red[tid][x]);
            const float f = __expf(mrow[tid] - mx);
            srow[tid] = f;
            mrow[tid] = mx;
            lrow[tid] *= f;
        }
        __syncthreads();

        // P = exp(S - m); store transposed Ps[s][r]; partial row sums;
        // rescale O accumulator.
        #pragma unroll
        for (int i = 0; i < 4; ++i) {
            const int r = ty * 4 + i;
            const float m = mrow[r];
            float sum = 0.0f;
            #pragma unroll
            for (int j = 0; j < 4; ++j) {
                const float p = __expf(sreg[i][j] - m);
                Ps[tx * 4 + j][r] = p;
                sum += p;
            }
            red[r][tx] = sum;
            const float f = srow[r];
            #pragma unroll
            for (int j = 0; j < 4; ++j) o[i][j] *= f;
        }
        __syncthreads();

        if (tid < 64) {
            float s = 0.0f;
            #pragma unroll
            for (int x = 0; x < 16; ++x) s += red[tid][x];
            lrow[tid] += s;
        }

        // O += P * V : rows r = ty*4+i, dims d = tx*4+j.
        #pragma unroll
        for (int s = 0; s < 64; ++s) {
            const float4 p4 = *reinterpret_cast<const float4*>(&Ps[s][ty * 4]);
            const float4 v4 = *reinterpret_cast<const float4*>(&Vs[s][tx * 4]);
            const float p[4] = {p4.x, p4.y, p4.z, p4.w};
            const float vv[4] = {v4.x, v4.y, v4.z, v4.w};
            #pragma unroll
            for (int i = 0; i < 4; ++i)
                #pragma unroll
                for (int j = 0; j < 4; ++j)
                    o[i][j] += p[i] * vv[j];
        }
        __syncthreads();
    }

    #pragma unroll
    for (int i = 0; i < 4; ++i) {
        const int r = ty * 4 + i;
        const float inv = 1.0f / lrow[r];
        float4 ov = make_float4(o[i][0] * inv, o[i][1] * inv,
                                o[i][2] * inv, o[i][3] * inv);
        *reinterpret_cast<float4*>(
            &O[(((size_t)b * T + t0 + r) * N_HEADS + h) * HEAD_DIM + tx * 4]) = ov;
    }
}

// ---------------------------------------------------------------------------
extern "C" void kernel_launch(void* const* d_in, const int* in_sizes, int n_in,
                              void* d_out, int out_size, void* d_ws, size_t ws_size,
                              hipStream_t stream) {
    const int B = 4, T = 1024, S = 2048, D = 1024;

    const float* query = (const float*)d_in[0];  // [B*T, D]
    const float* keyv  = (const float*)d_in[1];  // [B*S, D]
    const float* wq    = (const float*)d_in[2];  // [D, D]
    const float* wk    = (const float*)d_in[3];
    const float* wv    = (const float*)d_in[4];
    const float* wo    = (const float*)d_in[5];
    float* out = (float*)d_out;                  // [B*T, D]

    const size_t nQ = (size_t)B * T * D;  // 4M
    const size_t nK = (size_t)B * S * D;  // 8M
    float* Qp = (float*)d_ws;             // 16 MB
    float* Kp = Qp + nQ;                  // 32 MB
    float* Vp = Kp + nK;                  // 32 MB
    float* AO = Vp + nK;                  // 16 MB   (total 96 MB)

    dim3 blk(256);
    // Projections.
    gemm_awt<<<dim3(D / 64, (B * T) / 64), blk, 0, stream>>>(query, wq, Qp, B * T, D, D);
    gemm_awt<<<dim3(D / 64, (B * S) / 64), blk, 0, stream>>>(keyv,  wk, Kp, B * S, D, D);
    gemm_awt<<<dim3(D / 64, (B * S) / 64), blk, 0, stream>>>(keyv,  wv, Vp, B * S, D, D);
    // Attention.
    attn_fwd<<<dim3(B * N_HEADS, T / 64), blk, 0, stream>>>(Qp, Kp, Vp, AO, T, S);
    // Output projection.
    gemm_awt<<<dim3(D / 64, (B * T) / 64), blk, 0, stream>>>(AO, wo, out, B * T, D, D);
}

// Round 2
// 741.154 us; speedup vs baseline: 1.6774x; 1.6774x over previous
//
#include <hip/hip_runtime.h>
#include <cstdint>
#include <cstddef>

#define N_HEADS 16
#define HEAD_DIM 64

typedef __attribute__((ext_vector_type(4))) float f32x4;
typedef __attribute__((ext_vector_type(8))) short bf16x8;

// ---------------------------------------------------------------------------
// fp32 -> (hi, lo) bf16 split helpers (RTN-even, no NaN inputs).
// ---------------------------------------------------------------------------
static __device__ inline ushort f2bf(float x) {
    uint32_t u = __float_as_uint(x);
    uint32_t r = (u + 0x7fffu + ((u >> 16) & 1u)) >> 16;
    return (ushort)r;
}
static __device__ inline float bf2f(ushort h) {
    return __uint_as_float(((uint32_t)h) << 16);
}

__global__ __launch_bounds__(256) void split_bf16_kernel(
    const float* __restrict__ x, ushort* __restrict__ hi,
    ushort* __restrict__ lo, int n4) {
    const int stride = gridDim.x * blockDim.x;
    for (int i = blockIdx.x * blockDim.x + threadIdx.x; i < n4; i += stride) {
        const float4 v = reinterpret_cast<const float4*>(x)[i];
        ushort4 h, l;
        h.x = f2bf(v.x); l.x = f2bf(v.x - bf2f(h.x));
        h.y = f2bf(v.y); l.y = f2bf(v.y - bf2f(h.y));
        h.z = f2bf(v.z); l.z = f2bf(v.z - bf2f(h.z));
        h.w = f2bf(v.w); l.w = f2bf(v.w - bf2f(h.w));
        reinterpret_cast<ushort4*>(hi)[i] = h;
        reinterpret_cast<ushort4*>(lo)[i] = l;
    }
}

// ---------------------------------------------------------------------------
// Split-bf16 MFMA GEMM: C[M,N] = A[M,K] * W[N,K]^T, fp32-accurate via
// acc = Ahi*Whi + Ahi*Wlo + Alo*Whi. m97 structure: 128x128 tile, BK=32,
// 4 waves (2x2), 4x4 fragments of 16x16x32 each, global_load_lds staging.
// LDS layout per array: row-major [128][32] bf16 (64B rows), k8-slot
// XOR-swizzled with (row>>1)&3 (2-way conflicts max; pre-swizzled global src).
// ---------------------------------------------------------------------------
#define BM 128
#define BN 128
#define BK 32

#define GLD_LDS16(gp, lp)                                                  \
    __builtin_amdgcn_global_load_lds(                                      \
        (const __attribute__((address_space(1))) void*)(gp),               \
        (__attribute__((address_space(3))) void*)(lp), 16, 0, 0)

__global__ __launch_bounds__(256, 2) void gemm_split(
    const ushort* __restrict__ Ahi, const ushort* __restrict__ Alo,
    const ushort* __restrict__ Whi, const ushort* __restrict__ Wlo,
    float* __restrict__ C, int M, int N, int K) {
    __shared__ ushort sA[2][BM * BK];  // [hi/lo][row*32 + physslot*8 + e]
    __shared__ ushort sB[2][BN * BK];

    const int tid = threadIdx.x;
    const int lane = tid & 63;
    const int w = tid >> 6;
    const int m0 = blockIdx.y * BM;
    const int n0 = blockIdx.x * BN;
    const int wm = (w >> 1) * 64;
    const int wn = (w & 1) * 64;

    // Staging geometry: each wave writes 2 linear 1KB LDS chunks per array.
    // Chunk c covers rows [(w*2+c)*16, +16); lane -> row=(base+(lane>>2)),
    // physslot=lane&3; the global k8 placed there is physslot ^ ((row>>1)&3).
    int srow[2], skq[2];
#pragma unroll
    for (int c = 0; c < 2; ++c) {
        const int row = (w * 2 + c) * 16 + (lane >> 2);
        srow[c] = row;
        skq[c] = (((lane & 3) ^ ((row >> 1) & 3)) << 3);
    }

    f32x4 acc[4][4];
#pragma unroll
    for (int i = 0; i < 4; ++i)
#pragma unroll
        for (int j = 0; j < 4; ++j) acc[i][j] = (f32x4)0.0f;

    const int lr = lane & 15;  // fragment row (A) / col (B)
    const int kq = lane >> 4;  // logical k8 block 0..3

    for (int k0 = 0; k0 < K; k0 += BK) {
#pragma unroll
        for (int c = 0; c < 2; ++c) {
            const size_t ga = (size_t)(m0 + srow[c]) * K + k0 + skq[c];
            const size_t gb = (size_t)(n0 + srow[c]) * K + k0 + skq[c];
            const int loff = (w * 2 + c) * 512;  // ushort units (1KB chunk)
            GLD_LDS16(Ahi + ga, &sA[0][loff]);
            GLD_LDS16(Alo + ga, &sA[1][loff]);
            GLD_LDS16(Whi + gb, &sB[0][loff]);
            GLD_LDS16(Wlo + gb, &sB[1][loff]);
        }
        __syncthreads();

        bf16x8 afh[4], afl[4], bfh[4], bfl[4];
#pragma unroll
        for (int f = 0; f < 4; ++f) {
            const int arow = wm + f * 16 + lr;
            const int aoff = arow * 32 + ((kq ^ ((arow >> 1) & 3)) << 3);
            afh[f] = *reinterpret_cast<const bf16x8*>(&sA[0][aoff]);
            afl[f] = *reinterpret_cast<const bf16x8*>(&sA[1][aoff]);
            const int brow = wn + f * 16 + lr;
            const int boff = brow * 32 + ((kq ^ ((brow >> 1) & 3)) << 3);
            bfh[f] = *reinterpret_cast<const bf16x8*>(&sB[0][boff]);
            bfl[f] = *reinterpret_cast<const bf16x8*>(&sB[1][boff]);
        }
#pragma unroll
        for (int i = 0; i < 4; ++i)
#pragma unroll
            for (int j = 0; j < 4; ++j) {
                acc[i][j] = __builtin_amdgcn_mfma_f32_16x16x32_bf16(
                    afh[i], bfh[j], acc[i][j], 0, 0, 0);
                acc[i][j] = __builtin_amdgcn_mfma_f32_16x16x32_bf16(
                    afh[i], bfl[j], acc[i][j], 0, 0, 0);
                acc[i][j] = __builtin_amdgcn_mfma_f32_16x16x32_bf16(
                    afl[i], bfh[j], acc[i][j], 0, 0, 0);
            }
        __syncthreads();
    }

    // C/D layout (m89): col = lane&15, row = (lane>>4)*4 + reg.
    const int cr = (lane >> 4) << 2;
    const int cc = lane & 15;
#pragma unroll
    for (int i = 0; i < 4; ++i)
#pragma unroll
        for (int j = 0; j < 4; ++j) {
            float* cp = &C[(size_t)(m0 + wm + i * 16 + cr) * N + n0 + wn +
                           j * 16 + cc];
#pragma unroll
            for (int r = 0; r < 4; ++r) cp[(size_t)r * N] = acc[i][j][r];
        }
}

// ---------------------------------------------------------------------------
// Flash-style attention, fp32 (unchanged from round 1 — MFMA next round).
// ---------------------------------------------------------------------------
__global__ __launch_bounds__(256) void attn_fwd(const float* __restrict__ Q,
                                                const float* __restrict__ K,
                                                const float* __restrict__ V,
                                                float* __restrict__ O,
                                                int T, int S) {
    __shared__ float Qs[HEAD_DIM][68];   // [d][r]
    __shared__ float Ks[HEAD_DIM][68];   // [d][s]
    __shared__ float Vs[64][68];         // [s][d]
    __shared__ float Ps[64][68];         // [s][r]
    __shared__ float red[64][17];
    __shared__ float mrow[64], lrow[64], srow[64];

    const int bh = blockIdx.x;
    const int b  = bh / N_HEADS;
    const int h  = bh % N_HEADS;
    const int t0 = blockIdx.y * 64;

    const int tid = threadIdx.x;
    const int tx = tid & 15;
    const int ty = tid >> 4;
    const float scale = 0.125f;  // HEAD_DIM^-0.5

#pragma unroll
    for (int idx4 = tid; idx4 < 64 * HEAD_DIM / 4; idx4 += 256) {
        const int r  = idx4 >> 4;
        const int d4 = (idx4 & 15) << 2;
        const float4 qv = *reinterpret_cast<const float4*>(
            &Q[(((size_t)b * T + t0 + r) * N_HEADS + h) * HEAD_DIM + d4]);
        Qs[d4 + 0][r] = qv.x; Qs[d4 + 1][r] = qv.y;
        Qs[d4 + 2][r] = qv.z; Qs[d4 + 3][r] = qv.w;
    }
    if (tid < 64) { mrow[tid] = -1e30f; lrow[tid] = 0.0f; }

    float o[4][4] = {};
    __syncthreads();

    for (int s0 = 0; s0 < S; s0 += 64) {
#pragma unroll
        for (int idx4 = tid; idx4 < 64 * HEAD_DIM / 4; idx4 += 256) {
            const int s  = idx4 >> 4;
            const int d4 = (idx4 & 15) << 2;
            const size_t base =
                (((size_t)b * S + s0 + s) * N_HEADS + h) * HEAD_DIM + d4;
            const float4 kv = *reinterpret_cast<const float4*>(&K[base]);
            const float4 vv = *reinterpret_cast<const float4*>(&V[base]);
            Ks[d4 + 0][s] = kv.x; Ks[d4 + 1][s] = kv.y;
            Ks[d4 + 2][s] = kv.z; Ks[d4 + 3][s] = kv.w;
            Vs[s][d4 + 0] = vv.x; Vs[s][d4 + 1] = vv.y;
            Vs[s][d4 + 2] = vv.z; Vs[s][d4 + 3] = vv.w;
        }
        __syncthreads();

        float sreg[4][4] = {};
#pragma unroll
        for (int k = 0; k < HEAD_DIM; ++k) {
            const float4 a4 = *reinterpret_cast<const float4*>(&Qs[k][ty * 4]);
            const float4 b4 = *reinterpret_cast<const float4*>(&Ks[k][tx * 4]);
            const float a[4] = {a4.x, a4.y, a4.z, a4.w};
            const float bb[4] = {b4.x, b4.y, b4.z, b4.w};
#pragma unroll
            for (int i = 0; i < 4; ++i)
#pragma unroll
                for (int j = 0; j < 4; ++j)
                    sreg[i][j] += a[i] * bb[j];
        }
#pragma unroll
        for (int i = 0; i < 4; ++i)
#pragma unroll
            for (int j = 0; j < 4; ++j)
                sreg[i][j] *= scale;

#pragma unroll
        for (int i = 0; i < 4; ++i) {
            float mx = fmaxf(fmaxf(sreg[i][0], sreg[i][1]),
                             fmaxf(sreg[i][2], sreg[i][3]));
            red[ty * 4 + i][tx] = mx;
        }
        __syncthreads();

        if (tid < 64) {
            float mx = mrow[tid];
#pragma unroll
            for (int x = 0; x < 16; ++x) mx = fmaxf(mx, red[tid][x]);
            const float f = __expf(mrow[tid] - mx);
            srow[tid] = f;
            mrow[tid] = mx;
            lrow[tid] *= f;
        }
        __syncthreads();

#pragma unroll
        for (int i = 0; i < 4; ++i) {
            const int r = ty * 4 + i;
            const float m = mrow[r];
            float sum = 0.0f;
#pragma unroll
            for (int j = 0; j < 4; ++j) {
                const float p = __expf(sreg[i][j] - m);
                Ps[tx * 4 + j][r] = p;
                sum += p;
            }
            red[r][tx] = sum;
            const float f = srow[r];
#pragma unroll
            for (int j = 0; j < 4; ++j) o[i][j] *= f;
        }
        __syncthreads();

        if (tid < 64) {
            float s = 0.0f;
#pragma unroll
            for (int x = 0; x < 16; ++x) s += red[tid][x];
            lrow[tid] += s;
        }

#pragma unroll
        for (int s = 0; s < 64; ++s) {
            const float4 p4 = *reinterpret_cast<const float4*>(&Ps[s][ty * 4]);
            const float4 v4 = *reinterpret_cast<const float4*>(&Vs[s][tx * 4]);
            const float p[4] = {p4.x, p4.y, p4.z, p4.w};
            const float vv[4] = {v4.x, v4.y, v4.z, v4.w};
#pragma unroll
            for (int i = 0; i < 4; ++i)
#pragma unroll
                for (int j = 0; j < 4; ++j)
                    o[i][j] += p[i] * vv[j];
        }
        __syncthreads();
    }

#pragma unroll
    for (int i = 0; i < 4; ++i) {
        const int r = ty * 4 + i;
        const float inv = 1.0f / lrow[r];
        float4 ov = make_float4(o[i][0] * inv, o[i][1] * inv,
                                o[i][2] * inv, o[i][3] * inv);
        *reinterpret_cast<float4*>(
            &O[(((size_t)b * T + t0 + r) * N_HEADS + h) * HEAD_DIM + tx * 4]) = ov;
    }
}

// ---------------------------------------------------------------------------
extern "C" void kernel_launch(void* const* d_in, const int* in_sizes, int n_in,
                              void* d_out, int out_size, void* d_ws, size_t ws_size,
                              hipStream_t stream) {
    const int B = 4, T = 1024, S = 2048, D = 1024;

    const float* query = (const float*)d_in[0];  // [B*T, D]
    const float* keyv  = (const float*)d_in[1];  // [B*S, D]
    const float* wq    = (const float*)d_in[2];  // [D, D]
    const float* wk    = (const float*)d_in[3];
    const float* wv    = (const float*)d_in[4];
    const float* wo    = (const float*)d_in[5];
    float* out = (float*)d_out;                  // [B*T, D]

    const size_t nQ = (size_t)B * T * D;  // 4M
    const size_t nK = (size_t)B * S * D;  // 8M
    const size_t nW = (size_t)D * D;      // 1M

    uint8_t* p = (uint8_t*)d_ws;
    float* Qp = (float*)p;        p += nQ * 4;   // 16 MB
    float* Kp = (float*)p;        p += nK * 4;   // 32 MB
    float* Vp = (float*)p;        p += nK * 4;   // 32 MB
    float* AO = (float*)p;        p += nQ * 4;   // 16 MB
    ushort* qhi = (ushort*)p;     p += nQ * 2;
    ushort* qlo = (ushort*)p;     p += nQ * 2;   // +16 MB
    ushort* kvhi = (ushort*)p;    p += nK * 2;
    ushort* kvlo = (ushort*)p;    p += nK * 2;   // +32 MB
    ushort* aohi = (ushort*)p;    p += nQ * 2;
    ushort* aolo = (ushort*)p;    p += nQ * 2;   // +16 MB
    ushort* whi[4];
    ushort* wlo[4];
    for (int i = 0; i < 4; ++i) {
        whi[i] = (ushort*)p; p += nW * 2;
        wlo[i] = (ushort*)p; p += nW * 2;        // +16 MB total
    }
    // total ws use: 176 MB

    const dim3 blk(256);
    const float* wsrc[4] = {wq, wk, wv, wo};

    // fp32 -> (hi,lo) bf16 splits.
    split_bf16_kernel<<<2048, blk, 0, stream>>>(query, qhi, qlo, (int)(nQ / 4));
    split_bf16_kernel<<<2048, blk, 0, stream>>>(keyv, kvhi, kvlo, (int)(nK / 4));
    for (int i = 0; i < 4; ++i)
        split_bf16_kernel<<<1024, blk, 0, stream>>>(wsrc[i], whi[i], wlo[i],
                                                    (int)(nW / 4));

    // Projections via split-bf16 MFMA.
    gemm_split<<<dim3(D / BN, (B * T) / BM), blk, 0, stream>>>(
        qhi, qlo, whi[0], wlo[0], Qp, B * T, D, D);
    gemm_split<<<dim3(D / BN, (B * S) / BM), blk, 0, stream>>>(
        kvhi, kvlo, whi[1], wlo[1], Kp, B * S, D, D);
    gemm_split<<<dim3(D / BN, (B * S) / BM), blk, 0, stream>>>(
        kvhi, kvlo, whi[2], wlo[2], Vp, B * S, D, D);

    // Attention (fp32, unchanged).
    attn_fwd<<<dim3(B * N_HEADS, T / 64), blk, 0, stream>>>(Qp, Kp, Vp, AO, T, S);

    // Output projection.
    split_bf16_kernel<<<2048, blk, 0, stream>>>(AO, aohi, aolo, (int)(nQ / 4));
    gemm_split<<<dim3(D / BN, (B * T) / BM), blk, 0, stream>>>(
        aohi, aolo, whi[3], wlo[3], out, B * T, D, D);
}

// Round 3
// 439.576 us; speedup vs baseline: 2.8283x; 1.6861x over previous
//
#include <hip/hip_runtime.h>
#include <cstdint>
#include <cstddef>

#define N_HEADS 16
#define HEAD_DIM 64

typedef __attribute__((ext_vector_type(4))) float f32x4;
typedef __attribute__((ext_vector_type(8))) short bf16x8;

// ---------------------------------------------------------------------------
// fp32 -> (hi, lo) bf16 split helpers (RTN-even, no NaN inputs).
// ---------------------------------------------------------------------------
static __device__ inline ushort f2bf(float x) {
    uint32_t u = __float_as_uint(x);
    uint32_t r = (u + 0x7fffu + ((u >> 16) & 1u)) >> 16;
    return (ushort)r;
}
static __device__ inline float bf2f(ushort h) {
    return __uint_as_float(((uint32_t)h) << 16);
}

__global__ __launch_bounds__(256) void split_bf16_kernel(
    const float* __restrict__ x, ushort* __restrict__ hi,
    ushort* __restrict__ lo, int n4) {
    const int stride = gridDim.x * blockDim.x;
    for (int i = blockIdx.x * blockDim.x + threadIdx.x; i < n4; i += stride) {
        const float4 v = reinterpret_cast<const float4*>(x)[i];
        ushort4 h, l;
        h.x = f2bf(v.x); l.x = f2bf(v.x - bf2f(h.x));
        h.y = f2bf(v.y); l.y = f2bf(v.y - bf2f(h.y));
        h.z = f2bf(v.z); l.z = f2bf(v.z - bf2f(h.z));
        h.w = f2bf(v.w); l.w = f2bf(v.w - bf2f(h.w));
        reinterpret_cast<ushort4*>(hi)[i] = h;
        reinterpret_cast<ushort4*>(lo)[i] = l;
    }
}

// ---------------------------------------------------------------------------
// Re-layout + split for attention Q/K: in [B][X][H][64] f32 ->
// out [B*H][X][64] bf16 hi/lo, element dd stored at dd ^ ((x&7)<<3)
// (bank-conflict-free ds_read_b128 after linear global_load_lds staging).
// ---------------------------------------------------------------------------
__global__ __launch_bounds__(256) void reorder_split(
    const float* __restrict__ in, ushort* __restrict__ hi,
    ushort* __restrict__ lo, int X, float scale) {
    const int tid = threadIdx.x;
    const int x = blockIdx.x * 16 + (tid >> 4);
    const int bh = blockIdx.y;
    const int b = bh >> 4, h = bh & 15;
    const int dd4 = (tid & 15) << 2;
    const float4 v = *reinterpret_cast<const float4*>(
        &in[(((size_t)b * X + x) * N_HEADS + h) * 64 + dd4]);
    ushort4 hv, lv;
    float a;
    a = v.x * scale; hv.x = f2bf(a); lv.x = f2bf(a - bf2f(hv.x));
    a = v.y * scale; hv.y = f2bf(a); lv.y = f2bf(a - bf2f(hv.y));
    a = v.z * scale; hv.z = f2bf(a); lv.z = f2bf(a - bf2f(hv.z));
    a = v.w * scale; hv.w = f2bf(a); lv.w = f2bf(a - bf2f(hv.w));
    const size_t pos = ((size_t)bh * X + x) * 64 + (dd4 ^ ((x & 7) << 3));
    *reinterpret_cast<ushort4*>(&hi[pos]) = hv;
    *reinterpret_cast<ushort4*>(&lo[pos]) = lv;
}

// ---------------------------------------------------------------------------
// V re-layout: [B][S][H][64] f32 -> transposed [B*H][64 d][S] bf16 hi/lo,
// element s stored at (s&63) ^ ((dd&7)<<3) within its 64-block (LDS-tiled
// transpose so both global sides stay coalesced).
// ---------------------------------------------------------------------------
__global__ __launch_bounds__(256) void v_split_t(const float* __restrict__ in,
                                                 ushort* __restrict__ hi,
                                                 ushort* __restrict__ lo) {
    constexpr int S = 2048;
    __shared__ float tile[64][68];
    const int tid = threadIdx.x;
    const int s0 = blockIdx.x * 64;
    const int bh = blockIdx.y;
    const int b = bh >> 4, h = bh & 15;
#pragma unroll
    for (int it = 0; it < 4; ++it) {
        const int idx = it * 256 + tid;
        const int row = idx >> 4;
        const int dd4 = (idx & 15) << 2;
        const float4 v = *reinterpret_cast<const float4*>(
            &in[(((size_t)b * S + s0 + row) * N_HEADS + h) * 64 + dd4]);
        tile[row][dd4 + 0] = v.x; tile[row][dd4 + 1] = v.y;
        tile[row][dd4 + 2] = v.z; tile[row][dd4 + 3] = v.w;
    }
    __syncthreads();
#pragma unroll
    for (int it = 0; it < 4; ++it) {
        const int idx = it * 256 + tid;
        const int dd = idx >> 4;
        const int sl4 = (idx & 15) << 2;
        ushort4 hv, lv;
        float a;
        a = tile[sl4 + 0][dd]; hv.x = f2bf(a); lv.x = f2bf(a - bf2f(hv.x));
        a = tile[sl4 + 1][dd]; hv.y = f2bf(a); lv.y = f2bf(a - bf2f(hv.y));
        a = tile[sl4 + 2][dd]; hv.z = f2bf(a); lv.z = f2bf(a - bf2f(hv.z));
        a = tile[sl4 + 3][dd]; hv.w = f2bf(a); lv.w = f2bf(a - bf2f(hv.w));
        const size_t pos =
            ((size_t)bh * 64 + dd) * S + s0 + (sl4 ^ ((dd & 7) << 3));
        *reinterpret_cast<ushort4*>(&hi[pos]) = hv;
        *reinterpret_cast<ushort4*>(&lo[pos]) = lv;
    }
}

// ---------------------------------------------------------------------------
// Split-bf16 MFMA GEMM (unchanged from round 2): C = A * W^T.
// ---------------------------------------------------------------------------
#define BM 128
#define BN 128
#define BK 32

#define GLD_LDS16(gp, lp)                                                  \
    __builtin_amdgcn_global_load_lds(                                      \
        (const __attribute__((address_space(1))) void*)(gp),               \
        (__attribute__((address_space(3))) void*)(lp), 16, 0, 0)

__global__ __launch_bounds__(256, 2) void gemm_split(
    const ushort* __restrict__ Ahi, const ushort* __restrict__ Alo,
    const ushort* __restrict__ Whi, const ushort* __restrict__ Wlo,
    float* __restrict__ C, int M, int N, int K) {
    __shared__ ushort sA[2][BM * BK];
    __shared__ ushort sB[2][BN * BK];

    const int tid = threadIdx.x;
    const int lane = tid & 63;
    const int w = tid >> 6;
    const int m0 = blockIdx.y * BM;
    const int n0 = blockIdx.x * BN;
    const int wm = (w >> 1) * 64;
    const int wn = (w & 1) * 64;

    int srow[2], skq[2];
#pragma unroll
    for (int c = 0; c < 2; ++c) {
        const int row = (w * 2 + c) * 16 + (lane >> 2);
        srow[c] = row;
        skq[c] = (((lane & 3) ^ ((row >> 1) & 3)) << 3);
    }

    f32x4 acc[4][4];
#pragma unroll
    for (int i = 0; i < 4; ++i)
#pragma unroll
        for (int j = 0; j < 4; ++j) acc[i][j] = (f32x4)0.0f;

    const int lr = lane & 15;
    const int kq = lane >> 4;

    for (int k0 = 0; k0 < K; k0 += BK) {
#pragma unroll
        for (int c = 0; c < 2; ++c) {
            const size_t ga = (size_t)(m0 + srow[c]) * K + k0 + skq[c];
            const size_t gb = (size_t)(n0 + srow[c]) * K + k0 + skq[c];
            const int loff = (w * 2 + c) * 512;
            GLD_LDS16(Ahi + ga, &sA[0][loff]);
            GLD_LDS16(Alo + ga, &sA[1][loff]);
            GLD_LDS16(Whi + gb, &sB[0][loff]);
            GLD_LDS16(Wlo + gb, &sB[1][loff]);
        }
        __syncthreads();

        bf16x8 afh[4], afl[4], bfh[4], bfl[4];
#pragma unroll
        for (int f = 0; f < 4; ++f) {
            const int arow = wm + f * 16 + lr;
            const int aoff = arow * 32 + ((kq ^ ((arow >> 1) & 3)) << 3);
            afh[f] = *reinterpret_cast<const bf16x8*>(&sA[0][aoff]);
            afl[f] = *reinterpret_cast<const bf16x8*>(&sA[1][aoff]);
            const int brow = wn + f * 16 + lr;
            const int boff = brow * 32 + ((kq ^ ((brow >> 1) & 3)) << 3);
            bfh[f] = *reinterpret_cast<const bf16x8*>(&sB[0][boff]);
            bfl[f] = *reinterpret_cast<const bf16x8*>(&sB[1][boff]);
        }
#pragma unroll
        for (int i = 0; i < 4; ++i)
#pragma unroll
            for (int j = 0; j < 4; ++j) {
                acc[i][j] = __builtin_amdgcn_mfma_f32_16x16x32_bf16(
                    afh[i], bfh[j], acc[i][j], 0, 0, 0);
                acc[i][j] = __builtin_amdgcn_mfma_f32_16x16x32_bf16(
                    afh[i], bfl[j], acc[i][j], 0, 0, 0);
                acc[i][j] = __builtin_amdgcn_mfma_f32_16x16x32_bf16(
                    afl[i], bfh[j], acc[i][j], 0, 0, 0);
            }
        __syncthreads();
    }

    const int cr = (lane >> 4) << 2;
    const int cc = lane & 15;
#pragma unroll
    for (int i = 0; i < 4; ++i)
#pragma unroll
        for (int j = 0; j < 4; ++j) {
            float* cp = &C[(size_t)(m0 + wm + i * 16 + cr) * N + n0 + wn +
                           j * 16 + cc];
#pragma unroll
            for (int r = 0; r < 4; ++r) cp[(size_t)r * N] = acc[i][j][r];
        }
}

// ---------------------------------------------------------------------------
// MFMA flash attention. Inputs pre-split/reordered/swizzled:
//   Q [bh][T][64] (scaled by 0.125*log2e), K [bh][S][64], Vt [bh][64][S].
// Block: 256 threads / 4 waves; 64 q-rows per block (16 per wave); KV tile 64.
// QK^T: 3-pass split bf16 MFMA. Softmax in exp2 units. PV: P->bf16 (l summed
// from rounded P for consistency), V 2-pass hi/lo.
// ---------------------------------------------------------------------------
__global__ __launch_bounds__(256, 2) void attn_mfma(
    const ushort* __restrict__ Qhi, const ushort* __restrict__ Qlo,
    const ushort* __restrict__ Khi, const ushort* __restrict__ Klo,
    const ushort* __restrict__ Vhi, const ushort* __restrict__ Vlo,
    float* __restrict__ O) {
    constexpr int T = 1024, S = 2048, H = N_HEADS;
    __shared__ ushort sQ[2][64 * 64];
    __shared__ ushort sK[2][64 * 64];
    __shared__ ushort sV[2][64 * 64];
    __shared__ ushort sP[4][16 * 64];

    const int tid = threadIdx.x;
    const int lane = tid & 63;
    const int w = tid >> 6;
    const int t0 = blockIdx.x * 64;
    const int bh = blockIdx.y;
    const int lr = lane & 15;
    const int g = lane >> 4;
    const int swz = (lr & 7) << 3;

    // ---- stage Q once ----
    const size_t qbase = ((size_t)bh * T + t0) * 64;
#pragma unroll
    for (int i = 0; i < 2; ++i) {
        const int off = i * 2048 + w * 512 + lane * 8;
        GLD_LDS16(Qhi + qbase + off, &sQ[0][off]);
        GLD_LDS16(Qlo + qbase + off, &sQ[1][off]);
    }
    __syncthreads();

    bf16x8 qf[2][2];  // [hi/lo][kk]
    {
        const int row = w * 16 + lr;
#pragma unroll
        for (int kk = 0; kk < 2; ++kk) {
            const int off = row * 64 + ((kk * 32 + g * 8) ^ swz);
            qf[0][kk] = *reinterpret_cast<const bf16x8*>(&sQ[0][off]);
            qf[1][kk] = *reinterpret_cast<const bf16x8*>(&sQ[1][off]);
        }
    }

    f32x4 oacc[4];
#pragma unroll
    for (int jd = 0; jd < 4; ++jd) oacc[jd] = (f32x4)0.0f;
    float m[4], l[4];
#pragma unroll
    for (int r = 0; r < 4; ++r) { m[r] = -1e30f; l[r] = 0.0f; }

    const size_t kbase = (size_t)bh * S * 64;
    const size_t vrow = (size_t)bh * 64;

    for (int s0 = 0; s0 < S; s0 += 64) {
        __syncthreads();  // previous tile's sK/sV reads complete
#pragma unroll
        for (int i = 0; i < 2; ++i) {
            const int off = i * 2048 + w * 512 + lane * 8;
            GLD_LDS16(Khi + kbase + (size_t)s0 * 64 + off, &sK[0][off]);
            GLD_LDS16(Klo + kbase + (size_t)s0 * 64 + off, &sK[1][off]);
        }
#pragma unroll
        for (int i = 0; i < 2; ++i) {
            const int off = i * 2048 + w * 512 + lane * 8;
            const int dd = off >> 6, sl = off & 63;
            const size_t src = (vrow + dd) * S + s0 + sl;
            GLD_LDS16(Vhi + src, &sV[0][off]);
            GLD_LDS16(Vlo + src, &sV[1][off]);
        }
        __syncthreads();  // barrier drains vmcnt -> tiles ready

        // ---- QK^T (logits already in exp2 units) ----
        f32x4 sacc[4];
#pragma unroll
        for (int j = 0; j < 4; ++j) {
            sacc[j] = (f32x4)0.0f;
            const int krow = j * 16 + lr;
            bf16x8 kfh[2], kfl[2];
#pragma unroll
            for (int kk = 0; kk < 2; ++kk) {
                const int off = krow * 64 + ((kk * 32 + g * 8) ^ swz);
                kfh[kk] = *reinterpret_cast<const bf16x8*>(&sK[0][off]);
                kfl[kk] = *reinterpret_cast<const bf16x8*>(&sK[1][off]);
            }
#pragma unroll
            for (int kk = 0; kk < 2; ++kk) {
                sacc[j] = __builtin_amdgcn_mfma_f32_16x16x32_bf16(
                    qf[0][kk], kfh[kk], sacc[j], 0, 0, 0);
                sacc[j] = __builtin_amdgcn_mfma_f32_16x16x32_bf16(
                    qf[0][kk], kfl[kk], sacc[j], 0, 0, 0);
                sacc[j] = __builtin_amdgcn_mfma_f32_16x16x32_bf16(
                    qf[1][kk], kfh[kk], sacc[j], 0, 0, 0);
            }
        }

        // ---- online softmax (rows = g*4 + r) ----
        float f[4], psum[4];
#pragma unroll
        for (int r = 0; r < 4; ++r) {
            float mx = fmaxf(fmaxf(sacc[0][r], sacc[1][r]),
                             fmaxf(sacc[2][r], sacc[3][r]));
            mx = fmaxf(mx, __shfl_xor(mx, 1));
            mx = fmaxf(mx, __shfl_xor(mx, 2));
            mx = fmaxf(mx, __shfl_xor(mx, 4));
            mx = fmaxf(mx, __shfl_xor(mx, 8));
            const float mn = fmaxf(m[r], mx);
            f[r] = exp2f(m[r] - mn);
            m[r] = mn;
            psum[r] = 0.0f;
        }
#pragma unroll
        for (int j = 0; j < 4; ++j) {
#pragma unroll
            for (int r = 0; r < 4; ++r) {
                const int row = g * 4 + r;
                const float p = exp2f(sacc[j][r] - m[r]);
                const ushort ph = f2bf(p);
                psum[r] += bf2f(ph);
                sP[w][row * 64 + ((j * 16 + lr) ^ ((row & 7) << 3))] = ph;
            }
        }
#pragma unroll
        for (int r = 0; r < 4; ++r) {
            float s = psum[r];
            s += __shfl_xor(s, 1);
            s += __shfl_xor(s, 2);
            s += __shfl_xor(s, 4);
            s += __shfl_xor(s, 8);
            l[r] = l[r] * f[r] + s;
        }
#pragma unroll
        for (int jd = 0; jd < 4; ++jd)
#pragma unroll
            for (int r = 0; r < 4; ++r) oacc[jd][r] *= f[r];

        // sP is wave-private; ensure cross-lane ds_writes retired before reads
        asm volatile("s_waitcnt lgkmcnt(0)" ::: "memory");
        __builtin_amdgcn_sched_barrier(0);

        // ---- PV ----
        bf16x8 pf[2];
#pragma unroll
        for (int kk = 0; kk < 2; ++kk) {
            const int off = lr * 64 + ((kk * 32 + g * 8) ^ swz);
            pf[kk] = *reinterpret_cast<const bf16x8*>(&sP[w][off]);
        }
#pragma unroll
        for (int jd = 0; jd < 4; ++jd) {
            const int vr = jd * 16 + lr;
#pragma unroll
            for (int kk = 0; kk < 2; ++kk) {
                const int off = vr * 64 + ((kk * 32 + g * 8) ^ swz);
                const bf16x8 vfh =
                    *reinterpret_cast<const bf16x8*>(&sV[0][off]);
                const bf16x8 vfl =
                    *reinterpret_cast<const bf16x8*>(&sV[1][off]);
                oacc[jd] = __builtin_amdgcn_mfma_f32_16x16x32_bf16(
                    pf[kk], vfh, oacc[jd], 0, 0, 0);
                oacc[jd] = __builtin_amdgcn_mfma_f32_16x16x32_bf16(
                    pf[kk], vfl, oacc[jd], 0, 0, 0);
            }
        }
    }

    // ---- epilogue: O[b][t][h][dd] ----
    const int b = bh >> 4, h = bh & 15;
#pragma unroll
    for (int r = 0; r < 4; ++r) {
        const float inv = 1.0f / l[r];
        const int q = t0 + w * 16 + g * 4 + r;
#pragma unroll
        for (int jd = 0; jd < 4; ++jd)
            O[(((size_t)b * T + q) * H + h) * 64 + jd * 16 + lr] =
                oacc[jd][r] * inv;
    }
}

// ---------------------------------------------------------------------------
extern "C" void kernel_launch(void* const* d_in, const int* in_sizes, int n_in,
                              void* d_out, int out_size, void* d_ws, size_t ws_size,
                              hipStream_t stream) {
    const int B = 4, T = 1024, S = 2048, D = 1024;

    const float* query = (const float*)d_in[0];
    const float* keyv  = (const float*)d_in[1];
    const float* wq    = (const float*)d_in[2];
    const float* wk    = (const float*)d_in[3];
    const float* wv    = (const float*)d_in[4];
    const float* wo    = (const float*)d_in[5];
    float* out = (float*)d_out;

    const size_t nQ = (size_t)B * T * D;  // 4M
    const size_t nK = (size_t)B * S * D;  // 8M
    const size_t nW = (size_t)D * D;      // 1M

    uint8_t* p = (uint8_t*)d_ws;
    ushort* inq_h = (ushort*)p;  p += nQ * 2;
    ushort* inq_l = (ushort*)p;  p += nQ * 2;   // 16 MB (reused as aq hi/lo)
    ushort* inkv_h = (ushort*)p; p += nK * 2;
    ushort* inkv_l = (ushort*)p; p += nK * 2;   // 32 MB (reused as avt hi/lo)
    ushort* whi[4]; ushort* wlo[4];
    for (int i = 0; i < 4; ++i) {
        whi[i] = (ushort*)p; p += nW * 2;
        wlo[i] = (ushort*)p; p += nW * 2;       // 16 MB
    }
    float* Qp = (float*)p; p += nQ * 4;         // 16 MB (reused as AO)
    float* Kp = (float*)p; p += nK * 4;         // 32 MB (reused as ao hi/lo)
    float* Vp = (float*)p; p += nK * 4;         // 32 MB
    ushort* ak_h = (ushort*)p; p += nK * 2;
    ushort* ak_l = (ushort*)p; p += nK * 2;     // 32 MB
    // total 176 MB

    // aliases (stream-ordered safe)
    ushort* aq_h = inq_h;   ushort* aq_l = inq_l;     // after Q-proj
    ushort* avt_h = inkv_h; ushort* avt_l = inkv_l;   // after K/V-proj
    float* AO = Qp;                                   // after reorder(Qp)
    ushort* ao_h = (ushort*)Kp;                       // after reorder(Kp)
    ushort* ao_l = ((ushort*)Kp) + nQ;

    const dim3 blk(256);
    const float* wsrc[4] = {wq, wk, wv, wo};
    const float QSCALE = 0.18033688011112042f;  // 0.125 * log2(e)

    // input/weight splits
    split_bf16_kernel<<<2048, blk, 0, stream>>>(query, inq_h, inq_l, (int)(nQ / 4));
    split_bf16_kernel<<<2048, blk, 0, stream>>>(keyv, inkv_h, inkv_l, (int)(nK / 4));
    for (int i = 0; i < 4; ++i)
        split_bf16_kernel<<<1024, blk, 0, stream>>>(wsrc[i], whi[i], wlo[i],
                                                    (int)(nW / 4));

    // projections
    gemm_split<<<dim3(D / BN, (B * T) / BM), blk, 0, stream>>>(
        inq_h, inq_l, whi[0], wlo[0], Qp, B * T, D, D);
    gemm_split<<<dim3(D / BN, (B * S) / BM), blk, 0, stream>>>(
        inkv_h, inkv_l, whi[1], wlo[1], Kp, B * S, D, D);
    gemm_split<<<dim3(D / BN, (B * S) / BM), blk, 0, stream>>>(
        inkv_h, inkv_l, whi[2], wlo[2], Vp, B * S, D, D);

    // attention pre-layout
    reorder_split<<<dim3(T / 16, B * N_HEADS), blk, 0, stream>>>(Qp, aq_h, aq_l, T, QSCALE);
    reorder_split<<<dim3(S / 16, B * N_HEADS), blk, 0, stream>>>(Kp, ak_h, ak_l, S, 1.0f);
    v_split_t<<<dim3(S / 64, B * N_HEADS), blk, 0, stream>>>(Vp, avt_h, avt_l);

    // attention
    attn_mfma<<<dim3(T / 64, B * N_HEADS), blk, 0, stream>>>(
        aq_h, aq_l, ak_h, ak_l, avt_h, avt_l, AO);

    // output projection
    split_bf16_kernel<<<2048, blk, 0, stream>>>(AO, ao_h, ao_l, (int)(nQ / 4));
    gemm_split<<<dim3(D / BN, (B * T) / BM), blk, 0, stream>>>(
        ao_h, ao_l, whi[3], wlo[3], out, B * T, D, D);
}

// Round 4
// 366.267 us; speedup vs baseline: 3.3944x; 1.2002x over previous
//
#include <hip/hip_runtime.h>
#include <cstdint>
#include <cstddef>

#define N_HEADS 16

typedef __attribute__((ext_vector_type(4))) float f32x4;
typedef __attribute__((ext_vector_type(8))) short bf16x8;

// ---------------------------------------------------------------------------
// fp32 -> (hi, lo) bf16 split helpers (RTN-even, no NaN inputs).
// ---------------------------------------------------------------------------
static __device__ inline ushort f2bf(float x) {
    uint32_t u = __float_as_uint(x);
    uint32_t r = (u + 0x7fffu + ((u >> 16) & 1u)) >> 16;
    return (ushort)r;
}
static __device__ inline float bf2f(ushort h) {
    return __uint_as_float(((uint32_t)h) << 16);
}
static __device__ inline uint32_t cvt_pk_bf16(float lo, float hi) {
    uint32_t r;
    asm("v_cvt_pk_bf16_f32 %0, %1, %2" : "=v"(r) : "v"(lo), "v"(hi));
    return r;
}

__global__ __launch_bounds__(256) void split_bf16_kernel(
    const float* __restrict__ x, ushort* __restrict__ hi,
    ushort* __restrict__ lo, int n4) {
    const int stride = gridDim.x * blockDim.x;
    for (int i = blockIdx.x * blockDim.x + threadIdx.x; i < n4; i += stride) {
        const float4 v = reinterpret_cast<const float4*>(x)[i];
        ushort4 h, l;
        h.x = f2bf(v.x); l.x = f2bf(v.x - bf2f(h.x));
        h.y = f2bf(v.y); l.y = f2bf(v.y - bf2f(h.y));
        h.z = f2bf(v.z); l.z = f2bf(v.z - bf2f(h.z));
        h.w = f2bf(v.w); l.w = f2bf(v.w - bf2f(h.w));
        reinterpret_cast<ushort4*>(hi)[i] = h;
        reinterpret_cast<ushort4*>(lo)[i] = l;
    }
}

// ---------------------------------------------------------------------------
// Split-bf16 MFMA GEMM: C = A[M,K] * W[N,K]^T with fused epilogues.
// MODE 0: plain fp32 C.
// MODE 1: bf16 hi/lo split to attn Q/K layout [bh][x][64], dd ^ ((x&7)<<3),
//         with scale folded before split. X = 1<<log2X rows per batch.
// MODE 2: bf16 hi/lo split to attn V^T layout [bh][dd][2048], s-swizzled.
// ---------------------------------------------------------------------------
#define BM 128
#define BN 128
#define BK 32

#define GLD_LDS16(gp, lp)                                                  \
    __builtin_amdgcn_global_load_lds(                                      \
        (const __attribute__((address_space(1))) void*)(gp),               \
        (__attribute__((address_space(3))) void*)(lp), 16, 0, 0)

template <int MODE>
__global__ __launch_bounds__(256, 2) void gemm_split(
    const ushort* __restrict__ Ahi, const ushort* __restrict__ Alo,
    const ushort* __restrict__ Whi, const ushort* __restrict__ Wlo,
    float* __restrict__ Cf, ushort* __restrict__ Chi,
    ushort* __restrict__ Clo, int M, int N, int K, int log2X, float scale) {
    __shared__ ushort sA[2][BM * BK];
    __shared__ ushort sB[2][BN * BK];

    const int tid = threadIdx.x;
    const int lane = tid & 63;
    const int w = tid >> 6;
    const int m0 = blockIdx.y * BM;
    const int n0 = blockIdx.x * BN;
    const int wm = (w >> 1) * 64;
    const int wn = (w & 1) * 64;

    int srow[2], skq[2];
#pragma unroll
    for (int c = 0; c < 2; ++c) {
        const int row = (w * 2 + c) * 16 + (lane >> 2);
        srow[c] = row;
        skq[c] = (((lane & 3) ^ ((row >> 1) & 3)) << 3);
    }

    f32x4 acc[4][4];
#pragma unroll
    for (int i = 0; i < 4; ++i)
#pragma unroll
        for (int j = 0; j < 4; ++j) acc[i][j] = (f32x4)0.0f;

    const int lr = lane & 15;
    const int kq = lane >> 4;

    for (int k0 = 0; k0 < K; k0 += BK) {
#pragma unroll
        for (int c = 0; c < 2; ++c) {
            const size_t ga = (size_t)(m0 + srow[c]) * K + k0 + skq[c];
            const size_t gb = (size_t)(n0 + srow[c]) * K + k0 + skq[c];
            const int loff = (w * 2 + c) * 512;
            GLD_LDS16(Ahi + ga, &sA[0][loff]);
            GLD_LDS16(Alo + ga, &sA[1][loff]);
            GLD_LDS16(Whi + gb, &sB[0][loff]);
            GLD_LDS16(Wlo + gb, &sB[1][loff]);
        }
        __syncthreads();

        bf16x8 afh[4], afl[4], bfh[4], bfl[4];
#pragma unroll
        for (int f = 0; f < 4; ++f) {
            const int arow = wm + f * 16 + lr;
            const int aoff = arow * 32 + ((kq ^ ((arow >> 1) & 3)) << 3);
            afh[f] = *reinterpret_cast<const bf16x8*>(&sA[0][aoff]);
            afl[f] = *reinterpret_cast<const bf16x8*>(&sA[1][aoff]);
            const int brow = wn + f * 16 + lr;
            const int boff = brow * 32 + ((kq ^ ((brow >> 1) & 3)) << 3);
            bfh[f] = *reinterpret_cast<const bf16x8*>(&sB[0][boff]);
            bfl[f] = *reinterpret_cast<const bf16x8*>(&sB[1][boff]);
        }
#pragma unroll
        for (int i = 0; i < 4; ++i)
#pragma unroll
            for (int j = 0; j < 4; ++j) {
                acc[i][j] = __builtin_amdgcn_mfma_f32_16x16x32_bf16(
                    afh[i], bfh[j], acc[i][j], 0, 0, 0);
                acc[i][j] = __builtin_amdgcn_mfma_f32_16x16x32_bf16(
                    afh[i], bfl[j], acc[i][j], 0, 0, 0);
                acc[i][j] = __builtin_amdgcn_mfma_f32_16x16x32_bf16(
                    afl[i], bfh[j], acc[i][j], 0, 0, 0);
            }
        __syncthreads();
    }

    const int cr = (lane >> 4) << 2;
    const int cc = lane & 15;

    if constexpr (MODE == 0) {
#pragma unroll
        for (int i = 0; i < 4; ++i)
#pragma unroll
            for (int j = 0; j < 4; ++j) {
                float* cp = &Cf[(size_t)(m0 + wm + i * 16 + cr) * N + n0 + wn +
                                j * 16 + cc];
#pragma unroll
                for (int r = 0; r < 4; ++r) cp[(size_t)r * N] = acc[i][j][r];
            }
    } else if constexpr (MODE == 1) {
        const int xm = (1 << log2X) - 1;
#pragma unroll
        for (int i = 0; i < 4; ++i)
#pragma unroll
            for (int j = 0; j < 4; ++j) {
                const int col = n0 + wn + j * 16 + cc;
                const int h = col >> 6, dd = col & 63;
#pragma unroll
                for (int r = 0; r < 4; ++r) {
                    const int mr = m0 + wm + i * 16 + cr + r;
                    const int bb = mr >> log2X;
                    const int x = mr & xm;
                    const float v = acc[i][j][r] * scale;
                    const ushort hv = f2bf(v);
                    const ushort lv = f2bf(v - bf2f(hv));
                    const size_t pos =
                        (((size_t)(bb * N_HEADS + h) << log2X) + x) * 64 +
                        (dd ^ ((x & 7) << 3));
                    Chi[pos] = hv;
                    Clo[pos] = lv;
                }
            }
    } else {  // MODE 2: V^T [bh][dd][2048], s swizzled within 64-blocks
#pragma unroll
        for (int i = 0; i < 4; ++i)
#pragma unroll
            for (int j = 0; j < 4; ++j) {
                const int col = n0 + wn + j * 16 + cc;
                const int h = col >> 6, dd = col & 63;
                const int sb = m0 + wm + i * 16 + cr;  // 4-aligned s base
                const int bb = sb >> 11;
                const int sx = sb & 2047;
                ushort4 hv, lv;
#pragma unroll
                for (int r = 0; r < 4; ++r) {
                    const float v = acc[i][j][r];
                    const ushort h16 = f2bf(v);
                    ((ushort*)&hv)[r] = h16;
                    ((ushort*)&lv)[r] = f2bf(v - bf2f(h16));
                }
                const size_t pos =
                    ((size_t)(bb * N_HEADS + h) * 64 + dd) * 2048 +
                    (sx & ~63) + ((sx & 63) ^ ((dd & 7) << 3));
                *reinterpret_cast<ushort4*>(&Chi[pos]) = hv;
                *reinterpret_cast<ushort4*>(&Clo[pos]) = lv;
            }
    }
}

// ---------------------------------------------------------------------------
// MFMA flash attention, swapped-QK^T in-register softmax, 2-phase K/V dbuf.
// Q [bh][T][64] (pre-scaled by 0.125*log2e, swizzled), K [bh][S][64]
// (swizzled), Vt [bh][64][S] (s-swizzled). Output: bf16 hi/lo split in
// O-proj A-layout [B*T][1024].
// ---------------------------------------------------------------------------
__global__ __launch_bounds__(256, 2) void attn_mfma(
    const ushort* __restrict__ Qhi, const ushort* __restrict__ Qlo,
    const ushort* __restrict__ Khi, const ushort* __restrict__ Klo,
    const ushort* __restrict__ Vhi, const ushort* __restrict__ Vlo,
    ushort* __restrict__ Ohi, ushort* __restrict__ Olo) {
    constexpr int T = 1024, S = 2048, NT = S / 64;
    __shared__ ushort sK[2][2][4096];  // [buf][hi/lo][s*64+dd]
    __shared__ ushort sV[2][2][4096];  // [buf][hi/lo][dd*64+s]
    __shared__ ushort sQ[2][4096];     // [hi/lo]; sQ[0] reused as P buffers

    const int tid = threadIdx.x;
    const int lane = tid & 63;
    const int w = tid >> 6;
    const int t0 = blockIdx.x * 64;
    const int bh = blockIdx.y;
    const int lr = lane & 15;
    const int g = lane >> 4;
    const int swz = (lr & 7) << 3;

    const size_t qbase = ((size_t)bh * T + t0) * 64;
    const size_t kbase = (size_t)bh * S * 64;
    const size_t vbase = (size_t)bh * 64;

    auto stage_kv = [&](int bi, int s0) {
#pragma unroll
        for (int i = 0; i < 2; ++i) {
            const int off = i * 2048 + w * 512 + lane * 8;
            GLD_LDS16(Khi + kbase + (size_t)s0 * 64 + off, &sK[bi][0][off]);
            GLD_LDS16(Klo + kbase + (size_t)s0 * 64 + off, &sK[bi][1][off]);
            const int dd = off >> 6, sl = off & 63;
            const size_t src = (vbase + dd) * S + s0 + sl;
            GLD_LDS16(Vhi + src, &sV[bi][0][off]);
            GLD_LDS16(Vlo + src, &sV[bi][1][off]);
        }
    };

    // prologue: stage Q + first K/V tile
#pragma unroll
    for (int i = 0; i < 2; ++i) {
        const int off = i * 2048 + w * 512 + lane * 8;
        GLD_LDS16(Qhi + qbase + off, &sQ[0][off]);
        GLD_LDS16(Qlo + qbase + off, &sQ[1][off]);
    }
    stage_kv(0, 0);
    __syncthreads();

    // Q fragments (B-operand): lane holds q-col = lr of this wave's 16 rows
    bf16x8 qf[2][2];  // [hi/lo][kk]
    {
        const int qrow = w * 16 + lr;
#pragma unroll
        for (int kk = 0; kk < 2; ++kk) {
            const int off = qrow * 64 + ((kk * 32 + g * 8) ^ swz);
            qf[0][kk] = *reinterpret_cast<const bf16x8*>(&sQ[0][off]);
            qf[1][kk] = *reinterpret_cast<const bf16x8*>(&sQ[1][off]);
        }
    }
    // wave-private P buffer overlays this wave's own Q-hi rows
    ushort* sP = &sQ[0][w * 1024];

    f32x4 oacc[4];
#pragma unroll
    for (int jd = 0; jd < 4; ++jd) oacc[jd] = (f32x4)0.0f;
    float m = -1e30f, l = 0.0f;  // state for q-row = lr (replicated over g)

    for (int t = 0; t < NT; ++t) {
        const int bi = t & 1;
        if (t + 1 < NT) stage_kv(bi ^ 1, (t + 1) * 64);

        // ---- QK^T swapped: sacc[j] = S^T tile, rows s=j*16+g*4+r, col q=lr
        f32x4 sacc[4];
        __builtin_amdgcn_s_setprio(1);
#pragma unroll
        for (int j = 0; j < 4; ++j) {
            sacc[j] = (f32x4)0.0f;
            const int krow = j * 16 + lr;
#pragma unroll
            for (int kk = 0; kk < 2; ++kk) {
                const int off = krow * 64 + ((kk * 32 + g * 8) ^ swz);
                const bf16x8 kh =
                    *reinterpret_cast<const bf16x8*>(&sK[bi][0][off]);
                const bf16x8 kl =
                    *reinterpret_cast<const bf16x8*>(&sK[bi][1][off]);
                sacc[j] = __builtin_amdgcn_mfma_f32_16x16x32_bf16(
                    kh, qf[0][kk], sacc[j], 0, 0, 0);
                sacc[j] = __builtin_amdgcn_mfma_f32_16x16x32_bf16(
                    kh, qf[1][kk], sacc[j], 0, 0, 0);
                sacc[j] = __builtin_amdgcn_mfma_f32_16x16x32_bf16(
                    kl, qf[0][kk], sacc[j], 0, 0, 0);
            }
        }
        __builtin_amdgcn_s_setprio(0);

        // ---- in-register online softmax (q-row = lr) ----
        float mx = fmaxf(fmaxf(sacc[0][0], sacc[0][1]),
                         fmaxf(sacc[0][2], sacc[0][3]));
#pragma unroll
        for (int j = 1; j < 4; ++j)
            mx = fmaxf(mx, fmaxf(fmaxf(sacc[j][0], sacc[j][1]),
                                 fmaxf(sacc[j][2], sacc[j][3])));
        mx = fmaxf(mx, __shfl_xor(mx, 16));
        mx = fmaxf(mx, __shfl_xor(mx, 32));
        const float mn = fmaxf(m, mx);
        const float f = exp2f(m - mn);
        m = mn;

        uint32_t wpk[4][2];
        float psum = 0.0f;
#pragma unroll
        for (int j = 0; j < 4; ++j) {
            const float p0 = exp2f(sacc[j][0] - m);
            const float p1 = exp2f(sacc[j][1] - m);
            const float p2 = exp2f(sacc[j][2] - m);
            const float p3 = exp2f(sacc[j][3] - m);
            wpk[j][0] = cvt_pk_bf16(p0, p1);
            wpk[j][1] = cvt_pk_bf16(p2, p3);
#pragma unroll
            for (int h2 = 0; h2 < 2; ++h2) {
                psum += __uint_as_float(wpk[j][h2] << 16);
                psum += __uint_as_float(wpk[j][h2] & 0xffff0000u);
            }
        }
        psum += __shfl_xor(psum, 16);
        psum += __shfl_xor(psum, 32);
        l = l * f + psum;

        // rescale O accumulator (rows q = g*4+r)
        float fq[4];
#pragma unroll
        for (int r = 0; r < 4; ++r) fq[r] = __shfl(f, g * 4 + r);
#pragma unroll
        for (int jd = 0; jd < 4; ++jd)
#pragma unroll
            for (int r = 0; r < 4; ++r) oacc[jd][r] *= fq[r];

        // write packed P to wave-private LDS: row q=lr, s = j*16+g*4+{0..3}
#pragma unroll
        for (int j = 0; j < 4; ++j) {
            const int sloc = (j * 16 + g * 4) ^ swz;
            *reinterpret_cast<uint2*>(&sP[lr * 64 + sloc]) =
                make_uint2(wpk[j][0], wpk[j][1]);
        }
        asm volatile("s_waitcnt lgkmcnt(0)" ::: "memory");
        __builtin_amdgcn_sched_barrier(0);

        // ---- PV: A=P (row q=lr), B=V ----
        bf16x8 pf[2];
#pragma unroll
        for (int kk = 0; kk < 2; ++kk)
            pf[kk] = *reinterpret_cast<const bf16x8*>(
                &sP[lr * 64 + ((kk * 32 + g * 8) ^ swz)]);
        __builtin_amdgcn_s_setprio(1);
#pragma unroll
        for (int jd = 0; jd < 4; ++jd) {
            const int vr = jd * 16 + lr;
#pragma unroll
            for (int kk = 0; kk < 2; ++kk) {
                const int off = vr * 64 + ((kk * 32 + g * 8) ^ swz);
                const bf16x8 vh =
                    *reinterpret_cast<const bf16x8*>(&sV[bi][0][off]);
                const bf16x8 vl =
                    *reinterpret_cast<const bf16x8*>(&sV[bi][1][off]);
                oacc[jd] = __builtin_amdgcn_mfma_f32_16x16x32_bf16(
                    pf[kk], vh, oacc[jd], 0, 0, 0);
                oacc[jd] = __builtin_amdgcn_mfma_f32_16x16x32_bf16(
                    pf[kk], vl, oacc[jd], 0, 0, 0);
            }
        }
        __builtin_amdgcn_s_setprio(0);
        __syncthreads();  // drains next tile's loads; protects dbuf reuse
    }

    // ---- epilogue: split to bf16 hi/lo in O-proj A layout ----
    const int b = bh >> 4, h = bh & 15;
    float linv[4];
#pragma unroll
    for (int r = 0; r < 4; ++r) linv[r] = 1.0f / __shfl(l, g * 4 + r);
#pragma unroll
    for (int r = 0; r < 4; ++r) {
        const int q = t0 + w * 16 + g * 4 + r;
        const size_t rowb = ((size_t)(b * T + q)) * 1024 + h * 64;
#pragma unroll
        for (int jd = 0; jd < 4; ++jd) {
            const float v = oacc[jd][r] * linv[r];
            const ushort hv = f2bf(v);
            const ushort lv = f2bf(v - bf2f(hv));
            Ohi[rowb + jd * 16 + lr] = hv;
            Olo[rowb + jd * 16 + lr] = lv;
        }
    }
}

// ---------------------------------------------------------------------------
extern "C" void kernel_launch(void* const* d_in, const int* in_sizes, int n_in,
                              void* d_out, int out_size, void* d_ws, size_t ws_size,
                              hipStream_t stream) {
    const int B = 4, T = 1024, S = 2048, D = 1024;

    const float* query = (const float*)d_in[0];
    const float* keyv  = (const float*)d_in[1];
    const float* wq    = (const float*)d_in[2];
    const float* wk    = (const float*)d_in[3];
    const float* wv    = (const float*)d_in[4];
    const float* wo    = (const float*)d_in[5];
    float* out = (float*)d_out;

    const size_t nQ = (size_t)B * T * D;  // 4M
    const size_t nK = (size_t)B * S * D;  // 8M
    const size_t nW = (size_t)D * D;      // 1M

    uint8_t* p = (uint8_t*)d_ws;
    ushort* inq_h = (ushort*)p;  p += nQ * 2;
    ushort* inq_l = (ushort*)p;  p += nQ * 2;   // 16 MB
    ushort* inkv_h = (ushort*)p; p += nK * 2;
    ushort* inkv_l = (ushort*)p; p += nK * 2;   // 32 MB
    ushort* whi[4]; ushort* wlo[4];
    for (int i = 0; i < 4; ++i) {
        whi[i] = (ushort*)p; p += nW * 2;
        wlo[i] = (ushort*)p; p += nW * 2;       // 16 MB
    }
    ushort* aq_h = (ushort*)p;  p += nQ * 2;
    ushort* aq_l = (ushort*)p;  p += nQ * 2;    // 16 MB
    ushort* ak_h = (ushort*)p;  p += nK * 2;
    ushort* ak_l = (ushort*)p;  p += nK * 2;    // 32 MB
    ushort* avt_h = (ushort*)p; p += nK * 2;
    ushort* avt_l = (ushort*)p; p += nK * 2;    // 32 MB
    ushort* ao_h = (ushort*)p;  p += nQ * 2;
    ushort* ao_l = (ushort*)p;  p += nQ * 2;    // 16 MB
    // total 160 MB

    const dim3 blk(256);
    const float QSCALE = 0.18033688011112042f;  // 0.125 * log2(e)

    // input/weight splits
    split_bf16_kernel<<<2048, blk, 0, stream>>>(query, inq_h, inq_l, (int)(nQ / 4));
    split_bf16_kernel<<<2048, blk, 0, stream>>>(keyv, inkv_h, inkv_l, (int)(nK / 4));
    split_bf16_kernel<<<1024, blk, 0, stream>>>(wq, whi[0], wlo[0], (int)(nW / 4));
    split_bf16_kernel<<<1024, blk, 0, stream>>>(wk, whi[1], wlo[1], (int)(nW / 4));
    split_bf16_kernel<<<1024, blk, 0, stream>>>(wv, whi[2], wlo[2], (int)(nW / 4));
    split_bf16_kernel<<<1024, blk, 0, stream>>>(wo, whi[3], wlo[3], (int)(nW / 4));

    // projections with fused attn-layout epilogues
    gemm_split<1><<<dim3(D / BN, (B * T) / BM), blk, 0, stream>>>(
        inq_h, inq_l, whi[0], wlo[0], nullptr, aq_h, aq_l, B * T, D, D, 10, QSCALE);
    gemm_split<1><<<dim3(D / BN, (B * S) / BM), blk, 0, stream>>>(
        inkv_h, inkv_l, whi[1], wlo[1], nullptr, ak_h, ak_l, B * S, D, D, 11, 1.0f);
    gemm_split<2><<<dim3(D / BN, (B * S) / BM), blk, 0, stream>>>(
        inkv_h, inkv_l, whi[2], wlo[2], nullptr, avt_h, avt_l, B * S, D, D, 11, 1.0f);

    // attention (writes split hi/lo directly)
    attn_mfma<<<dim3(T / 64, B * N_HEADS), blk, 0, stream>>>(
        aq_h, aq_l, ak_h, ak_l, avt_h, avt_l, ao_h, ao_l);

    // output projection
    gemm_split<0><<<dim3(D / BN, (B * T) / BM), blk, 0, stream>>>(
        ao_h, ao_l, whi[3], wlo[3], out, nullptr, nullptr, B * T, D, D, 10, 1.0f);
}

// Round 5
// 320.248 us; speedup vs baseline: 3.8821x; 1.1437x over previous
//
#include <hip/hip_runtime.h>
#include <cstdint>
#include <cstddef>

#define N_HEADS 16

typedef __attribute__((ext_vector_type(4))) float f32x4;
typedef __attribute__((ext_vector_type(8))) short bf16x8;

// ---------------------------------------------------------------------------
// fp32 -> (hi, lo) bf16 split helpers (RTN-even, no NaN inputs).
// ---------------------------------------------------------------------------
static __device__ inline ushort f2bf(float x) {
    uint32_t u = __float_as_uint(x);
    uint32_t r = (u + 0x7fffu + ((u >> 16) & 1u)) >> 16;
    return (ushort)r;
}
static __device__ inline float bf2f(ushort h) {
    return __uint_as_float(((uint32_t)h) << 16);
}
static __device__ inline uint32_t cvt_pk_bf16(float lo, float hi) {
    uint32_t r;
    asm("v_cvt_pk_bf16_f32 %0, %1, %2" : "=v"(r) : "v"(lo), "v"(hi));
    return r;
}

__global__ __launch_bounds__(256) void split_bf16_kernel(
    const float* __restrict__ x, ushort* __restrict__ hi,
    ushort* __restrict__ lo, int n4) {
    const int stride = gridDim.x * blockDim.x;
    for (int i = blockIdx.x * blockDim.x + threadIdx.x; i < n4; i += stride) {
        const float4 v = reinterpret_cast<const float4*>(x)[i];
        ushort4 h, l;
        h.x = f2bf(v.x); l.x = f2bf(v.x - bf2f(h.x));
        h.y = f2bf(v.y); l.y = f2bf(v.y - bf2f(h.y));
        h.z = f2bf(v.z); l.z = f2bf(v.z - bf2f(h.z));
        h.w = f2bf(v.w); l.w = f2bf(v.w - bf2f(h.w));
        reinterpret_cast<ushort4*>(hi)[i] = h;
        reinterpret_cast<ushort4*>(lo)[i] = l;
    }
}

// ---------------------------------------------------------------------------
// Split-bf16 MFMA GEMM: C = A[M,K] * W[N,K]^T with fused epilogues.
// MODE 0: plain fp32 C.
// MODE 1: hi+lo split to attn Q layout [bh][x][64], dd ^ ((x&7)<<3), scaled.
// MODE 2: hi-only split to attn V^T layout [bh][dd][2048], s-swizzled.
// MODE 3: hi-only split to attn K layout (same addressing as MODE 1).
// ---------------------------------------------------------------------------
#define BM 128
#define BN 128
#define BK 32

#define GLD_LDS16(gp, lp)                                                  \
    __builtin_amdgcn_global_load_lds(                                      \
        (const __attribute__((address_space(1))) void*)(gp),               \
        (__attribute__((address_space(3))) void*)(lp), 16, 0, 0)

template <int MODE>
__global__ __launch_bounds__(256, 2) void gemm_split(
    const ushort* __restrict__ Ahi, const ushort* __restrict__ Alo,
    const ushort* __restrict__ Whi, const ushort* __restrict__ Wlo,
    float* __restrict__ Cf, ushort* __restrict__ Chi,
    ushort* __restrict__ Clo, int M, int N, int K, int log2X, float scale) {
    __shared__ ushort sA[2][BM * BK];
    __shared__ ushort sB[2][BN * BK];

    const int tid = threadIdx.x;
    const int lane = tid & 63;
    const int w = tid >> 6;
    const int m0 = blockIdx.y * BM;
    const int n0 = blockIdx.x * BN;
    const int wm = (w >> 1) * 64;
    const int wn = (w & 1) * 64;

    int srow[2], skq[2];
#pragma unroll
    for (int c = 0; c < 2; ++c) {
        const int row = (w * 2 + c) * 16 + (lane >> 2);
        srow[c] = row;
        skq[c] = (((lane & 3) ^ ((row >> 1) & 3)) << 3);
    }

    f32x4 acc[4][4];
#pragma unroll
    for (int i = 0; i < 4; ++i)
#pragma unroll
        for (int j = 0; j < 4; ++j) acc[i][j] = (f32x4)0.0f;

    const int lr = lane & 15;
    const int kq = lane >> 4;

    for (int k0 = 0; k0 < K; k0 += BK) {
#pragma unroll
        for (int c = 0; c < 2; ++c) {
            const size_t ga = (size_t)(m0 + srow[c]) * K + k0 + skq[c];
            const size_t gb = (size_t)(n0 + srow[c]) * K + k0 + skq[c];
            const int loff = (w * 2 + c) * 512;
            GLD_LDS16(Ahi + ga, &sA[0][loff]);
            GLD_LDS16(Alo + ga, &sA[1][loff]);
            GLD_LDS16(Whi + gb, &sB[0][loff]);
            GLD_LDS16(Wlo + gb, &sB[1][loff]);
        }
        __syncthreads();

        bf16x8 afh[4], afl[4], bfh[4], bfl[4];
#pragma unroll
        for (int f = 0; f < 4; ++f) {
            const int arow = wm + f * 16 + lr;
            const int aoff = arow * 32 + ((kq ^ ((arow >> 1) & 3)) << 3);
            afh[f] = *reinterpret_cast<const bf16x8*>(&sA[0][aoff]);
            afl[f] = *reinterpret_cast<const bf16x8*>(&sA[1][aoff]);
            const int brow = wn + f * 16 + lr;
            const int boff = brow * 32 + ((kq ^ ((brow >> 1) & 3)) << 3);
            bfh[f] = *reinterpret_cast<const bf16x8*>(&sB[0][boff]);
            bfl[f] = *reinterpret_cast<const bf16x8*>(&sB[1][boff]);
        }
#pragma unroll
        for (int i = 0; i < 4; ++i)
#pragma unroll
            for (int j = 0; j < 4; ++j) {
                acc[i][j] = __builtin_amdgcn_mfma_f32_16x16x32_bf16(
                    afh[i], bfh[j], acc[i][j], 0, 0, 0);
                acc[i][j] = __builtin_amdgcn_mfma_f32_16x16x32_bf16(
                    afh[i], bfl[j], acc[i][j], 0, 0, 0);
                acc[i][j] = __builtin_amdgcn_mfma_f32_16x16x32_bf16(
                    afl[i], bfh[j], acc[i][j], 0, 0, 0);
            }
        __syncthreads();
    }

    const int cr = (lane >> 4) << 2;
    const int cc = lane & 15;

    if constexpr (MODE == 0) {
#pragma unroll
        for (int i = 0; i < 4; ++i)
#pragma unroll
            for (int j = 0; j < 4; ++j) {
                float* cp = &Cf[(size_t)(m0 + wm + i * 16 + cr) * N + n0 + wn +
                                j * 16 + cc];
#pragma unroll
                for (int r = 0; r < 4; ++r) cp[(size_t)r * N] = acc[i][j][r];
            }
    } else if constexpr (MODE == 1 || MODE == 3) {
        const int xm = (1 << log2X) - 1;
#pragma unroll
        for (int i = 0; i < 4; ++i)
#pragma unroll
            for (int j = 0; j < 4; ++j) {
                const int col = n0 + wn + j * 16 + cc;
                const int h = col >> 6, dd = col & 63;
#pragma unroll
                for (int r = 0; r < 4; ++r) {
                    const int mr = m0 + wm + i * 16 + cr + r;
                    const int bb = mr >> log2X;
                    const int x = mr & xm;
                    const float v = acc[i][j][r] * scale;
                    const ushort hv = f2bf(v);
                    const size_t pos =
                        (((size_t)(bb * N_HEADS + h) << log2X) + x) * 64 +
                        (dd ^ ((x & 7) << 3));
                    Chi[pos] = hv;
                    if constexpr (MODE == 1) Clo[pos] = f2bf(v - bf2f(hv));
                }
            }
    } else {  // MODE 2: V^T [bh][dd][2048], s swizzled within 64-blocks
#pragma unroll
        for (int i = 0; i < 4; ++i)
#pragma unroll
            for (int j = 0; j < 4; ++j) {
                const int col = n0 + wn + j * 16 + cc;
                const int h = col >> 6, dd = col & 63;
                const int sb = m0 + wm + i * 16 + cr;  // 4-aligned s base
                const int bb = sb >> 11;
                const int sx = sb & 2047;
                ushort4 hv;
#pragma unroll
                for (int r = 0; r < 4; ++r) ((ushort*)&hv)[r] = f2bf(acc[i][j][r]);
                const size_t pos =
                    ((size_t)(bb * N_HEADS + h) * 64 + dd) * 2048 +
                    (sx & ~63) + ((sx & 63) ^ ((dd & 7) << 3));
                *reinterpret_cast<ushort4*>(&Chi[pos]) = hv;
            }
    }
}

// ---------------------------------------------------------------------------
// MFMA flash attention. Swapped QK^T, in-register softmax, defer-max,
// 2-phase K/V dbuf, K/V hi-only (2-pass QK = k·(qhi+qlo); 1-pass PV).
// Q [bh][T][64] hi+lo (pre-scaled by 0.125*log2e, swizzled), K [bh][S][64]
// hi (swizzled), Vt [bh][64][S] hi (s-swizzled). Output: bf16 hi/lo split.
// LDS = 48 KB -> 3 blocks/CU.
// ---------------------------------------------------------------------------
__global__ __launch_bounds__(256, 3) void attn_mfma(
    const ushort* __restrict__ Qhi, const ushort* __restrict__ Qlo,
    const ushort* __restrict__ Khi, const ushort* __restrict__ Vhi,
    ushort* __restrict__ Ohi, ushort* __restrict__ Olo) {
    constexpr int T = 1024, S = 2048, NT = S / 64;
    __shared__ ushort sK[2][4096];  // [buf][s*64+dd]     (hi)
    __shared__ ushort sV[2][4096];  // [buf][dd*64+s]     (hi)
    __shared__ ushort sQ[2][4096];  // [hi/lo]; sQ[0] reused as P buffers

    const int tid = threadIdx.x;
    const int lane = tid & 63;
    const int w = tid >> 6;
    const int t0 = blockIdx.x * 64;
    const int bh = blockIdx.y;
    const int lr = lane & 15;
    const int g = lane >> 4;
    const int swz = (lr & 7) << 3;

    const size_t qbase = ((size_t)bh * T + t0) * 64;
    const size_t kbase = (size_t)bh * S * 64;
    const size_t vbase = (size_t)bh * 64;

    auto stage_kv = [&](int bi, int s0) {
#pragma unroll
        for (int i = 0; i < 2; ++i) {
            const int off = i * 2048 + w * 512 + lane * 8;
            GLD_LDS16(Khi + kbase + (size_t)s0 * 64 + off, &sK[bi][off]);
            const int dd = off >> 6, sl = off & 63;
            GLD_LDS16(Vhi + (vbase + dd) * S + s0 + sl, &sV[bi][off]);
        }
    };

    // prologue: stage Q + first K/V tile
#pragma unroll
    for (int i = 0; i < 2; ++i) {
        const int off = i * 2048 + w * 512 + lane * 8;
        GLD_LDS16(Qhi + qbase + off, &sQ[0][off]);
        GLD_LDS16(Qlo + qbase + off, &sQ[1][off]);
    }
    stage_kv(0, 0);
    __syncthreads();

    // Q fragments (B-operand): lane holds q-col = lr of this wave's 16 rows
    bf16x8 qf[2][2];  // [hi/lo][kk]
    {
        const int qrow = w * 16 + lr;
#pragma unroll
        for (int kk = 0; kk < 2; ++kk) {
            const int off = qrow * 64 + ((kk * 32 + g * 8) ^ swz);
            qf[0][kk] = *reinterpret_cast<const bf16x8*>(&sQ[0][off]);
            qf[1][kk] = *reinterpret_cast<const bf16x8*>(&sQ[1][off]);
        }
    }
    // wave-private P buffer overlays this wave's OWN Q-hi rows (safe: in regs)
    ushort* sP = &sQ[0][w * 1024];

    f32x4 oacc[4];
#pragma unroll
    for (int jd = 0; jd < 4; ++jd) oacc[jd] = (f32x4)0.0f;
    float m = -1e30f, l = 0.0f;  // state for q-row = lr (replicated over g)

    for (int t = 0; t < NT; ++t) {
        const int bi = t & 1;
        if (t + 1 < NT) stage_kv(bi ^ 1, (t + 1) * 64);

        // ---- QK^T swapped, 2-pass: k_hi·(q_hi + q_lo) ----
        f32x4 sacc[4];
        __builtin_amdgcn_s_setprio(1);
#pragma unroll
        for (int j = 0; j < 4; ++j) {
            sacc[j] = (f32x4)0.0f;
            const int krow = j * 16 + lr;
#pragma unroll
            for (int kk = 0; kk < 2; ++kk) {
                const int off = krow * 64 + ((kk * 32 + g * 8) ^ swz);
                const bf16x8 kh =
                    *reinterpret_cast<const bf16x8*>(&sK[bi][off]);
                sacc[j] = __builtin_amdgcn_mfma_f32_16x16x32_bf16(
                    kh, qf[0][kk], sacc[j], 0, 0, 0);
                sacc[j] = __builtin_amdgcn_mfma_f32_16x16x32_bf16(
                    kh, qf[1][kk], sacc[j], 0, 0, 0);
            }
        }
        __builtin_amdgcn_s_setprio(0);

        // ---- row max (q-row = lr; nested triples encourage v_max3) ----
        float mx = fmaxf(fmaxf(sacc[0][0], sacc[0][1]),
                         fmaxf(sacc[0][2], sacc[0][3]));
#pragma unroll
        for (int j = 1; j < 4; ++j)
            mx = fmaxf(mx, fmaxf(fmaxf(sacc[j][0], sacc[j][1]),
                                 fmaxf(sacc[j][2], sacc[j][3])));
        mx = fmaxf(mx, __shfl_xor(mx, 16));
        mx = fmaxf(mx, __shfl_xor(mx, 32));

        // ---- defer-max: rescale only when max grew past THR=8 (exp2 units)
        if (!__all(mx <= m + 8.0f)) {
            const float mn = fmaxf(m, mx);
            const float f = exp2f(m - mn);
            m = mn;
            l *= f;
            float fq[4];
#pragma unroll
            for (int r = 0; r < 4; ++r) fq[r] = __shfl(f, g * 4 + r);
#pragma unroll
            for (int jd = 0; jd < 4; ++jd)
#pragma unroll
                for (int r = 0; r < 4; ++r) oacc[jd][r] *= fq[r];
        }

        // ---- P = exp2(S - m); l from raw values; pack to bf16 ----
        uint32_t wpk[4][2];
        float psum = 0.0f;
#pragma unroll
        for (int j = 0; j < 4; ++j) {
            const float p0 = exp2f(sacc[j][0] - m);
            const float p1 = exp2f(sacc[j][1] - m);
            const float p2 = exp2f(sacc[j][2] - m);
            const float p3 = exp2f(sacc[j][3] - m);
            psum += (p0 + p1) + (p2 + p3);
            wpk[j][0] = cvt_pk_bf16(p0, p1);
            wpk[j][1] = cvt_pk_bf16(p2, p3);
        }
        psum += __shfl_xor(psum, 16);
        psum += __shfl_xor(psum, 32);
        l += psum;

        // write packed P to wave-private LDS: row q=lr, s = j*16+g*4+{0..3}
#pragma unroll
        for (int j = 0; j < 4; ++j) {
            const int sloc = (j * 16 + g * 4) ^ swz;
            *reinterpret_cast<uint2*>(&sP[lr * 64 + sloc]) =
                make_uint2(wpk[j][0], wpk[j][1]);
        }
        asm volatile("s_waitcnt lgkmcnt(0)" ::: "memory");
        __builtin_amdgcn_sched_barrier(0);

        // ---- PV, 1-pass: A=P (row q=lr), B=V_hi ----
        bf16x8 pf[2];
#pragma unroll
        for (int kk = 0; kk < 2; ++kk)
            pf[kk] = *reinterpret_cast<const bf16x8*>(
                &sP[lr * 64 + ((kk * 32 + g * 8) ^ swz)]);
        __builtin_amdgcn_s_setprio(1);
#pragma unroll
        for (int jd = 0; jd < 4; ++jd) {
            const int vr = jd * 16 + lr;
#pragma unroll
            for (int kk = 0; kk < 2; ++kk) {
                const bf16x8 vh = *reinterpret_cast<const bf16x8*>(
                    &sV[bi][vr * 64 + ((kk * 32 + g * 8) ^ swz)]);
                oacc[jd] = __builtin_amdgcn_mfma_f32_16x16x32_bf16(
                    pf[kk], vh, oacc[jd], 0, 0, 0);
            }
        }
        __builtin_amdgcn_s_setprio(0);
        __syncthreads();  // drains next tile's loads; protects dbuf reuse
    }

    // ---- epilogue: split to bf16 hi/lo in O-proj A layout ----
    const int b = bh >> 4, h = bh & 15;
    float linv[4];
#pragma unroll
    for (int r = 0; r < 4; ++r) linv[r] = 1.0f / __shfl(l, g * 4 + r);
#pragma unroll
    for (int r = 0; r < 4; ++r) {
        const int q = t0 + w * 16 + g * 4 + r;
        const size_t rowb = ((size_t)(b * T + q)) * 1024 + h * 64;
#pragma unroll
        for (int jd = 0; jd < 4; ++jd) {
            const float v = oacc[jd][r] * linv[r];
            const ushort hv = f2bf(v);
            Ohi[rowb + jd * 16 + lr] = hv;
            Olo[rowb + jd * 16 + lr] = f2bf(v - bf2f(hv));
        }
    }
}

// ---------------------------------------------------------------------------
extern "C" void kernel_launch(void* const* d_in, const int* in_sizes, int n_in,
                              void* d_out, int out_size, void* d_ws, size_t ws_size,
                              hipStream_t stream) {
    const int B = 4, T = 1024, S = 2048, D = 1024;

    const float* query = (const float*)d_in[0];
    const float* keyv  = (const float*)d_in[1];
    const float* wq    = (const float*)d_in[2];
    const float* wk    = (const float*)d_in[3];
    const float* wv    = (const float*)d_in[4];
    const float* wo    = (const float*)d_in[5];
    float* out = (float*)d_out;

    const size_t nQ = (size_t)B * T * D;  // 4M
    const size_t nK = (size_t)B * S * D;  // 8M
    const size_t nW = (size_t)D * D;      // 1M

    uint8_t* p = (uint8_t*)d_ws;
    ushort* inq_h = (ushort*)p;  p += nQ * 2;
    ushort* inq_l = (ushort*)p;  p += nQ * 2;   // 16 MB
    ushort* inkv_h = (ushort*)p; p += nK * 2;
    ushort* inkv_l = (ushort*)p; p += nK * 2;   // 32 MB
    ushort* whi[4]; ushort* wlo[4];
    for (int i = 0; i < 4; ++i) {
        whi[i] = (ushort*)p; p += nW * 2;
        wlo[i] = (ushort*)p; p += nW * 2;       // 16 MB
    }
    ushort* aq_h = (ushort*)p;  p += nQ * 2;
    ushort* aq_l = (ushort*)p;  p += nQ * 2;    // 16 MB
    ushort* ak_h = (ushort*)p;  p += nK * 2;    // 16 MB (hi only)
    ushort* avt_h = (ushort*)p; p += nK * 2;    // 16 MB (hi only)
    ushort* ao_h = (ushort*)p;  p += nQ * 2;
    ushort* ao_l = (ushort*)p;  p += nQ * 2;    // 16 MB
    // total 128 MB

    const dim3 blk(256);
    const float QSCALE = 0.18033688011112042f;  // 0.125 * log2(e)

    // input/weight splits
    split_bf16_kernel<<<2048, blk, 0, stream>>>(query, inq_h, inq_l, (int)(nQ / 4));
    split_bf16_kernel<<<2048, blk, 0, stream>>>(keyv, inkv_h, inkv_l, (int)(nK / 4));
    split_bf16_kernel<<<1024, blk, 0, stream>>>(wq, whi[0], wlo[0], (int)(nW / 4));
    split_bf16_kernel<<<1024, blk, 0, stream>>>(wk, whi[1], wlo[1], (int)(nW / 4));
    split_bf16_kernel<<<1024, blk, 0, stream>>>(wv, whi[2], wlo[2], (int)(nW / 4));
    split_bf16_kernel<<<1024, blk, 0, stream>>>(wo, whi[3], wlo[3], (int)(nW / 4));

    // projections with fused attn-layout epilogues
    gemm_split<1><<<dim3(D / BN, (B * T) / BM), blk, 0, stream>>>(
        inq_h, inq_l, whi[0], wlo[0], nullptr, aq_h, aq_l, B * T, D, D, 10, QSCALE);
    gemm_split<3><<<dim3(D / BN, (B * S) / BM), blk, 0, stream>>>(
        inkv_h, inkv_l, whi[1], wlo[1], nullptr, ak_h, nullptr, B * S, D, D, 11, 1.0f);
    gemm_split<2><<<dim3(D / BN, (B * S) / BM), blk, 0, stream>>>(
        inkv_h, inkv_l, whi[2], wlo[2], nullptr, avt_h, nullptr, B * S, D, D, 11, 1.0f);

    // attention (writes split hi/lo directly)
    attn_mfma<<<dim3(T / 64, B * N_HEADS), blk, 0, stream>>>(
        aq_h, aq_l, ak_h, avt_h, ao_h, ao_l);

    // output projection
    gemm_split<0><<<dim3(D / BN, (B * T) / BM), blk, 0, stream>>>(
        ao_h, ao_l, whi[3], wlo[3], out, nullptr, nullptr, B * T, D, D, 10, 1.0f);
}

// Round 6
// 294.279 us; speedup vs baseline: 4.2247x; 1.0882x over previous
//
#include <hip/hip_runtime.h>
#include <cstdint>
#include <cstddef>

#define N_HEADS 16

typedef __attribute__((ext_vector_type(4))) float f32x4;
typedef __attribute__((ext_vector_type(8))) short bf16x8;

// ---------------------------------------------------------------------------
// fp32 -> (hi, lo) bf16 split helpers (RTN-even, no NaN inputs).
// ---------------------------------------------------------------------------
static __device__ inline ushort f2bf(float x) {
    uint32_t u = __float_as_uint(x);
    uint32_t r = (u + 0x7fffu + ((u >> 16) & 1u)) >> 16;
    return (ushort)r;
}
static __device__ inline float bf2f(ushort h) {
    return __uint_as_float(((uint32_t)h) << 16);
}
static __device__ inline uint32_t cvt_pk_bf16(float lo, float hi) {
    uint32_t r;
    asm("v_cvt_pk_bf16_f32 %0, %1, %2" : "=v"(r) : "v"(lo), "v"(hi));
    return r;
}

__global__ __launch_bounds__(256) void split_bf16_kernel(
    const float* __restrict__ x, ushort* __restrict__ hi,
    ushort* __restrict__ lo, int n4) {
    const int stride = gridDim.x * blockDim.x;
    for (int i = blockIdx.x * blockDim.x + threadIdx.x; i < n4; i += stride) {
        const float4 v = reinterpret_cast<const float4*>(x)[i];
        ushort4 h, l;
        h.x = f2bf(v.x); l.x = f2bf(v.x - bf2f(h.x));
        h.y = f2bf(v.y); l.y = f2bf(v.y - bf2f(h.y));
        h.z = f2bf(v.z); l.z = f2bf(v.z - bf2f(h.z));
        h.w = f2bf(v.w); l.w = f2bf(v.w - bf2f(h.w));
        reinterpret_cast<ushort4*>(hi)[i] = h;
        reinterpret_cast<ushort4*>(lo)[i] = l;
    }
}

// One launch for all 4 weight matrices (blockIdx.y selects; uniform branch).
__global__ __launch_bounds__(256) void split4_bf16_kernel(
    const float* __restrict__ w0, const float* __restrict__ w1,
    const float* __restrict__ w2, const float* __restrict__ w3,
    ushort* __restrict__ h0, ushort* __restrict__ l0,
    ushort* __restrict__ h1, ushort* __restrict__ l1,
    ushort* __restrict__ h2, ushort* __restrict__ l2,
    ushort* __restrict__ h3, ushort* __restrict__ l3, int n4) {
    const float* x;
    ushort *hi, *lo;
    if (blockIdx.y == 0)      { x = w0; hi = h0; lo = l0; }
    else if (blockIdx.y == 1) { x = w1; hi = h1; lo = l1; }
    else if (blockIdx.y == 2) { x = w2; hi = h2; lo = l2; }
    else                      { x = w3; hi = h3; lo = l3; }
    const int stride = gridDim.x * blockDim.x;
    for (int i = blockIdx.x * blockDim.x + threadIdx.x; i < n4; i += stride) {
        const float4 v = reinterpret_cast<const float4*>(x)[i];
        ushort4 h, l;
        h.x = f2bf(v.x); l.x = f2bf(v.x - bf2f(h.x));
        h.y = f2bf(v.y); l.y = f2bf(v.y - bf2f(h.y));
        h.z = f2bf(v.z); l.z = f2bf(v.z - bf2f(h.z));
        h.w = f2bf(v.w); l.w = f2bf(v.w - bf2f(h.w));
        reinterpret_cast<ushort4*>(hi)[i] = h;
        reinterpret_cast<ushort4*>(lo)[i] = l;
    }
}

// ---------------------------------------------------------------------------
// Split-bf16 MFMA GEMM: C = A[M,K] * W[N,K]^T with fused epilogues.
// MODE 0: plain fp32 C.
// MODE 1: hi+lo split to attn Q layout [bh][x][64], dd ^ ((x&7)<<3), scaled.
// MODE 2: hi-only split to attn V^T layout [bh][dd][2048], s-swizzled.
// MODE 3: hi-only split to attn K layout (same addressing as MODE 1).
// ---------------------------------------------------------------------------
#define BM 128
#define BN 128
#define BK 32

#define GLD_LDS16(gp, lp)                                                  \
    __builtin_amdgcn_global_load_lds(                                      \
        (const __attribute__((address_space(1))) void*)(gp),               \
        (__attribute__((address_space(3))) void*)(lp), 16, 0, 0)

template <int MODE>
__global__ __launch_bounds__(256, 2) void gemm_split(
    const ushort* __restrict__ Ahi, const ushort* __restrict__ Alo,
    const ushort* __restrict__ Whi, const ushort* __restrict__ Wlo,
    float* __restrict__ Cf, ushort* __restrict__ Chi,
    ushort* __restrict__ Clo, int M, int N, int K, int log2X, float scale) {
    __shared__ ushort sA[2][BM * BK];
    __shared__ ushort sB[2][BN * BK];

    const int tid = threadIdx.x;
    const int lane = tid & 63;
    const int w = tid >> 6;
    const int m0 = blockIdx.y * BM;
    const int n0 = blockIdx.x * BN;
    const int wm = (w >> 1) * 64;
    const int wn = (w & 1) * 64;

    int srow[2], skq[2];
#pragma unroll
    for (int c = 0; c < 2; ++c) {
        const int row = (w * 2 + c) * 16 + (lane >> 2);
        srow[c] = row;
        skq[c] = (((lane & 3) ^ ((row >> 1) & 3)) << 3);
    }

    f32x4 acc[4][4];
#pragma unroll
    for (int i = 0; i < 4; ++i)
#pragma unroll
        for (int j = 0; j < 4; ++j) acc[i][j] = (f32x4)0.0f;

    const int lr = lane & 15;
    const int kq = lane >> 4;

    for (int k0 = 0; k0 < K; k0 += BK) {
#pragma unroll
        for (int c = 0; c < 2; ++c) {
            const size_t ga = (size_t)(m0 + srow[c]) * K + k0 + skq[c];
            const size_t gb = (size_t)(n0 + srow[c]) * K + k0 + skq[c];
            const int loff = (w * 2 + c) * 512;
            GLD_LDS16(Ahi + ga, &sA[0][loff]);
            GLD_LDS16(Alo + ga, &sA[1][loff]);
            GLD_LDS16(Whi + gb, &sB[0][loff]);
            GLD_LDS16(Wlo + gb, &sB[1][loff]);
        }
        __syncthreads();

        bf16x8 afh[4], afl[4], bfh[4], bfl[4];
#pragma unroll
        for (int f = 0; f < 4; ++f) {
            const int arow = wm + f * 16 + lr;
            const int aoff = arow * 32 + ((kq ^ ((arow >> 1) & 3)) << 3);
            afh[f] = *reinterpret_cast<const bf16x8*>(&sA[0][aoff]);
            afl[f] = *reinterpret_cast<const bf16x8*>(&sA[1][aoff]);
            const int brow = wn + f * 16 + lr;
            const int boff = brow * 32 + ((kq ^ ((brow >> 1) & 3)) << 3);
            bfh[f] = *reinterpret_cast<const bf16x8*>(&sB[0][boff]);
            bfl[f] = *reinterpret_cast<const bf16x8*>(&sB[1][boff]);
        }
#pragma unroll
        for (int i = 0; i < 4; ++i)
#pragma unroll
            for (int j = 0; j < 4; ++j) {
                acc[i][j] = __builtin_amdgcn_mfma_f32_16x16x32_bf16(
                    afh[i], bfh[j], acc[i][j], 0, 0, 0);
                acc[i][j] = __builtin_amdgcn_mfma_f32_16x16x32_bf16(
                    afh[i], bfl[j], acc[i][j], 0, 0, 0);
                acc[i][j] = __builtin_amdgcn_mfma_f32_16x16x32_bf16(
                    afl[i], bfh[j], acc[i][j], 0, 0, 0);
            }
        __syncthreads();
    }

    const int cr = (lane >> 4) << 2;
    const int cc = lane & 15;

    if constexpr (MODE == 0) {
#pragma unroll
        for (int i = 0; i < 4; ++i)
#pragma unroll
            for (int j = 0; j < 4; ++j) {
                float* cp = &Cf[(size_t)(m0 + wm + i * 16 + cr) * N + n0 + wn +
                                j * 16 + cc];
#pragma unroll
                for (int r = 0; r < 4; ++r) cp[(size_t)r * N] = acc[i][j][r];
            }
    } else if constexpr (MODE == 1 || MODE == 3) {
        const int xm = (1 << log2X) - 1;
#pragma unroll
        for (int i = 0; i < 4; ++i)
#pragma unroll
            for (int j = 0; j < 4; ++j) {
                const int col = n0 + wn + j * 16 + cc;
                const int h = col >> 6, dd = col & 63;
#pragma unroll
                for (int r = 0; r < 4; ++r) {
                    const int mr = m0 + wm + i * 16 + cr + r;
                    const int bb = mr >> log2X;
                    const int x = mr & xm;
                    const float v = acc[i][j][r] * scale;
                    const ushort hv = f2bf(v);
                    const size_t pos =
                        (((size_t)(bb * N_HEADS + h) << log2X) + x) * 64 +
                        (dd ^ ((x & 7) << 3));
                    Chi[pos] = hv;
                    if constexpr (MODE == 1) Clo[pos] = f2bf(v - bf2f(hv));
                }
            }
    } else {  // MODE 2: V^T [bh][dd][2048], s swizzled within 64-blocks
#pragma unroll
        for (int i = 0; i < 4; ++i)
#pragma unroll
            for (int j = 0; j < 4; ++j) {
                const int col = n0 + wn + j * 16 + cc;
                const int h = col >> 6, dd = col & 63;
                const int sb = m0 + wm + i * 16 + cr;  // 4-aligned s base
                const int bb = sb >> 11;
                const int sx = sb & 2047;
                ushort4 hv;
#pragma unroll
                for (int r = 0; r < 4; ++r) ((ushort*)&hv)[r] = f2bf(acc[i][j][r]);
                const size_t pos =
                    ((size_t)(bb * N_HEADS + h) * 64 + dd) * 2048 +
                    (sx & ~63) + ((sx & 63) ^ ((dd & 7) << 3));
                *reinterpret_cast<ushort4*>(&Chi[pos]) = hv;
            }
    }
}

// ---------------------------------------------------------------------------
// MFMA flash attention. Swapped QK^T, in-register softmax, defer-max,
// 2-phase K/V dbuf, K/V hi-only. LDS = 40 KB -> 4 blocks/CU (grid 1024 =
// exactly full residency). Q staged through the idle dbuf half (buf 1).
// 1-D grid with XCD-grouping: each XCD owns 8 whole bh groups so K/V are
// L2-resident per XCD.
// ---------------------------------------------------------------------------
__global__ __launch_bounds__(256, 4) void attn_mfma(
    const ushort* __restrict__ Qhi, const ushort* __restrict__ Qlo,
    const ushort* __restrict__ Khi, const ushort* __restrict__ Vhi,
    ushort* __restrict__ Ohi, ushort* __restrict__ Olo) {
    constexpr int T = 1024, S = 2048, NT = S / 64;
    __shared__ ushort sK[2][4096];  // [buf][s*64+dd]  (hi)
    __shared__ ushort sV[2][4096];  // [buf][dd*64+s]  (hi)
    __shared__ ushort sPb[4096];    // 4 x 2KB wave-private P buffers

    const int tid = threadIdx.x;
    const int lane = tid & 63;
    const int w = tid >> 6;
    // XCD-grouped decode: blocks with id%8==c all map to bh in [8c, 8c+8).
    const int id = blockIdx.x;
    const int wid = (id & 7) * 128 + (id >> 3);
    const int t0 = (wid & 15) * 64;
    const int bh = wid >> 4;
    const int lr = lane & 15;
    const int g = lane >> 4;
    const int swz = (lr & 7) << 3;

    const size_t qbase = ((size_t)bh * T + t0) * 64;
    const size_t kbase = (size_t)bh * S * 64;
    const size_t vbase = (size_t)bh * 64;

    auto stage_kv = [&](int bi, int s0) {
#pragma unroll
        for (int i = 0; i < 2; ++i) {
            const int off = i * 2048 + w * 512 + lane * 8;
            GLD_LDS16(Khi + kbase + (size_t)s0 * 64 + off, &sK[bi][off]);
            const int dd = off >> 6, sl = off & 63;
            GLD_LDS16(Vhi + (vbase + dd) * S + s0 + sl, &sV[bi][off]);
        }
    };

    // prologue: Q-hi -> sK[1], Q-lo -> sV[1]; first K/V tile -> buf 0
#pragma unroll
    for (int i = 0; i < 2; ++i) {
        const int off = i * 2048 + w * 512 + lane * 8;
        GLD_LDS16(Qhi + qbase + off, &sK[1][off]);
        GLD_LDS16(Qlo + qbase + off, &sV[1][off]);
    }
    stage_kv(0, 0);
    __syncthreads();  // drains all prologue loads

    // Q fragments (B-operand): lane holds q-col = lr of this wave's 16 rows
    bf16x8 qf[2][2];  // [hi/lo][kk]
    {
        const int qrow = w * 16 + lr;
#pragma unroll
        for (int kk = 0; kk < 2; ++kk) {
            const int off = qrow * 64 + ((kk * 32 + g * 8) ^ swz);
            qf[0][kk] = *reinterpret_cast<const bf16x8*>(&sK[1][off]);
            qf[1][kk] = *reinterpret_cast<const bf16x8*>(&sV[1][off]);
        }
    }
    __syncthreads();  // all Q reads done before buf1 gets overwritten

    ushort* sP = &sPb[w * 1024];  // wave-private

    f32x4 oacc[4];
#pragma unroll
    for (int jd = 0; jd < 4; ++jd) oacc[jd] = (f32x4)0.0f;
    float m = -1e30f, l = 0.0f;  // state for q-row = lr (replicated over g)

    for (int t = 0; t < NT; ++t) {
        const int bi = t & 1;
        if (t + 1 < NT) stage_kv(bi ^ 1, (t + 1) * 64);

        // ---- QK^T swapped, 2-pass: k_hi·(q_hi + q_lo) ----
        f32x4 sacc[4];
        __builtin_amdgcn_s_setprio(1);
#pragma unroll
        for (int j = 0; j < 4; ++j) {
            sacc[j] = (f32x4)0.0f;
            const int krow = j * 16 + lr;
#pragma unroll
            for (int kk = 0; kk < 2; ++kk) {
                const int off = krow * 64 + ((kk * 32 + g * 8) ^ swz);
                const bf16x8 kh =
                    *reinterpret_cast<const bf16x8*>(&sK[bi][off]);
                sacc[j] = __builtin_amdgcn_mfma_f32_16x16x32_bf16(
                    kh, qf[0][kk], sacc[j], 0, 0, 0);
                sacc[j] = __builtin_amdgcn_mfma_f32_16x16x32_bf16(
                    kh, qf[1][kk], sacc[j], 0, 0, 0);
            }
        }
        __builtin_amdgcn_s_setprio(0);

        // ---- row max (q-row = lr) ----
        float mx = fmaxf(fmaxf(sacc[0][0], sacc[0][1]),
                         fmaxf(sacc[0][2], sacc[0][3]));
#pragma unroll
        for (int j = 1; j < 4; ++j)
            mx = fmaxf(mx, fmaxf(fmaxf(sacc[j][0], sacc[j][1]),
                                 fmaxf(sacc[j][2], sacc[j][3])));
        mx = fmaxf(mx, __shfl_xor(mx, 16));
        mx = fmaxf(mx, __shfl_xor(mx, 32));

        // ---- defer-max: rescale only when max grew past THR=8 (exp2 units)
        if (!__all(mx <= m + 8.0f)) {
            const float mn = fmaxf(m, mx);
            const float f = exp2f(m - mn);
            m = mn;
            l *= f;
            float fq[4];
#pragma unroll
            for (int r = 0; r < 4; ++r) fq[r] = __shfl(f, g * 4 + r);
#pragma unroll
            for (int jd = 0; jd < 4; ++jd)
#pragma unroll
                for (int r = 0; r < 4; ++r) oacc[jd][r] *= fq[r];
        }

        // ---- P = exp2(S - m); l from raw values; pack to bf16 ----
        uint32_t wpk[4][2];
        float psum = 0.0f;
#pragma unroll
        for (int j = 0; j < 4; ++j) {
            const float p0 = exp2f(sacc[j][0] - m);
            const float p1 = exp2f(sacc[j][1] - m);
            const float p2 = exp2f(sacc[j][2] - m);
            const float p3 = exp2f(sacc[j][3] - m);
            psum += (p0 + p1) + (p2 + p3);
            wpk[j][0] = cvt_pk_bf16(p0, p1);
            wpk[j][1] = cvt_pk_bf16(p2, p3);
        }
        psum += __shfl_xor(psum, 16);
        psum += __shfl_xor(psum, 32);
        l += psum;

        // write packed P to wave-private LDS: row q=lr, s = j*16+g*4+{0..3}
#pragma unroll
        for (int j = 0; j < 4; ++j) {
            const int sloc = (j * 16 + g * 4) ^ swz;
            *reinterpret_cast<uint2*>(&sP[lr * 64 + sloc]) =
                make_uint2(wpk[j][0], wpk[j][1]);
        }
        asm volatile("s_waitcnt lgkmcnt(0)" ::: "memory");
        __builtin_amdgcn_sched_barrier(0);

        // ---- PV, 1-pass: A=P (row q=lr), B=V_hi ----
        bf16x8 pf[2];
#pragma unroll
        for (int kk = 0; kk < 2; ++kk)
            pf[kk] = *reinterpret_cast<const bf16x8*>(
                &sP[lr * 64 + ((kk * 32 + g * 8) ^ swz)]);
        __builtin_amdgcn_s_setprio(1);
#pragma unroll
        for (int jd = 0; jd < 4; ++jd) {
            const int vr = jd * 16 + lr;
#pragma unroll
            for (int kk = 0; kk < 2; ++kk) {
                const bf16x8 vh = *reinterpret_cast<const bf16x8*>(
                    &sV[bi][vr * 64 + ((kk * 32 + g * 8) ^ swz)]);
                oacc[jd] = __builtin_amdgcn_mfma_f32_16x16x32_bf16(
                    pf[kk], vh, oacc[jd], 0, 0, 0);
            }
        }
        __builtin_amdgcn_s_setprio(0);
        __syncthreads();  // drains next tile's loads; protects dbuf reuse
    }

    // ---- epilogue: split to bf16 hi/lo in O-proj A layout ----
    const int b = bh >> 4, h = bh & 15;
    float linv[4];
#pragma unroll
    for (int r = 0; r < 4; ++r) linv[r] = 1.0f / __shfl(l, g * 4 + r);
#pragma unroll
    for (int r = 0; r < 4; ++r) {
        const int q = t0 + w * 16 + g * 4 + r;
        const size_t rowb = ((size_t)(b * T + q)) * 1024 + h * 64;
#pragma unroll
        for (int jd = 0; jd < 4; ++jd) {
            const float v = oacc[jd][r] * linv[r];
            const ushort hv = f2bf(v);
            Ohi[rowb + jd * 16 + lr] = hv;
            Olo[rowb + jd * 16 + lr] = f2bf(v - bf2f(hv));
        }
    }
}

// ---------------------------------------------------------------------------
extern "C" void kernel_launch(void* const* d_in, const int* in_sizes, int n_in,
                              void* d_out, int out_size, void* d_ws, size_t ws_size,
                              hipStream_t stream) {
    const int B = 4, T = 1024, S = 2048, D = 1024;

    const float* query = (const float*)d_in[0];
    const float* keyv  = (const float*)d_in[1];
    const float* wq    = (const float*)d_in[2];
    const float* wk    = (const float*)d_in[3];
    const float* wv    = (const float*)d_in[4];
    const float* wo    = (const float*)d_in[5];
    float* out = (float*)d_out;

    const size_t nQ = (size_t)B * T * D;  // 4M
    const size_t nK = (size_t)B * S * D;  // 8M
    const size_t nW = (size_t)D * D;      // 1M

    uint8_t* p = (uint8_t*)d_ws;
    ushort* inq_h = (ushort*)p;  p += nQ * 2;
    ushort* inq_l = (ushort*)p;  p += nQ * 2;   // 16 MB
    ushort* inkv_h = (ushort*)p; p += nK * 2;
    ushort* inkv_l = (ushort*)p; p += nK * 2;   // 32 MB
    ushort* whi[4]; ushort* wlo[4];
    for (int i = 0; i < 4; ++i) {
        whi[i] = (ushort*)p; p += nW * 2;
        wlo[i] = (ushort*)p; p += nW * 2;       // 16 MB
    }
    ushort* aq_h = (ushort*)p;  p += nQ * 2;
    ushort* aq_l = (ushort*)p;  p += nQ * 2;    // 16 MB
    ushort* ak_h = (ushort*)p;  p += nK * 2;    // 16 MB (hi only)
    ushort* avt_h = (ushort*)p; p += nK * 2;    // 16 MB (hi only)
    ushort* ao_h = (ushort*)p;  p += nQ * 2;
    ushort* ao_l = (ushort*)p;  p += nQ * 2;    // 16 MB
    // total 128 MB

    const dim3 blk(256);
    const float QSCALE = 0.18033688011112042f;  // 0.125 * log2(e)

    // input/weight splits
    split_bf16_kernel<<<2048, blk, 0, stream>>>(query, inq_h, inq_l, (int)(nQ / 4));
    split_bf16_kernel<<<2048, blk, 0, stream>>>(keyv, inkv_h, inkv_l, (int)(nK / 4));
    split4_bf16_kernel<<<dim3(256, 4), blk, 0, stream>>>(
        wq, wk, wv, wo, whi[0], wlo[0], whi[1], wlo[1], whi[2], wlo[2],
        whi[3], wlo[3], (int)(nW / 4));

    // projections with fused attn-layout epilogues
    gemm_split<1><<<dim3(D / BN, (B * T) / BM), blk, 0, stream>>>(
        inq_h, inq_l, whi[0], wlo[0], nullptr, aq_h, aq_l, B * T, D, D, 10, QSCALE);
    gemm_split<3><<<dim3(D / BN, (B * S) / BM), blk, 0, stream>>>(
        inkv_h, inkv_l, whi[1], wlo[1], nullptr, ak_h, nullptr, B * S, D, D, 11, 1.0f);
    gemm_split<2><<<dim3(D / BN, (B * S) / BM), blk, 0, stream>>>(
        inkv_h, inkv_l, whi[2], wlo[2], nullptr, avt_h, nullptr, B * S, D, D, 11, 1.0f);

    // attention (1-D XCD-grouped grid; writes split hi/lo directly)
    attn_mfma<<<dim3((T / 64) * B * N_HEADS), blk, 0, stream>>>(
        aq_h, aq_l, ak_h, avt_h, ao_h, ao_l);

    // output projection
    gemm_split<0><<<dim3(D / BN, (B * T) / BM), blk, 0, stream>>>(
        ao_h, ao_l, whi[3], wlo[3], out, nullptr, nullptr, B * T, D, D, 10, 1.0f);
}

// Round 7
// 238.483 us; speedup vs baseline: 5.2132x; 1.2340x over previous
//
#include <hip/hip_runtime.h>
#include <cstdint>
#include <cstddef>

#define N_HEADS 16

typedef __attribute__((ext_vector_type(4))) float f32x4;
typedef __attribute__((ext_vector_type(8))) short bf16x8;

// ---------------------------------------------------------------------------
// fp32 -> (hi, lo) bf16 split helpers (RTN-even, no NaN inputs).
// ---------------------------------------------------------------------------
static __device__ inline ushort f2bf(float x) {
    uint32_t u = __float_as_uint(x);
    uint32_t r = (u + 0x7fffu + ((u >> 16) & 1u)) >> 16;
    return (ushort)r;
}
static __device__ inline float bf2f(ushort h) {
    return __uint_as_float(((uint32_t)h) << 16);
}
static __device__ inline uint32_t cvt_pk_bf16(float lo, float hi) {
    uint32_t r;
    asm("v_cvt_pk_bf16_f32 %0, %1, %2" : "=v"(r) : "v"(lo), "v"(hi));
    return r;
}

// hi-only split (for activations consumed by 1-/2-pass GEMMs).
__global__ __launch_bounds__(256) void split_hi_kernel(
    const float* __restrict__ x, ushort* __restrict__ hi, int n4) {
    const int stride = gridDim.x * blockDim.x;
    for (int i = blockIdx.x * blockDim.x + threadIdx.x; i < n4; i += stride) {
        const float4 v = reinterpret_cast<const float4*>(x)[i];
        ushort4 h;
        h.x = f2bf(v.x); h.y = f2bf(v.y); h.z = f2bf(v.z); h.w = f2bf(v.w);
        reinterpret_cast<ushort4*>(hi)[i] = h;
    }
}

// One launch for all 4 weight matrices (blockIdx.y selects; uniform branch).
__global__ __launch_bounds__(256) void split4_bf16_kernel(
    const float* __restrict__ w0, const float* __restrict__ w1,
    const float* __restrict__ w2, const float* __restrict__ w3,
    ushort* __restrict__ h0, ushort* __restrict__ l0,
    ushort* __restrict__ h1, ushort* __restrict__ l1,
    ushort* __restrict__ h2, ushort* __restrict__ l2,
    ushort* __restrict__ h3, ushort* __restrict__ l3, int n4) {
    const float* x;
    ushort *hi, *lo;
    if (blockIdx.y == 0)      { x = w0; hi = h0; lo = l0; }
    else if (blockIdx.y == 1) { x = w1; hi = h1; lo = l1; }
    else if (blockIdx.y == 2) { x = w2; hi = h2; lo = l2; }
    else                      { x = w3; hi = h3; lo = l3; }
    const int stride = gridDim.x * blockDim.x;
    for (int i = blockIdx.x * blockDim.x + threadIdx.x; i < n4; i += stride) {
        const float4 v = reinterpret_cast<const float4*>(x)[i];
        ushort4 h, l;
        h.x = f2bf(v.x); l.x = f2bf(v.x - bf2f(h.x));
        h.y = f2bf(v.y); l.y = f2bf(v.y - bf2f(h.y));
        h.z = f2bf(v.z); l.z = f2bf(v.z - bf2f(h.z));
        h.w = f2bf(v.w); l.w = f2bf(v.w - bf2f(h.w));
        reinterpret_cast<ushort4*>(hi)[i] = h;
        reinterpret_cast<ushort4*>(lo)[i] = l;
    }
}

// ---------------------------------------------------------------------------
// Split-bf16 MFMA GEMM: C = A[M,K] * W[N,K]^T with fused epilogues.
// PASSES: 3 = Ahi*Whi + Ahi*Wlo + Alo*Whi; 2 = Ahi*(Whi+Wlo); 1 = Ahi*Whi.
// MODE 0: plain fp32 C.
// MODE 1: hi+lo split to attn Q layout [bh][x][64], dd ^ ((x&7)<<3), scaled.
// MODE 2: hi-only split to attn V^T layout [bh][dd][2048], s-swizzled.
// MODE 3: hi-only split to attn K layout (same addressing as MODE 1).
// ---------------------------------------------------------------------------
#define BM 128
#define BN 128
#define BK 32

#define GLD_LDS16(gp, lp)                                                  \
    __builtin_amdgcn_global_load_lds(                                      \
        (const __attribute__((address_space(1))) void*)(gp),               \
        (__attribute__((address_space(3))) void*)(lp), 16, 0, 0)

template <int MODE, int PASSES>
__global__ __launch_bounds__(256, 2) void gemm_split(
    const ushort* __restrict__ Ahi, const ushort* __restrict__ Alo,
    const ushort* __restrict__ Whi, const ushort* __restrict__ Wlo,
    float* __restrict__ Cf, ushort* __restrict__ Chi,
    ushort* __restrict__ Clo, int M, int N, int K, int log2X, float scale) {
    constexpr int NA = (PASSES == 3) ? 2 : 1;
    constexpr int NB = (PASSES >= 2) ? 2 : 1;
    __shared__ ushort sA[NA][BM * BK];
    __shared__ ushort sB[NB][BN * BK];

    const int tid = threadIdx.x;
    const int lane = tid & 63;
    const int w = tid >> 6;
    const int m0 = blockIdx.y * BM;
    const int n0 = blockIdx.x * BN;
    const int wm = (w >> 1) * 64;
    const int wn = (w & 1) * 64;

    int srow[2], skq[2];
#pragma unroll
    for (int c = 0; c < 2; ++c) {
        const int row = (w * 2 + c) * 16 + (lane >> 2);
        srow[c] = row;
        skq[c] = (((lane & 3) ^ ((row >> 1) & 3)) << 3);
    }

    f32x4 acc[4][4];
#pragma unroll
    for (int i = 0; i < 4; ++i)
#pragma unroll
        for (int j = 0; j < 4; ++j) acc[i][j] = (f32x4)0.0f;

    const int lr = lane & 15;
    const int kq = lane >> 4;

    for (int k0 = 0; k0 < K; k0 += BK) {
#pragma unroll
        for (int c = 0; c < 2; ++c) {
            const size_t ga = (size_t)(m0 + srow[c]) * K + k0 + skq[c];
            const size_t gb = (size_t)(n0 + srow[c]) * K + k0 + skq[c];
            const int loff = (w * 2 + c) * 512;
            GLD_LDS16(Ahi + ga, &sA[0][loff]);
            if constexpr (PASSES == 3) GLD_LDS16(Alo + ga, &sA[NA - 1][loff]);
            GLD_LDS16(Whi + gb, &sB[0][loff]);
            if constexpr (PASSES >= 2) GLD_LDS16(Wlo + gb, &sB[NB - 1][loff]);
        }
        __syncthreads();

        bf16x8 afh[4], afl[4], bfh[4], bfl[4];
#pragma unroll
        for (int f = 0; f < 4; ++f) {
            const int arow = wm + f * 16 + lr;
            const int aoff = arow * 32 + ((kq ^ ((arow >> 1) & 3)) << 3);
            afh[f] = *reinterpret_cast<const bf16x8*>(&sA[0][aoff]);
            if constexpr (PASSES == 3)
                afl[f] = *reinterpret_cast<const bf16x8*>(&sA[NA - 1][aoff]);
            const int brow = wn + f * 16 + lr;
            const int boff = brow * 32 + ((kq ^ ((brow >> 1) & 3)) << 3);
            bfh[f] = *reinterpret_cast<const bf16x8*>(&sB[0][boff]);
            if constexpr (PASSES >= 2)
                bfl[f] = *reinterpret_cast<const bf16x8*>(&sB[NB - 1][boff]);
        }
#pragma unroll
        for (int i = 0; i < 4; ++i)
#pragma unroll
            for (int j = 0; j < 4; ++j) {
                acc[i][j] = __builtin_amdgcn_mfma_f32_16x16x32_bf16(
                    afh[i], bfh[j], acc[i][j], 0, 0, 0);
                if constexpr (PASSES >= 2)
                    acc[i][j] = __builtin_amdgcn_mfma_f32_16x16x32_bf16(
                        afh[i], bfl[j], acc[i][j], 0, 0, 0);
                if constexpr (PASSES == 3)
                    acc[i][j] = __builtin_amdgcn_mfma_f32_16x16x32_bf16(
                        afl[i], bfh[j], acc[i][j], 0, 0, 0);
            }
        __syncthreads();
    }

    const int cr = (lane >> 4) << 2;
    const int cc = lane & 15;

    if constexpr (MODE == 0) {
#pragma unroll
        for (int i = 0; i < 4; ++i)
#pragma unroll
            for (int j = 0; j < 4; ++j) {
                float* cp = &Cf[(size_t)(m0 + wm + i * 16 + cr) * N + n0 + wn +
                                j * 16 + cc];
#pragma unroll
                for (int r = 0; r < 4; ++r) cp[(size_t)r * N] = acc[i][j][r];
            }
    } else if constexpr (MODE == 1 || MODE == 3) {
        const int xm = (1 << log2X) - 1;
#pragma unroll
        for (int i = 0; i < 4; ++i)
#pragma unroll
            for (int j = 0; j < 4; ++j) {
                const int col = n0 + wn + j * 16 + cc;
                const int h = col >> 6, dd = col & 63;
#pragma unroll
                for (int r = 0; r < 4; ++r) {
                    const int mr = m0 + wm + i * 16 + cr + r;
                    const int bb = mr >> log2X;
                    const int x = mr & xm;
                    const float v = acc[i][j][r] * scale;
                    const ushort hv = f2bf(v);
                    const size_t pos =
                        (((size_t)(bb * N_HEADS + h) << log2X) + x) * 64 +
                        (dd ^ ((x & 7) << 3));
                    Chi[pos] = hv;
                    if constexpr (MODE == 1) Clo[pos] = f2bf(v - bf2f(hv));
                }
            }
    } else {  // MODE 2: V^T [bh][dd][2048], s swizzled within 64-blocks
#pragma unroll
        for (int i = 0; i < 4; ++i)
#pragma unroll
            for (int j = 0; j < 4; ++j) {
                const int col = n0 + wn + j * 16 + cc;
                const int h = col >> 6, dd = col & 63;
                const int sb = m0 + wm + i * 16 + cr;  // 4-aligned s base
                const int bb = sb >> 11;
                const int sx = sb & 2047;
                ushort4 hv;
#pragma unroll
                for (int r = 0; r < 4; ++r) ((ushort*)&hv)[r] = f2bf(acc[i][j][r]);
                const size_t pos =
                    ((size_t)(bb * N_HEADS + h) * 64 + dd) * 2048 +
                    (sx & ~63) + ((sx & 63) ^ ((dd & 7) << 3));
                *reinterpret_cast<ushort4*>(&Chi[pos]) = hv;
            }
    }
}

// ---------------------------------------------------------------------------
// MFMA flash attention (unchanged from round 6). Swapped QK^T, in-register
// softmax, defer-max, 2-phase K/V dbuf, K/V hi-only, 40 KB LDS -> 4
// blocks/CU, XCD-grouped 1-D grid.
// ---------------------------------------------------------------------------
__global__ __launch_bounds__(256, 4) void attn_mfma(
    const ushort* __restrict__ Qhi, const ushort* __restrict__ Qlo,
    const ushort* __restrict__ Khi, const ushort* __restrict__ Vhi,
    ushort* __restrict__ Ohi, ushort* __restrict__ Olo) {
    constexpr int T = 1024, S = 2048, NT = S / 64;
    __shared__ ushort sK[2][4096];  // [buf][s*64+dd]  (hi)
    __shared__ ushort sV[2][4096];  // [buf][dd*64+s]  (hi)
    __shared__ ushort sPb[4096];    // 4 x 2KB wave-private P buffers

    const int tid = threadIdx.x;
    const int lane = tid & 63;
    const int w = tid >> 6;
    const int id = blockIdx.x;
    const int wid = (id & 7) * 128 + (id >> 3);
    const int t0 = (wid & 15) * 64;
    const int bh = wid >> 4;
    const int lr = lane & 15;
    const int g = lane >> 4;
    const int swz = (lr & 7) << 3;

    const size_t qbase = ((size_t)bh * T + t0) * 64;
    const size_t kbase = (size_t)bh * S * 64;
    const size_t vbase = (size_t)bh * 64;

    auto stage_kv = [&](int bi, int s0) {
#pragma unroll
        for (int i = 0; i < 2; ++i) {
            const int off = i * 2048 + w * 512 + lane * 8;
            GLD_LDS16(Khi + kbase + (size_t)s0 * 64 + off, &sK[bi][off]);
            const int dd = off >> 6, sl = off & 63;
            GLD_LDS16(Vhi + (vbase + dd) * S + s0 + sl, &sV[bi][off]);
        }
    };

    // prologue: Q-hi -> sK[1], Q-lo -> sV[1]; first K/V tile -> buf 0
#pragma unroll
    for (int i = 0; i < 2; ++i) {
        const int off = i * 2048 + w * 512 + lane * 8;
        GLD_LDS16(Qhi + qbase + off, &sK[1][off]);
        GLD_LDS16(Qlo + qbase + off, &sV[1][off]);
    }
    stage_kv(0, 0);
    __syncthreads();

    bf16x8 qf[2][2];  // [hi/lo][kk]
    {
        const int qrow = w * 16 + lr;
#pragma unroll
        for (int kk = 0; kk < 2; ++kk) {
            const int off = qrow * 64 + ((kk * 32 + g * 8) ^ swz);
            qf[0][kk] = *reinterpret_cast<const bf16x8*>(&sK[1][off]);
            qf[1][kk] = *reinterpret_cast<const bf16x8*>(&sV[1][off]);
        }
    }
    __syncthreads();  // all Q reads done before buf1 gets overwritten

    ushort* sP = &sPb[w * 1024];  // wave-private

    f32x4 oacc[4];
#pragma unroll
    for (int jd = 0; jd < 4; ++jd) oacc[jd] = (f32x4)0.0f;
    float m = -1e30f, l = 0.0f;

    for (int t = 0; t < NT; ++t) {
        const int bi = t & 1;
        if (t + 1 < NT) stage_kv(bi ^ 1, (t + 1) * 64);

        // ---- QK^T swapped, 2-pass: k_hi·(q_hi + q_lo) ----
        f32x4 sacc[4];
        __builtin_amdgcn_s_setprio(1);
#pragma unroll
        for (int j = 0; j < 4; ++j) {
            sacc[j] = (f32x4)0.0f;
            const int krow = j * 16 + lr;
#pragma unroll
            for (int kk = 0; kk < 2; ++kk) {
                const int off = krow * 64 + ((kk * 32 + g * 8) ^ swz);
                const bf16x8 kh =
                    *reinterpret_cast<const bf16x8*>(&sK[bi][off]);
                sacc[j] = __builtin_amdgcn_mfma_f32_16x16x32_bf16(
                    kh, qf[0][kk], sacc[j], 0, 0, 0);
                sacc[j] = __builtin_amdgcn_mfma_f32_16x16x32_bf16(
                    kh, qf[1][kk], sacc[j], 0, 0, 0);
            }
        }
        __builtin_amdgcn_s_setprio(0);

        // ---- row max (q-row = lr) ----
        float mx = fmaxf(fmaxf(sacc[0][0], sacc[0][1]),
                         fmaxf(sacc[0][2], sacc[0][3]));
#pragma unroll
        for (int j = 1; j < 4; ++j)
            mx = fmaxf(mx, fmaxf(fmaxf(sacc[j][0], sacc[j][1]),
                                 fmaxf(sacc[j][2], sacc[j][3])));
        mx = fmaxf(mx, __shfl_xor(mx, 16));
        mx = fmaxf(mx, __shfl_xor(mx, 32));

        // ---- defer-max ----
        if (!__all(mx <= m + 8.0f)) {
            const float mn = fmaxf(m, mx);
            const float f = exp2f(m - mn);
            m = mn;
            l *= f;
            float fq[4];
#pragma unroll
            for (int r = 0; r < 4; ++r) fq[r] = __shfl(f, g * 4 + r);
#pragma unroll
            for (int jd = 0; jd < 4; ++jd)
#pragma unroll
                for (int r = 0; r < 4; ++r) oacc[jd][r] *= fq[r];
        }

        // ---- P = exp2(S - m); l from raw values; pack to bf16 ----
        uint32_t wpk[4][2];
        float psum = 0.0f;
#pragma unroll
        for (int j = 0; j < 4; ++j) {
            const float p0 = exp2f(sacc[j][0] - m);
            const float p1 = exp2f(sacc[j][1] - m);
            const float p2 = exp2f(sacc[j][2] - m);
            const float p3 = exp2f(sacc[j][3] - m);
            psum += (p0 + p1) + (p2 + p3);
            wpk[j][0] = cvt_pk_bf16(p0, p1);
            wpk[j][1] = cvt_pk_bf16(p2, p3);
        }
        psum += __shfl_xor(psum, 16);
        psum += __shfl_xor(psum, 32);
        l += psum;

#pragma unroll
        for (int j = 0; j < 4; ++j) {
            const int sloc = (j * 16 + g * 4) ^ swz;
            *reinterpret_cast<uint2*>(&sP[lr * 64 + sloc]) =
                make_uint2(wpk[j][0], wpk[j][1]);
        }
        asm volatile("s_waitcnt lgkmcnt(0)" ::: "memory");
        __builtin_amdgcn_sched_barrier(0);

        // ---- PV, 1-pass ----
        bf16x8 pf[2];
#pragma unroll
        for (int kk = 0; kk < 2; ++kk)
            pf[kk] = *reinterpret_cast<const bf16x8*>(
                &sP[lr * 64 + ((kk * 32 + g * 8) ^ swz)]);
        __builtin_amdgcn_s_setprio(1);
#pragma unroll
        for (int jd = 0; jd < 4; ++jd) {
            const int vr = jd * 16 + lr;
#pragma unroll
            for (int kk = 0; kk < 2; ++kk) {
                const bf16x8 vh = *reinterpret_cast<const bf16x8*>(
                    &sV[bi][vr * 64 + ((kk * 32 + g * 8) ^ swz)]);
                oacc[jd] = __builtin_amdgcn_mfma_f32_16x16x32_bf16(
                    pf[kk], vh, oacc[jd], 0, 0, 0);
            }
        }
        __builtin_amdgcn_s_setprio(0);
        __syncthreads();
    }

    // ---- epilogue: split to bf16 hi/lo in O-proj A layout ----
    const int b = bh >> 4, h = bh & 15;
    float linv[4];
#pragma unroll
    for (int r = 0; r < 4; ++r) linv[r] = 1.0f / __shfl(l, g * 4 + r);
#pragma unroll
    for (int r = 0; r < 4; ++r) {
        const int q = t0 + w * 16 + g * 4 + r;
        const size_t rowb = ((size_t)(b * T + q)) * 1024 + h * 64;
#pragma unroll
        for (int jd = 0; jd < 4; ++jd) {
            const float v = oacc[jd][r] * linv[r];
            const ushort hv = f2bf(v);
            Ohi[rowb + jd * 16 + lr] = hv;
            Olo[rowb + jd * 16 + lr] = f2bf(v - bf2f(hv));
        }
    }
}

// ---------------------------------------------------------------------------
extern "C" void kernel_launch(void* const* d_in, const int* in_sizes, int n_in,
                              void* d_out, int out_size, void* d_ws, size_t ws_size,
                              hipStream_t stream) {
    const int B = 4, T = 1024, S = 2048, D = 1024;

    const float* query = (const float*)d_in[0];
    const float* keyv  = (const float*)d_in[1];
    const float* wq    = (const float*)d_in[2];
    const float* wk    = (const float*)d_in[3];
    const float* wv    = (const float*)d_in[4];
    const float* wo    = (const float*)d_in[5];
    float* out = (float*)d_out;

    const size_t nQ = (size_t)B * T * D;  // 4M
    const size_t nK = (size_t)B * S * D;  // 8M
    const size_t nW = (size_t)D * D;      // 1M

    uint8_t* p = (uint8_t*)d_ws;
    ushort* inq_h = (ushort*)p;  p += nQ * 2;   // 8 MB
    ushort* inkv_h = (ushort*)p; p += nK * 2;   // 16 MB
    ushort* whi[4]; ushort* wlo[4];
    for (int i = 0; i < 4; ++i) {
        whi[i] = (ushort*)p; p += nW * 2;
        wlo[i] = (ushort*)p; p += nW * 2;       // 16 MB
    }
    ushort* aq_h = (ushort*)p;  p += nQ * 2;
    ushort* aq_l = (ushort*)p;  p += nQ * 2;    // 16 MB
    ushort* ak_h = (ushort*)p;  p += nK * 2;    // 16 MB (hi only)
    ushort* avt_h = (ushort*)p; p += nK * 2;    // 16 MB (hi only)
    ushort* ao_h = (ushort*)p;  p += nQ * 2;
    ushort* ao_l = (ushort*)p;  p += nQ * 2;    // 16 MB
    // total 104 MB

    const dim3 blk(256);
    const float QSCALE = 0.18033688011112042f;  // 0.125 * log2(e)

    // input splits (hi only) + weight splits (hi+lo)
    split_hi_kernel<<<2048, blk, 0, stream>>>(query, inq_h, (int)(nQ / 4));
    split_hi_kernel<<<2048, blk, 0, stream>>>(keyv, inkv_h, (int)(nK / 4));
    split4_bf16_kernel<<<dim3(256, 4), blk, 0, stream>>>(
        wq, wk, wv, wo, whi[0], wlo[0], whi[1], wlo[1], whi[2], wlo[2],
        whi[3], wlo[3], (int)(nW / 4));

    // projections with fused attn-layout epilogues
    gemm_split<1, 2><<<dim3(D / BN, (B * T) / BM), blk, 0, stream>>>(
        inq_h, nullptr, whi[0], wlo[0], nullptr, aq_h, aq_l, B * T, D, D, 10, QSCALE);
    gemm_split<3, 1><<<dim3(D / BN, (B * S) / BM), blk, 0, stream>>>(
        inkv_h, nullptr, whi[1], nullptr, nullptr, ak_h, nullptr, B * S, D, D, 11, 1.0f);
    gemm_split<2, 1><<<dim3(D / BN, (B * S) / BM), blk, 0, stream>>>(
        inkv_h, nullptr, whi[2], nullptr, nullptr, avt_h, nullptr, B * S, D, D, 11, 1.0f);

    // attention (1-D XCD-grouped grid; writes split hi/lo directly)
    attn_mfma<<<dim3((T / 64) * B * N_HEADS), blk, 0, stream>>>(
        aq_h, aq_l, ak_h, avt_h, ao_h, ao_l);

    // output projection (full 3-pass: final output is directly thresholded)
    gemm_split<0, 3><<<dim3(D / BN, (B * T) / BM), blk, 0, stream>>>(
        ao_h, ao_l, whi[3], wlo[3], out, nullptr, nullptr, B * T, D, D, 10, 1.0f);
}

// Round 8
// 192.205 us; speedup vs baseline: 6.4683x; 1.2408x over previous
//
#include <hip/hip_runtime.h>
#include <cstdint>
#include <cstddef>

#define N_HEADS 16

typedef __attribute__((ext_vector_type(4))) float f32x4;
typedef __attribute__((ext_vector_type(8))) short bf16x8;

// ---------------------------------------------------------------------------
// fp32 -> (hi, lo) bf16 split helpers (RTN-even, no NaN inputs).
// ---------------------------------------------------------------------------
static __device__ inline ushort f2bf(float x) {
    uint32_t u = __float_as_uint(x);
    uint32_t r = (u + 0x7fffu + ((u >> 16) & 1u)) >> 16;
    return (ushort)r;
}
static __device__ inline float bf2f(ushort h) {
    return __uint_as_float(((uint32_t)h) << 16);
}
static __device__ inline uint32_t cvt_pk_bf16(float lo, float hi) {
    uint32_t r;
    asm("v_cvt_pk_bf16_f32 %0, %1, %2" : "=v"(r) : "v"(lo), "v"(hi));
    return r;
}

// ---------------------------------------------------------------------------
// One launch for ALL splits. blockIdx.y segments:
// 0: query -> hi              1: keyv -> hi
// 2: wq -> hi+lo   3: wk -> hi   4: wv -> hi   5: wo -> hi+lo
// ---------------------------------------------------------------------------
__global__ __launch_bounds__(256) void split_all(
    const float* __restrict__ query, const float* __restrict__ keyv,
    const float* __restrict__ wq, const float* __restrict__ wk,
    const float* __restrict__ wv, const float* __restrict__ wo,
    ushort* __restrict__ inq_h, ushort* __restrict__ inkv_h,
    ushort* __restrict__ wqh, ushort* __restrict__ wql,
    ushort* __restrict__ wkh, ushort* __restrict__ wvh,
    ushort* __restrict__ woh, ushort* __restrict__ wol) {
    const float* x;
    ushort* hi;
    ushort* lo = nullptr;
    int n4;
    switch (blockIdx.y) {
        case 0: x = query; hi = inq_h;            n4 = 1048576; break;
        case 1: x = keyv;  hi = inkv_h;           n4 = 2097152; break;
        case 2: x = wq;    hi = wqh;  lo = wql;   n4 = 262144;  break;
        case 3: x = wk;    hi = wkh;              n4 = 262144;  break;
        case 4: x = wv;    hi = wvh;              n4 = 262144;  break;
        default: x = wo;   hi = woh;  lo = wol;   n4 = 262144;  break;
    }
    const int stride = gridDim.x * blockDim.x;
    const bool wlo = (lo != nullptr);
    for (int i = blockIdx.x * blockDim.x + threadIdx.x; i < n4; i += stride) {
        const float4 v = reinterpret_cast<const float4*>(x)[i];
        ushort4 h;
        h.x = f2bf(v.x); h.y = f2bf(v.y); h.z = f2bf(v.z); h.w = f2bf(v.w);
        reinterpret_cast<ushort4*>(hi)[i] = h;
        if (wlo) {
            ushort4 l;
            l.x = f2bf(v.x - bf2f(h.x)); l.y = f2bf(v.y - bf2f(h.y));
            l.z = f2bf(v.z - bf2f(h.z)); l.w = f2bf(v.w - bf2f(h.w));
            reinterpret_cast<ushort4*>(lo)[i] = l;
        }
    }
}

#define BM 128
#define BN 128
#define BK 32

#define GLD_LDS16(gp, lp)                                                  \
    __builtin_amdgcn_global_load_lds(                                      \
        (const __attribute__((address_space(1))) void*)(gp),               \
        (__attribute__((address_space(3))) void*)(lp), 16, 0, 0)

// ---------------------------------------------------------------------------
// Batched Q/K/V projection, single launch (1280 blocks):
//   [0,256)   seg 0: Q = inq_h  @ wq^T, 2-pass (hi*(Whi+Wlo)), scaled,
//                    -> attn Q layout [bh][x][64] hi-only, x-swizzled
//   [256,768) seg 1: K = inkv_h @ wk^T, 1-pass -> attn K layout
//   [768,1280)seg 2: V = inkv_h @ wv^T, 1-pass -> attn V^T layout [bh][dd][S]
// Per-segment bijective XCD-grouping for A-panel L2 residency.
// ---------------------------------------------------------------------------
__global__ __launch_bounds__(256, 2) void qkv_proj(
    const ushort* __restrict__ Aq, const ushort* __restrict__ Akv,
    const ushort* __restrict__ Wqh, const ushort* __restrict__ Wql,
    const ushort* __restrict__ Wkh, const ushort* __restrict__ Wvh,
    ushort* __restrict__ aq, ushort* __restrict__ ak,
    ushort* __restrict__ avt) {
    constexpr int K = 1024;
    constexpr float QSCALE = 0.18033688011112042f;  // 0.125 * log2(e)
    __shared__ ushort sA[BM * BK];
    __shared__ ushort sB[2][BN * BK];

    const int bid = blockIdx.x;
    int seg, local, nrow;
    if (bid < 256)      { seg = 0; local = bid;       nrow = 32; }
    else if (bid < 768) { seg = 1; local = bid - 256; nrow = 64; }
    else                { seg = 2; local = bid - 768; nrow = 64; }
    // XCD-grouped bijection within segment (segment size % 8 == 0).
    local = (local & 7) * nrow + (local >> 3);
    const int n0 = (local & 7) * BN;
    const int m0 = (local >> 3) * BM;

    const ushort* A  = (seg == 0) ? Aq : Akv;
    const ushort* Wh = (seg == 0) ? Wqh : (seg == 1 ? Wkh : Wvh);
    const bool twopass = (seg == 0);

    const int tid = threadIdx.x;
    const int lane = tid & 63;
    const int w = tid >> 6;
    const int wm = (w >> 1) * 64;
    const int wn = (w & 1) * 64;

    int srow[2], skq[2];
#pragma unroll
    for (int c = 0; c < 2; ++c) {
        const int row = (w * 2 + c) * 16 + (lane >> 2);
        srow[c] = row;
        skq[c] = (((lane & 3) ^ ((row >> 1) & 3)) << 3);
    }

    f32x4 acc[4][4];
#pragma unroll
    for (int i = 0; i < 4; ++i)
#pragma unroll
        for (int j = 0; j < 4; ++j) acc[i][j] = (f32x4)0.0f;

    const int lr = lane & 15;
    const int kq = lane >> 4;

    for (int k0 = 0; k0 < K; k0 += BK) {
#pragma unroll
        for (int c = 0; c < 2; ++c) {
            const size_t ga = (size_t)(m0 + srow[c]) * K + k0 + skq[c];
            const size_t gb = (size_t)(n0 + srow[c]) * K + k0 + skq[c];
            const int loff = (w * 2 + c) * 512;
            GLD_LDS16(A + ga, &sA[loff]);
            GLD_LDS16(Wh + gb, &sB[0][loff]);
            if (twopass) GLD_LDS16(Wql + gb, &sB[1][loff]);
        }
        __syncthreads();

        bf16x8 afh[4], bfh[4], bfl[4];
#pragma unroll
        for (int f = 0; f < 4; ++f) {
            const int arow = wm + f * 16 + lr;
            afh[f] = *reinterpret_cast<const bf16x8*>(
                &sA[arow * 32 + ((kq ^ ((arow >> 1) & 3)) << 3)]);
            const int brow = wn + f * 16 + lr;
            const int boff = brow * 32 + ((kq ^ ((brow >> 1) & 3)) << 3);
            bfh[f] = *reinterpret_cast<const bf16x8*>(&sB[0][boff]);
            if (twopass)
                bfl[f] = *reinterpret_cast<const bf16x8*>(&sB[1][boff]);
        }
#pragma unroll
        for (int i = 0; i < 4; ++i)
#pragma unroll
            for (int j = 0; j < 4; ++j)
                acc[i][j] = __builtin_amdgcn_mfma_f32_16x16x32_bf16(
                    afh[i], bfh[j], acc[i][j], 0, 0, 0);
        if (twopass) {
#pragma unroll
            for (int i = 0; i < 4; ++i)
#pragma unroll
                for (int j = 0; j < 4; ++j)
                    acc[i][j] = __builtin_amdgcn_mfma_f32_16x16x32_bf16(
                        afh[i], bfl[j], acc[i][j], 0, 0, 0);
        }
        __syncthreads();
    }

    const int cr = (lane >> 4) << 2;
    const int cc = lane & 15;

    if (seg < 2) {  // Q / K layout: [bh][x][64] hi-only, dd ^ ((x&7)<<3)
        const int log2X = (seg == 0) ? 10 : 11;
        const float scale = (seg == 0) ? QSCALE : 1.0f;
        ushort* out = (seg == 0) ? aq : ak;
        const int xm = (1 << log2X) - 1;
#pragma unroll
        for (int i = 0; i < 4; ++i)
#pragma unroll
            for (int j = 0; j < 4; ++j) {
                const int col = n0 + wn + j * 16 + cc;
                const int h = col >> 6, dd = col & 63;
#pragma unroll
                for (int r = 0; r < 4; ++r) {
                    const int mr = m0 + wm + i * 16 + cr + r;
                    const int bb = mr >> log2X;
                    const int x = mr & xm;
                    out[(((size_t)(bb * N_HEADS + h) << log2X) + x) * 64 +
                        (dd ^ ((x & 7) << 3))] = f2bf(acc[i][j][r] * scale);
                }
            }
    } else {  // V^T layout: [bh][dd][2048], s swizzled within 64-blocks
#pragma unroll
        for (int i = 0; i < 4; ++i)
#pragma unroll
            for (int j = 0; j < 4; ++j) {
                const int col = n0 + wn + j * 16 + cc;
                const int h = col >> 6, dd = col & 63;
                const int sb = m0 + wm + i * 16 + cr;
                const int bb = sb >> 11;
                const int sx = sb & 2047;
                ushort4 hv;
#pragma unroll
                for (int r = 0; r < 4; ++r)
                    ((ushort*)&hv)[r] = f2bf(acc[i][j][r]);
                const size_t pos =
                    ((size_t)(bb * N_HEADS + h) * 64 + dd) * 2048 +
                    (sx & ~63) + ((sx & 63) ^ ((dd & 7) << 3));
                *reinterpret_cast<ushort4*>(&avt[pos]) = hv;
            }
    }
}

// ---------------------------------------------------------------------------
// O-projection GEMM: out = AO[M,K] * wo[N,K]^T, 3-pass split (full fp32
// fidelity — the output is directly thresholded). Same m97 structure.
// ---------------------------------------------------------------------------
__global__ __launch_bounds__(256, 2) void gemm_oproj(
    const ushort* __restrict__ Ahi, const ushort* __restrict__ Alo,
    const ushort* __restrict__ Whi, const ushort* __restrict__ Wlo,
    float* __restrict__ Cf, int M, int N, int K) {
    __shared__ ushort sA[2][BM * BK];
    __shared__ ushort sB[2][BN * BK];

    const int tid = threadIdx.x;
    const int lane = tid & 63;
    const int w = tid >> 6;
    const int m0 = blockIdx.y * BM;
    const int n0 = blockIdx.x * BN;
    const int wm = (w >> 1) * 64;
    const int wn = (w & 1) * 64;

    int srow[2], skq[2];
#pragma unroll
    for (int c = 0; c < 2; ++c) {
        const int row = (w * 2 + c) * 16 + (lane >> 2);
        srow[c] = row;
        skq[c] = (((lane & 3) ^ ((row >> 1) & 3)) << 3);
    }

    f32x4 acc[4][4];
#pragma unroll
    for (int i = 0; i < 4; ++i)
#pragma unroll
        for (int j = 0; j < 4; ++j) acc[i][j] = (f32x4)0.0f;

    const int lr = lane & 15;
    const int kq = lane >> 4;

    for (int k0 = 0; k0 < K; k0 += BK) {
#pragma unroll
        for (int c = 0; c < 2; ++c) {
            const size_t ga = (size_t)(m0 + srow[c]) * K + k0 + skq[c];
            const size_t gb = (size_t)(n0 + srow[c]) * K + k0 + skq[c];
            const int loff = (w * 2 + c) * 512;
            GLD_LDS16(Ahi + ga, &sA[0][loff]);
            GLD_LDS16(Alo + ga, &sA[1][loff]);
            GLD_LDS16(Whi + gb, &sB[0][loff]);
            GLD_LDS16(Wlo + gb, &sB[1][loff]);
        }
        __syncthreads();

        bf16x8 afh[4], afl[4], bfh[4], bfl[4];
#pragma unroll
        for (int f = 0; f < 4; ++f) {
            const int arow = wm + f * 16 + lr;
            const int aoff = arow * 32 + ((kq ^ ((arow >> 1) & 3)) << 3);
            afh[f] = *reinterpret_cast<const bf16x8*>(&sA[0][aoff]);
            afl[f] = *reinterpret_cast<const bf16x8*>(&sA[1][aoff]);
            const int brow = wn + f * 16 + lr;
            const int boff = brow * 32 + ((kq ^ ((brow >> 1) & 3)) << 3);
            bfh[f] = *reinterpret_cast<const bf16x8*>(&sB[0][boff]);
            bfl[f] = *reinterpret_cast<const bf16x8*>(&sB[1][boff]);
        }
#pragma unroll
        for (int i = 0; i < 4; ++i)
#pragma unroll
            for (int j = 0; j < 4; ++j) {
                acc[i][j] = __builtin_amdgcn_mfma_f32_16x16x32_bf16(
                    afh[i], bfh[j], acc[i][j], 0, 0, 0);
                acc[i][j] = __builtin_amdgcn_mfma_f32_16x16x32_bf16(
                    afh[i], bfl[j], acc[i][j], 0, 0, 0);
                acc[i][j] = __builtin_amdgcn_mfma_f32_16x16x32_bf16(
                    afl[i], bfh[j], acc[i][j], 0, 0, 0);
            }
        __syncthreads();
    }

    const int cr = (lane >> 4) << 2;
    const int cc = lane & 15;
#pragma unroll
    for (int i = 0; i < 4; ++i)
#pragma unroll
        for (int j = 0; j < 4; ++j) {
            float* cp = &Cf[(size_t)(m0 + wm + i * 16 + cr) * N + n0 + wn +
                            j * 16 + cc];
#pragma unroll
            for (int r = 0; r < 4; ++r) cp[(size_t)r * N] = acc[i][j][r];
        }
}

// ---------------------------------------------------------------------------
// MFMA flash attention. Swapped QK^T (now 1-pass: k_hi * q_hi), in-register
// softmax, defer-max, 2-phase K/V dbuf, 40 KB LDS -> 4 blocks/CU,
// XCD-grouped 1-D grid. Output: bf16 hi/lo split in O-proj A layout.
// ---------------------------------------------------------------------------
__global__ __launch_bounds__(256, 4) void attn_mfma(
    const ushort* __restrict__ Qhi, const ushort* __restrict__ Khi,
    const ushort* __restrict__ Vhi, ushort* __restrict__ Ohi,
    ushort* __restrict__ Olo) {
    constexpr int T = 1024, S = 2048, NT = S / 64;
    __shared__ ushort sK[2][4096];  // [buf][s*64+dd]  (hi)
    __shared__ ushort sV[2][4096];  // [buf][dd*64+s]  (hi)
    __shared__ ushort sPb[4096];    // 4 x 2KB wave-private P buffers

    const int tid = threadIdx.x;
    const int lane = tid & 63;
    const int w = tid >> 6;
    const int id = blockIdx.x;
    const int wid = (id & 7) * 128 + (id >> 3);
    const int t0 = (wid & 15) * 64;
    const int bh = wid >> 4;
    const int lr = lane & 15;
    const int g = lane >> 4;
    const int swz = (lr & 7) << 3;

    const size_t qbase = ((size_t)bh * T + t0) * 64;
    const size_t kbase = (size_t)bh * S * 64;
    const size_t vbase = (size_t)bh * 64;

    auto stage_kv = [&](int bi, int s0) {
#pragma unroll
        for (int i = 0; i < 2; ++i) {
            const int off = i * 2048 + w * 512 + lane * 8;
            GLD_LDS16(Khi + kbase + (size_t)s0 * 64 + off, &sK[bi][off]);
            const int dd = off >> 6, sl = off & 63;
            GLD_LDS16(Vhi + (vbase + dd) * S + s0 + sl, &sV[bi][off]);
        }
    };

    // prologue: Q-hi -> sK[1]; first K/V tile -> buf 0
#pragma unroll
    for (int i = 0; i < 2; ++i) {
        const int off = i * 2048 + w * 512 + lane * 8;
        GLD_LDS16(Qhi + qbase + off, &sK[1][off]);
    }
    stage_kv(0, 0);
    __syncthreads();

    bf16x8 qf[2];  // [kk]
    {
        const int qrow = w * 16 + lr;
#pragma unroll
        for (int kk = 0; kk < 2; ++kk)
            qf[kk] = *reinterpret_cast<const bf16x8*>(
                &sK[1][qrow * 64 + ((kk * 32 + g * 8) ^ swz)]);
    }
    __syncthreads();  // all Q reads done before buf1 gets overwritten

    ushort* sP = &sPb[w * 1024];  // wave-private

    f32x4 oacc[4];
#pragma unroll
    for (int jd = 0; jd < 4; ++jd) oacc[jd] = (f32x4)0.0f;
    float m = -1e30f, l = 0.0f;

    for (int t = 0; t < NT; ++t) {
        const int bi = t & 1;
        if (t + 1 < NT) stage_kv(bi ^ 1, (t + 1) * 64);

        // ---- QK^T swapped, 1-pass: k_hi * q_hi ----
        f32x4 sacc[4];
        __builtin_amdgcn_s_setprio(1);
#pragma unroll
        for (int j = 0; j < 4; ++j) {
            sacc[j] = (f32x4)0.0f;
            const int krow = j * 16 + lr;
#pragma unroll
            for (int kk = 0; kk < 2; ++kk) {
                const bf16x8 kh = *reinterpret_cast<const bf16x8*>(
                    &sK[bi][krow * 64 + ((kk * 32 + g * 8) ^ swz)]);
                sacc[j] = __builtin_amdgcn_mfma_f32_16x16x32_bf16(
                    kh, qf[kk], sacc[j], 0, 0, 0);
            }
        }
        __builtin_amdgcn_s_setprio(0);

        // ---- row max (q-row = lr) ----
        float mx = fmaxf(fmaxf(sacc[0][0], sacc[0][1]),
                         fmaxf(sacc[0][2], sacc[0][3]));
#pragma unroll
        for (int j = 1; j < 4; ++j)
            mx = fmaxf(mx, fmaxf(fmaxf(sacc[j][0], sacc[j][1]),
                                 fmaxf(sacc[j][2], sacc[j][3])));
        mx = fmaxf(mx, __shfl_xor(mx, 16));
        mx = fmaxf(mx, __shfl_xor(mx, 32));

        // ---- defer-max ----
        if (!__all(mx <= m + 8.0f)) {
            const float mn = fmaxf(m, mx);
            const float f = exp2f(m - mn);
            m = mn;
            l *= f;
            float fq[4];
#pragma unroll
            for (int r = 0; r < 4; ++r) fq[r] = __shfl(f, g * 4 + r);
#pragma unroll
            for (int jd = 0; jd < 4; ++jd)
#pragma unroll
                for (int r = 0; r < 4; ++r) oacc[jd][r] *= fq[r];
        }

        // ---- P = exp2(S - m); l from raw values; pack to bf16 ----
        uint32_t wpk[4][2];
        float psum = 0.0f;
#pragma unroll
        for (int j = 0; j < 4; ++j) {
            const float p0 = exp2f(sacc[j][0] - m);
            const float p1 = exp2f(sacc[j][1] - m);
            const float p2 = exp2f(sacc[j][2] - m);
            const float p3 = exp2f(sacc[j][3] - m);
            psum += (p0 + p1) + (p2 + p3);
            wpk[j][0] = cvt_pk_bf16(p0, p1);
            wpk[j][1] = cvt_pk_bf16(p2, p3);
        }
        psum += __shfl_xor(psum, 16);
        psum += __shfl_xor(psum, 32);
        l += psum;

#pragma unroll
        for (int j = 0; j < 4; ++j) {
            const int sloc = (j * 16 + g * 4) ^ swz;
            *reinterpret_cast<uint2*>(&sP[lr * 64 + sloc]) =
                make_uint2(wpk[j][0], wpk[j][1]);
        }
        asm volatile("s_waitcnt lgkmcnt(0)" ::: "memory");
        __builtin_amdgcn_sched_barrier(0);

        // ---- PV, 1-pass ----
        bf16x8 pf[2];
#pragma unroll
        for (int kk = 0; kk < 2; ++kk)
            pf[kk] = *reinterpret_cast<const bf16x8*>(
                &sP[lr * 64 + ((kk * 32 + g * 8) ^ swz)]);
        __builtin_amdgcn_s_setprio(1);
#pragma unroll
        for (int jd = 0; jd < 4; ++jd) {
            const int vr = jd * 16 + lr;
#pragma unroll
            for (int kk = 0; kk < 2; ++kk) {
                const bf16x8 vh = *reinterpret_cast<const bf16x8*>(
                    &sV[bi][vr * 64 + ((kk * 32 + g * 8) ^ swz)]);
                oacc[jd] = __builtin_amdgcn_mfma_f32_16x16x32_bf16(
                    pf[kk], vh, oacc[jd], 0, 0, 0);
            }
        }
        __builtin_amdgcn_s_setprio(0);
        __syncthreads();
    }

    // ---- epilogue: split to bf16 hi/lo in O-proj A layout ----
    const int b = bh >> 4, h = bh & 15;
    float linv[4];
#pragma unroll
    for (int r = 0; r < 4; ++r) linv[r] = 1.0f / __shfl(l, g * 4 + r);
#pragma unroll
    for (int r = 0; r < 4; ++r) {
        const int q = t0 + w * 16 + g * 4 + r;
        const size_t rowb = ((size_t)(b * T + q)) * 1024 + h * 64;
#pragma unroll
        for (int jd = 0; jd < 4; ++jd) {
            const float v = oacc[jd][r] * linv[r];
            const ushort hv = f2bf(v);
            Ohi[rowb + jd * 16 + lr] = hv;
            Olo[rowb + jd * 16 + lr] = f2bf(v - bf2f(hv));
        }
    }
}

// ---------------------------------------------------------------------------
extern "C" void kernel_launch(void* const* d_in, const int* in_sizes, int n_in,
                              void* d_out, int out_size, void* d_ws, size_t ws_size,
                              hipStream_t stream) {
    const int B = 4, T = 1024, S = 2048, D = 1024;

    const float* query = (const float*)d_in[0];
    const float* keyv  = (const float*)d_in[1];
    const float* wq    = (const float*)d_in[2];
    const float* wk    = (const float*)d_in[3];
    const float* wv    = (const float*)d_in[4];
    const float* wo    = (const float*)d_in[5];
    float* out = (float*)d_out;

    const size_t nQ = (size_t)B * T * D;  // 4M
    const size_t nK = (size_t)B * S * D;  // 8M
    const size_t nW = (size_t)D * D;      // 1M

    uint8_t* p = (uint8_t*)d_ws;
    ushort* inq_h = (ushort*)p;  p += nQ * 2;   // 8 MB
    ushort* inkv_h = (ushort*)p; p += nK * 2;   // 16 MB
    ushort* wqh = (ushort*)p;    p += nW * 2;
    ushort* wql = (ushort*)p;    p += nW * 2;
    ushort* wkh = (ushort*)p;    p += nW * 2;
    ushort* wvh = (ushort*)p;    p += nW * 2;
    ushort* woh = (ushort*)p;    p += nW * 2;
    ushort* wol = (ushort*)p;    p += nW * 2;   // 12 MB
    ushort* aq_h = (ushort*)p;   p += nQ * 2;   // 8 MB (hi only)
    ushort* ak_h = (ushort*)p;   p += nK * 2;   // 16 MB (hi only)
    ushort* avt_h = (ushort*)p;  p += nK * 2;   // 16 MB (hi only)
    ushort* ao_h = (ushort*)p;   p += nQ * 2;
    ushort* ao_l = (ushort*)p;   p += nQ * 2;   // 16 MB
    // total 92 MB

    const dim3 blk(256);

    // 1) all input/weight splits, one launch
    split_all<<<dim3(512, 6), blk, 0, stream>>>(
        query, keyv, wq, wk, wv, wo, inq_h, inkv_h, wqh, wql, wkh, wvh, woh,
        wol);

    // 2) Q/K/V projections, one batched launch (fused attn-layout epilogues)
    qkv_proj<<<dim3(1280), blk, 0, stream>>>(inq_h, inkv_h, wqh, wql, wkh,
                                             wvh, aq_h, ak_h, avt_h);

    // 3) attention (1-D XCD-grouped grid; writes split hi/lo directly)
    attn_mfma<<<dim3((T / 64) * B * N_HEADS), blk, 0, stream>>>(
        aq_h, ak_h, avt_h, ao_h, ao_l);

    // 4) output projection (full 3-pass: output directly thresholded)
    gemm_oproj<<<dim3(D / BN, (B * T) / BM), blk, 0, stream>>>(
        ao_h, ao_l, woh, wol, out, B * T, D, D);
}

// Round 9
// 183.457 us; speedup vs baseline: 6.7768x; 1.0477x over previous
//
#include <hip/hip_runtime.h>
#include <cstdint>
#include <cstddef>

#define N_HEADS 16

typedef __attribute__((ext_vector_type(4))) float f32x4;
typedef __attribute__((ext_vector_type(8))) short bf16x8;

// ---------------------------------------------------------------------------
// fp32 -> (hi, lo) bf16 split helpers (RTN-even, no NaN inputs).
// ---------------------------------------------------------------------------
static __device__ inline ushort f2bf(float x) {
    uint32_t u = __float_as_uint(x);
    uint32_t r = (u + 0x7fffu + ((u >> 16) & 1u)) >> 16;
    return (ushort)r;
}
static __device__ inline float bf2f(ushort h) {
    return __uint_as_float(((uint32_t)h) << 16);
}
static __device__ inline uint32_t cvt_pk_bf16(float lo, float hi) {
    uint32_t r;
    asm("v_cvt_pk_bf16_f32 %0, %1, %2" : "=v"(r) : "v"(lo), "v"(hi));
    return r;
}

// ---------------------------------------------------------------------------
// One launch for ALL splits. blockIdx.y segments:
// 0: query -> hi              1: keyv -> hi
// 2: wq -> hi+lo   3: wk -> hi   4: wv -> hi   5: wo -> hi+lo
// ---------------------------------------------------------------------------
__global__ __launch_bounds__(256) void split_all(
    const float* __restrict__ query, const float* __restrict__ keyv,
    const float* __restrict__ wq, const float* __restrict__ wk,
    const float* __restrict__ wv, const float* __restrict__ wo,
    ushort* __restrict__ inq_h, ushort* __restrict__ inkv_h,
    ushort* __restrict__ wqh, ushort* __restrict__ wql,
    ushort* __restrict__ wkh, ushort* __restrict__ wvh,
    ushort* __restrict__ woh, ushort* __restrict__ wol) {
    const float* x;
    ushort* hi;
    ushort* lo = nullptr;
    int n4;
    switch (blockIdx.y) {
        case 0: x = query; hi = inq_h;            n4 = 1048576; break;
        case 1: x = keyv;  hi = inkv_h;           n4 = 2097152; break;
        case 2: x = wq;    hi = wqh;  lo = wql;   n4 = 262144;  break;
        case 3: x = wk;    hi = wkh;              n4 = 262144;  break;
        case 4: x = wv;    hi = wvh;              n4 = 262144;  break;
        default: x = wo;   hi = woh;  lo = wol;   n4 = 262144;  break;
    }
    const int stride = gridDim.x * blockDim.x;
    const bool wlo = (lo != nullptr);
    for (int i = blockIdx.x * blockDim.x + threadIdx.x; i < n4; i += stride) {
        const float4 v = reinterpret_cast<const float4*>(x)[i];
        ushort4 h;
        h.x = f2bf(v.x); h.y = f2bf(v.y); h.z = f2bf(v.z); h.w = f2bf(v.w);
        reinterpret_cast<ushort4*>(hi)[i] = h;
        if (wlo) {
            ushort4 l;
            l.x = f2bf(v.x - bf2f(h.x)); l.y = f2bf(v.y - bf2f(h.y));
            l.z = f2bf(v.z - bf2f(h.z)); l.w = f2bf(v.w - bf2f(h.w));
            reinterpret_cast<ushort4*>(lo)[i] = l;
        }
    }
}

#define BM 128
#define BN 128
#define BK 32

#define GLD_LDS16(gp, lp)                                                  \
    __builtin_amdgcn_global_load_lds(                                      \
        (const __attribute__((address_space(1))) void*)(gp),               \
        (__attribute__((address_space(3))) void*)(lp), 16, 0, 0)

// ---------------------------------------------------------------------------
// Batched Q/K/V projection, single launch (1280 blocks):
//   [0,256)   seg 0: Q = inq_h  @ wq^T, 2-pass (hi*(Whi+Wlo)), scaled,
//                    -> attn Q layout [bh][x][64] hi-only, x-swizzled
//   [256,768) seg 1: K = inkv_h @ wk^T, 1-pass -> attn K layout
//   [768,1280)seg 2: V = inkv_h @ wv^T, 1-pass -> attn V^T layout [bh][dd][S]
// Per-segment bijective XCD-grouping for A-panel L2 residency.
// ---------------------------------------------------------------------------
__global__ __launch_bounds__(256, 2) void qkv_proj(
    const ushort* __restrict__ Aq, const ushort* __restrict__ Akv,
    const ushort* __restrict__ Wqh, const ushort* __restrict__ Wql,
    const ushort* __restrict__ Wkh, const ushort* __restrict__ Wvh,
    ushort* __restrict__ aq, ushort* __restrict__ ak,
    ushort* __restrict__ avt) {
    constexpr int K = 1024;
    constexpr float QSCALE = 0.18033688011112042f;  // 0.125 * log2(e)
    __shared__ ushort sA[BM * BK];
    __shared__ ushort sB[2][BN * BK];

    const int bid = blockIdx.x;
    int seg, local, nrow;
    if (bid < 256)      { seg = 0; local = bid;       nrow = 32; }
    else if (bid < 768) { seg = 1; local = bid - 256; nrow = 64; }
    else                { seg = 2; local = bid - 768; nrow = 64; }
    // XCD-grouped bijection within segment (segment size % 8 == 0).
    local = (local & 7) * nrow + (local >> 3);
    const int n0 = (local & 7) * BN;
    const int m0 = (local >> 3) * BM;

    const ushort* A  = (seg == 0) ? Aq : Akv;
    const ushort* Wh = (seg == 0) ? Wqh : (seg == 1 ? Wkh : Wvh);
    const bool twopass = (seg == 0);

    const int tid = threadIdx.x;
    const int lane = tid & 63;
    const int w = tid >> 6;
    const int wm = (w >> 1) * 64;
    const int wn = (w & 1) * 64;

    int srow[2], skq[2];
#pragma unroll
    for (int c = 0; c < 2; ++c) {
        const int row = (w * 2 + c) * 16 + (lane >> 2);
        srow[c] = row;
        skq[c] = (((lane & 3) ^ ((row >> 1) & 3)) << 3);
    }

    f32x4 acc[4][4];
#pragma unroll
    for (int i = 0; i < 4; ++i)
#pragma unroll
        for (int j = 0; j < 4; ++j) acc[i][j] = (f32x4)0.0f;

    const int lr = lane & 15;
    const int kq = lane >> 4;

    for (int k0 = 0; k0 < K; k0 += BK) {
#pragma unroll
        for (int c = 0; c < 2; ++c) {
            const size_t ga = (size_t)(m0 + srow[c]) * K + k0 + skq[c];
            const size_t gb = (size_t)(n0 + srow[c]) * K + k0 + skq[c];
            const int loff = (w * 2 + c) * 512;
            GLD_LDS16(A + ga, &sA[loff]);
            GLD_LDS16(Wh + gb, &sB[0][loff]);
            if (twopass) GLD_LDS16(Wql + gb, &sB[1][loff]);
        }
        __syncthreads();

        bf16x8 afh[4], bfh[4], bfl[4];
#pragma unroll
        for (int f = 0; f < 4; ++f) {
            const int arow = wm + f * 16 + lr;
            afh[f] = *reinterpret_cast<const bf16x8*>(
                &sA[arow * 32 + ((kq ^ ((arow >> 1) & 3)) << 3)]);
            const int brow = wn + f * 16 + lr;
            const int boff = brow * 32 + ((kq ^ ((brow >> 1) & 3)) << 3);
            bfh[f] = *reinterpret_cast<const bf16x8*>(&sB[0][boff]);
            if (twopass)
                bfl[f] = *reinterpret_cast<const bf16x8*>(&sB[1][boff]);
        }
#pragma unroll
        for (int i = 0; i < 4; ++i)
#pragma unroll
            for (int j = 0; j < 4; ++j)
                acc[i][j] = __builtin_amdgcn_mfma_f32_16x16x32_bf16(
                    afh[i], bfh[j], acc[i][j], 0, 0, 0);
        if (twopass) {
#pragma unroll
            for (int i = 0; i < 4; ++i)
#pragma unroll
                for (int j = 0; j < 4; ++j)
                    acc[i][j] = __builtin_amdgcn_mfma_f32_16x16x32_bf16(
                        afh[i], bfl[j], acc[i][j], 0, 0, 0);
        }
        __syncthreads();
    }

    const int cr = (lane >> 4) << 2;
    const int cc = lane & 15;

    if (seg < 2) {  // Q / K layout: [bh][x][64] hi-only, dd ^ ((x&7)<<3)
        const int log2X = (seg == 0) ? 10 : 11;
        const float scale = (seg == 0) ? QSCALE : 1.0f;
        ushort* out = (seg == 0) ? aq : ak;
        const int xm = (1 << log2X) - 1;
#pragma unroll
        for (int i = 0; i < 4; ++i)
#pragma unroll
            for (int j = 0; j < 4; ++j) {
                const int col = n0 + wn + j * 16 + cc;
                const int h = col >> 6, dd = col & 63;
#pragma unroll
                for (int r = 0; r < 4; ++r) {
                    const int mr = m0 + wm + i * 16 + cr + r;
                    const int bb = mr >> log2X;
                    const int x = mr & xm;
                    out[(((size_t)(bb * N_HEADS + h) << log2X) + x) * 64 +
                        (dd ^ ((x & 7) << 3))] = f2bf(acc[i][j][r] * scale);
                }
            }
    } else {  // V^T layout: [bh][dd][2048], s swizzled within 64-blocks
#pragma unroll
        for (int i = 0; i < 4; ++i)
#pragma unroll
            for (int j = 0; j < 4; ++j) {
                const int col = n0 + wn + j * 16 + cc;
                const int h = col >> 6, dd = col & 63;
                const int sb = m0 + wm + i * 16 + cr;
                const int bb = sb >> 11;
                const int sx = sb & 2047;
                ushort4 hv;
#pragma unroll
                for (int r = 0; r < 4; ++r)
                    ((ushort*)&hv)[r] = f2bf(acc[i][j][r]);
                const size_t pos =
                    ((size_t)(bb * N_HEADS + h) * 64 + dd) * 2048 +
                    (sx & ~63) + ((sx & 63) ^ ((dd & 7) << 3));
                *reinterpret_cast<ushort4*>(&avt[pos]) = hv;
            }
    }
}

// ---------------------------------------------------------------------------
// O-projection GEMM: out = AO[M,K] * wo[N,K]^T, 3-pass split (full fp32
// fidelity — the output is directly thresholded). Same m97 structure.
// ---------------------------------------------------------------------------
__global__ __launch_bounds__(256, 2) void gemm_oproj(
    const ushort* __restrict__ Ahi, const ushort* __restrict__ Alo,
    const ushort* __restrict__ Whi, const ushort* __restrict__ Wlo,
    float* __restrict__ Cf, int M, int N, int K) {
    __shared__ ushort sA[2][BM * BK];
    __shared__ ushort sB[2][BN * BK];

    const int tid = threadIdx.x;
    const int lane = tid & 63;
    const int w = tid >> 6;
    const int m0 = blockIdx.y * BM;
    const int n0 = blockIdx.x * BN;
    const int wm = (w >> 1) * 64;
    const int wn = (w & 1) * 64;

    int srow[2], skq[2];
#pragma unroll
    for (int c = 0; c < 2; ++c) {
        const int row = (w * 2 + c) * 16 + (lane >> 2);
        srow[c] = row;
        skq[c] = (((lane & 3) ^ ((row >> 1) & 3)) << 3);
    }

    f32x4 acc[4][4];
#pragma unroll
    for (int i = 0; i < 4; ++i)
#pragma unroll
        for (int j = 0; j < 4; ++j) acc[i][j] = (f32x4)0.0f;

    const int lr = lane & 15;
    const int kq = lane >> 4;

    for (int k0 = 0; k0 < K; k0 += BK) {
#pragma unroll
        for (int c = 0; c < 2; ++c) {
            const size_t ga = (size_t)(m0 + srow[c]) * K + k0 + skq[c];
            const size_t gb = (size_t)(n0 + srow[c]) * K + k0 + skq[c];
            const int loff = (w * 2 + c) * 512;
            GLD_LDS16(Ahi + ga, &sA[0][loff]);
            GLD_LDS16(Alo + ga, &sA[1][loff]);
            GLD_LDS16(Whi + gb, &sB[0][loff]);
            GLD_LDS16(Wlo + gb, &sB[1][loff]);
        }
        __syncthreads();

        bf16x8 afh[4], afl[4], bfh[4], bfl[4];
#pragma unroll
        for (int f = 0; f < 4; ++f) {
            const int arow = wm + f * 16 + lr;
            const int aoff = arow * 32 + ((kq ^ ((arow >> 1) & 3)) << 3);
            afh[f] = *reinterpret_cast<const bf16x8*>(&sA[0][aoff]);
            afl[f] = *reinterpret_cast<const bf16x8*>(&sA[1][aoff]);
            const int brow = wn + f * 16 + lr;
            const int boff = brow * 32 + ((kq ^ ((brow >> 1) & 3)) << 3);
            bfh[f] = *reinterpret_cast<const bf16x8*>(&sB[0][boff]);
            bfl[f] = *reinterpret_cast<const bf16x8*>(&sB[1][boff]);
        }
#pragma unroll
        for (int i = 0; i < 4; ++i)
#pragma unroll
            for (int j = 0; j < 4; ++j) {
                acc[i][j] = __builtin_amdgcn_mfma_f32_16x16x32_bf16(
                    afh[i], bfh[j], acc[i][j], 0, 0, 0);
                acc[i][j] = __builtin_amdgcn_mfma_f32_16x16x32_bf16(
                    afh[i], bfl[j], acc[i][j], 0, 0, 0);
                acc[i][j] = __builtin_amdgcn_mfma_f32_16x16x32_bf16(
                    afl[i], bfh[j], acc[i][j], 0, 0, 0);
            }
        __syncthreads();
    }

    const int cr = (lane >> 4) << 2;
    const int cc = lane & 15;
#pragma unroll
    for (int i = 0; i < 4; ++i)
#pragma unroll
        for (int j = 0; j < 4; ++j) {
            float* cp = &Cf[(size_t)(m0 + wm + i * 16 + cr) * N + n0 + wn +
                            j * 16 + cc];
#pragma unroll
            for (int r = 0; r < 4; ++r) cp[(size_t)r * N] = acc[i][j][r];
        }
}

// ---------------------------------------------------------------------------
// MFMA flash attention, max-free softmax. Logits (exp2 units) are bounded
// (|logit| <~ 10 « f32 exp2 range), softmax is shift-invariant, and p/l
// share scale so relative rounding is unchanged -> no running max, no
// rescale. Per-lane partial l reduced once in the epilogue. All staging
// addresses are pointer-increments; all LDS offsets precomputed.
// ---------------------------------------------------------------------------
__global__ __launch_bounds__(256, 4) void attn_mfma(
    const ushort* __restrict__ Qhi, const ushort* __restrict__ Khi,
    const ushort* __restrict__ Vhi, ushort* __restrict__ Ohi,
    ushort* __restrict__ Olo) {
    constexpr int T = 1024, S = 2048, NT = S / 64;
    __shared__ ushort sK[2][4096];  // [buf][s*64+dd]  (hi)
    __shared__ ushort sV[2][4096];  // [buf][dd*64+s]  (hi)
    __shared__ ushort sPb[4096];    // 4 x 2KB wave-private P buffers

    const int tid = threadIdx.x;
    const int lane = tid & 63;
    const int w = tid >> 6;
    const int id = blockIdx.x;
    const int wid = (id & 7) * 128 + (id >> 3);
    const int t0 = (wid & 15) * 64;
    const int bh = wid >> 4;
    const int lr = lane & 15;
    const int g = lane >> 4;
    const int swz = (lr & 7) << 3;

    const size_t qbase = ((size_t)bh * T + t0) * 64;
    const size_t kbase = (size_t)bh * S * 64;
    const size_t vbase = (size_t)bh * 64;

    // per-lane staging pointers (advance by constants per tile)
    int loff[2];
    const ushort* kp[2];
    const ushort* vp[2];
#pragma unroll
    for (int i = 0; i < 2; ++i) {
        loff[i] = i * 2048 + w * 512 + lane * 8;
        kp[i] = Khi + kbase + loff[i];
        vp[i] = Vhi + (vbase + (loff[i] >> 6)) * S + (loff[i] & 63);
    }

    // precomputed LDS offsets (K-read == V-read form), P write/read offsets
    int rdoff[4][2], pwoff[4], proff[2];
#pragma unroll
    for (int j = 0; j < 4; ++j) {
#pragma unroll
        for (int kk = 0; kk < 2; ++kk)
            rdoff[j][kk] = (j * 16 + lr) * 64 + ((kk * 32 + g * 8) ^ swz);
        pwoff[j] = lr * 64 + ((j * 16 + g * 4) ^ swz);
    }
#pragma unroll
    for (int kk = 0; kk < 2; ++kk)
        proff[kk] = lr * 64 + ((kk * 32 + g * 8) ^ swz);

    // prologue: Q-hi -> sK[1]; first K/V tile -> buf 0
#pragma unroll
    for (int i = 0; i < 2; ++i) GLD_LDS16(Qhi + qbase + loff[i], &sK[1][loff[i]]);
#pragma unroll
    for (int i = 0; i < 2; ++i) {
        GLD_LDS16(kp[i], &sK[0][loff[i]]);
        GLD_LDS16(vp[i], &sV[0][loff[i]]);
        kp[i] += 4096;
        vp[i] += 64;
    }
    __syncthreads();

    bf16x8 qf[2];
#pragma unroll
    for (int kk = 0; kk < 2; ++kk)
        qf[kk] = *reinterpret_cast<const bf16x8*>(
            &sK[1][(w * 16 + lr) * 64 + ((kk * 32 + g * 8) ^ swz)]);
    __syncthreads();  // all Q reads done before buf1 gets overwritten

    ushort* sP = &sPb[w * 1024];  // wave-private

    f32x4 oacc[4];
#pragma unroll
    for (int jd = 0; jd < 4; ++jd) oacc[jd] = (f32x4)0.0f;
    float lpart = 0.0f;  // per-lane partial denominator (own 16 s-slots)

    for (int t = 0; t < NT; ++t) {
        const int bi = t & 1;
        if (t + 1 < NT) {
#pragma unroll
            for (int i = 0; i < 2; ++i) {
                GLD_LDS16(kp[i], &sK[bi ^ 1][loff[i]]);
                GLD_LDS16(vp[i], &sV[bi ^ 1][loff[i]]);
                kp[i] += 4096;
                vp[i] += 64;
            }
        }

        // ---- QK^T swapped, 1-pass: k_hi * q_hi ----
        f32x4 sacc[4];
        __builtin_amdgcn_s_setprio(1);
#pragma unroll
        for (int j = 0; j < 4; ++j) {
            sacc[j] = (f32x4)0.0f;
#pragma unroll
            for (int kk = 0; kk < 2; ++kk) {
                const bf16x8 kh = *reinterpret_cast<const bf16x8*>(
                    &sK[bi][rdoff[j][kk]]);
                sacc[j] = __builtin_amdgcn_mfma_f32_16x16x32_bf16(
                    kh, qf[kk], sacc[j], 0, 0, 0);
            }
        }
        __builtin_amdgcn_s_setprio(0);

        // ---- max-free softmax: p = exp2(logit); partial l; pack bf16 ----
        uint32_t wpk[4][2];
#pragma unroll
        for (int j = 0; j < 4; ++j) {
            const float p0 = exp2f(sacc[j][0]);
            const float p1 = exp2f(sacc[j][1]);
            const float p2 = exp2f(sacc[j][2]);
            const float p3 = exp2f(sacc[j][3]);
            lpart += (p0 + p1) + (p2 + p3);
            wpk[j][0] = cvt_pk_bf16(p0, p1);
            wpk[j][1] = cvt_pk_bf16(p2, p3);
        }

#pragma unroll
        for (int j = 0; j < 4; ++j)
            *reinterpret_cast<uint2*>(&sP[pwoff[j]]) =
                make_uint2(wpk[j][0], wpk[j][1]);
        asm volatile("s_waitcnt lgkmcnt(0)" ::: "memory");
        __builtin_amdgcn_sched_barrier(0);

        // ---- PV, 1-pass ----
        bf16x8 pf[2];
#pragma unroll
        for (int kk = 0; kk < 2; ++kk)
            pf[kk] = *reinterpret_cast<const bf16x8*>(&sP[proff[kk]]);
        __builtin_amdgcn_s_setprio(1);
#pragma unroll
        for (int jd = 0; jd < 4; ++jd) {
#pragma unroll
            for (int kk = 0; kk < 2; ++kk) {
                const bf16x8 vh = *reinterpret_cast<const bf16x8*>(
                    &sV[bi][rdoff[jd][kk]]);
                oacc[jd] = __builtin_amdgcn_mfma_f32_16x16x32_bf16(
                    pf[kk], vh, oacc[jd], 0, 0, 0);
            }
        }
        __builtin_amdgcn_s_setprio(0);
        __syncthreads();  // drains next tile's loads; protects dbuf reuse
    }

    // ---- epilogue: reduce l across g-groups, split O to bf16 hi/lo ----
    float l = lpart;
    l += __shfl_xor(l, 16);
    l += __shfl_xor(l, 32);

    const int b = bh >> 4, h = bh & 15;
    float linv[4];
#pragma unroll
    for (int r = 0; r < 4; ++r) linv[r] = 1.0f / __shfl(l, g * 4 + r);
#pragma unroll
    for (int r = 0; r < 4; ++r) {
        const int q = t0 + w * 16 + g * 4 + r;
        const size_t rowb = ((size_t)(b * T + q)) * 1024 + h * 64;
#pragma unroll
        for (int jd = 0; jd < 4; ++jd) {
            const float v = oacc[jd][r] * linv[r];
            const ushort hv = f2bf(v);
            Ohi[rowb + jd * 16 + lr] = hv;
            Olo[rowb + jd * 16 + lr] = f2bf(v - bf2f(hv));
        }
    }
}

// ---------------------------------------------------------------------------
extern "C" void kernel_launch(void* const* d_in, const int* in_sizes, int n_in,
                              void* d_out, int out_size, void* d_ws, size_t ws_size,
                              hipStream_t stream) {
    const int B = 4, T = 1024, S = 2048, D = 1024;

    const float* query = (const float*)d_in[0];
    const float* keyv  = (const float*)d_in[1];
    const float* wq    = (const float*)d_in[2];
    const float* wk    = (const float*)d_in[3];
    const float* wv    = (const float*)d_in[4];
    const float* wo    = (const float*)d_in[5];
    float* out = (float*)d_out;

    const size_t nQ = (size_t)B * T * D;  // 4M
    const size_t nK = (size_t)B * S * D;  // 8M
    const size_t nW = (size_t)D * D;      // 1M

    uint8_t* p = (uint8_t*)d_ws;
    ushort* inq_h = (ushort*)p;  p += nQ * 2;   // 8 MB
    ushort* inkv_h = (ushort*)p; p += nK * 2;   // 16 MB
    ushort* wqh = (ushort*)p;    p += nW * 2;
    ushort* wql = (ushort*)p;    p += nW * 2;
    ushort* wkh = (ushort*)p;    p += nW * 2;
    ushort* wvh = (ushort*)p;    p += nW * 2;
    ushort* woh = (ushort*)p;    p += nW * 2;
    ushort* wol = (ushort*)p;    p += nW * 2;   // 12 MB
    ushort* aq_h = (ushort*)p;   p += nQ * 2;   // 8 MB (hi only)
    ushort* ak_h = (ushort*)p;   p += nK * 2;   // 16 MB (hi only)
    ushort* avt_h = (ushort*)p;  p += nK * 2;   // 16 MB (hi only)
    ushort* ao_h = (ushort*)p;   p += nQ * 2;
    ushort* ao_l = (ushort*)p;   p += nQ * 2;   // 16 MB
    // total 92 MB

    const dim3 blk(256);

    // 1) all input/weight splits, one launch
    split_all<<<dim3(512, 6), blk, 0, stream>>>(
        query, keyv, wq, wk, wv, wo, inq_h, inkv_h, wqh, wql, wkh, wvh, woh,
        wol);

    // 2) Q/K/V projections, one batched launch (fused attn-layout epilogues)
    qkv_proj<<<dim3(1280), blk, 0, stream>>>(inq_h, inkv_h, wqh, wql, wkh,
                                             wvh, aq_h, ak_h, avt_h);

    // 3) attention (1-D XCD-grouped grid; writes split hi/lo directly)
    attn_mfma<<<dim3((T / 64) * B * N_HEADS), blk, 0, stream>>>(
        aq_h, ak_h, avt_h, ao_h, ao_l);

    // 4) output projection (full 3-pass: output directly thresholded)
    gemm_oproj<<<dim3(D / BN, (B * T) / BM), blk, 0, stream>>>(
        ao_h, ao_l, woh, wol, out, B * T, D, D);
}

// Round 10
// 173.262 us; speedup vs baseline: 7.1755x; 1.0588x over previous
//
#include <hip/hip_runtime.h>
#include <cstdint>
#include <cstddef>

#define N_HEADS 16

typedef __attribute__((ext_vector_type(4))) float f32x4;
typedef __attribute__((ext_vector_type(8))) short bf16x8;

// ---------------------------------------------------------------------------
// fp32 -> (hi, lo) bf16 split helpers (RTN-even, no NaN inputs).
// ---------------------------------------------------------------------------
static __device__ inline ushort f2bf(float x) {
    uint32_t u = __float_as_uint(x);
    uint32_t r = (u + 0x7fffu + ((u >> 16) & 1u)) >> 16;
    return (ushort)r;
}
static __device__ inline float bf2f(ushort h) {
    return __uint_as_float(((uint32_t)h) << 16);
}
static __device__ inline uint32_t cvt_pk_bf16(float lo, float hi) {
    uint32_t r;
    asm("v_cvt_pk_bf16_f32 %0, %1, %2" : "=v"(r) : "v"(lo), "v"(hi));
    return r;
}

// ---------------------------------------------------------------------------
// One launch for ALL splits. blockIdx.y segments:
// 0: query -> hi   1: keyv -> hi
// 2: wq -> hi      3: wk -> hi    4: wv -> hi    5: wo -> hi+lo
// ---------------------------------------------------------------------------
__global__ __launch_bounds__(256) void split_all(
    const float* __restrict__ query, const float* __restrict__ keyv,
    const float* __restrict__ wq, const float* __restrict__ wk,
    const float* __restrict__ wv, const float* __restrict__ wo,
    ushort* __restrict__ inq_h, ushort* __restrict__ inkv_h,
    ushort* __restrict__ wqh, ushort* __restrict__ wkh,
    ushort* __restrict__ wvh, ushort* __restrict__ woh,
    ushort* __restrict__ wol) {
    const float* x;
    ushort* hi;
    ushort* lo = nullptr;
    int n4;
    switch (blockIdx.y) {
        case 0: x = query; hi = inq_h;           n4 = 1048576; break;
        case 1: x = keyv;  hi = inkv_h;          n4 = 2097152; break;
        case 2: x = wq;    hi = wqh;             n4 = 262144;  break;
        case 3: x = wk;    hi = wkh;             n4 = 262144;  break;
        case 4: x = wv;    hi = wvh;             n4 = 262144;  break;
        default: x = wo;   hi = woh; lo = wol;   n4 = 262144;  break;
    }
    const int stride = gridDim.x * blockDim.x;
    const bool wlo = (lo != nullptr);
    for (int i = blockIdx.x * blockDim.x + threadIdx.x; i < n4; i += stride) {
        const float4 v = reinterpret_cast<const float4*>(x)[i];
        ushort4 h;
        h.x = f2bf(v.x); h.y = f2bf(v.y); h.z = f2bf(v.z); h.w = f2bf(v.w);
        reinterpret_cast<ushort4*>(hi)[i] = h;
        if (wlo) {
            ushort4 l;
            l.x = f2bf(v.x - bf2f(h.x)); l.y = f2bf(v.y - bf2f(h.y));
            l.z = f2bf(v.z - bf2f(h.z)); l.w = f2bf(v.w - bf2f(h.w));
            reinterpret_cast<ushort4*>(lo)[i] = l;
        }
    }
}

#define BM 128
#define BN 128
#define BK 32

#define GLD_LDS16(gp, lp)                                                  \
    __builtin_amdgcn_global_load_lds(                                      \
        (const __attribute__((address_space(1))) void*)(gp),               \
        (__attribute__((address_space(3))) void*)(lp), 16, 0, 0)

// ---------------------------------------------------------------------------
// Batched Q/K/V projection, single launch (1280 blocks), all 1-pass hi*hi:
//   [0,256)   seg 0: Q = inq_h  @ wq^T, scaled -> attn Q layout [bh][x][64]
//   [256,768) seg 1: K = inkv_h @ wk^T -> attn K layout
//   [768,1280)seg 2: V = inkv_h @ wv^T -> attn V^T layout [bh][dd][2048]
// Per-segment bijective XCD-grouping for A-panel L2 residency.
// ---------------------------------------------------------------------------
__global__ __launch_bounds__(256, 2) void qkv_proj(
    const ushort* __restrict__ Aq, const ushort* __restrict__ Akv,
    const ushort* __restrict__ Wqh, const ushort* __restrict__ Wkh,
    const ushort* __restrict__ Wvh, ushort* __restrict__ aq,
    ushort* __restrict__ ak, ushort* __restrict__ avt) {
    constexpr int K = 1024;
    constexpr float QSCALE = 0.18033688011112042f;  // 0.125 * log2(e)
    __shared__ ushort sA[BM * BK];
    __shared__ ushort sB[BN * BK];

    const int bid = blockIdx.x;
    int seg, local, nrow;
    if (bid < 256)      { seg = 0; local = bid;       nrow = 32; }
    else if (bid < 768) { seg = 1; local = bid - 256; nrow = 64; }
    else                { seg = 2; local = bid - 768; nrow = 64; }
    // XCD-grouped bijection within segment (segment size % 8 == 0).
    local = (local & 7) * nrow + (local >> 3);
    const int n0 = (local & 7) * BN;
    const int m0 = (local >> 3) * BM;

    const ushort* A  = (seg == 0) ? Aq : Akv;
    const ushort* Wh = (seg == 0) ? Wqh : (seg == 1 ? Wkh : Wvh);

    const int tid = threadIdx.x;
    const int lane = tid & 63;
    const int w = tid >> 6;
    const int wm = (w >> 1) * 64;
    const int wn = (w & 1) * 64;

    int srow[2], skq[2];
#pragma unroll
    for (int c = 0; c < 2; ++c) {
        const int row = (w * 2 + c) * 16 + (lane >> 2);
        srow[c] = row;
        skq[c] = (((lane & 3) ^ ((row >> 1) & 3)) << 3);
    }

    f32x4 acc[4][4];
#pragma unroll
    for (int i = 0; i < 4; ++i)
#pragma unroll
        for (int j = 0; j < 4; ++j) acc[i][j] = (f32x4)0.0f;

    const int lr = lane & 15;
    const int kq = lane >> 4;

    for (int k0 = 0; k0 < K; k0 += BK) {
#pragma unroll
        for (int c = 0; c < 2; ++c) {
            const size_t ga = (size_t)(m0 + srow[c]) * K + k0 + skq[c];
            const size_t gb = (size_t)(n0 + srow[c]) * K + k0 + skq[c];
            const int loff = (w * 2 + c) * 512;
            GLD_LDS16(A + ga, &sA[loff]);
            GLD_LDS16(Wh + gb, &sB[loff]);
        }
        __syncthreads();

        bf16x8 afh[4], bfh[4];
#pragma unroll
        for (int f = 0; f < 4; ++f) {
            const int arow = wm + f * 16 + lr;
            afh[f] = *reinterpret_cast<const bf16x8*>(
                &sA[arow * 32 + ((kq ^ ((arow >> 1) & 3)) << 3)]);
            const int brow = wn + f * 16 + lr;
            bfh[f] = *reinterpret_cast<const bf16x8*>(
                &sB[brow * 32 + ((kq ^ ((brow >> 1) & 3)) << 3)]);
        }
#pragma unroll
        for (int i = 0; i < 4; ++i)
#pragma unroll
            for (int j = 0; j < 4; ++j)
                acc[i][j] = __builtin_amdgcn_mfma_f32_16x16x32_bf16(
                    afh[i], bfh[j], acc[i][j], 0, 0, 0);
        __syncthreads();
    }

    const int cr = (lane >> 4) << 2;
    const int cc = lane & 15;

    if (seg < 2) {  // Q / K layout: [bh][x][64] hi-only, dd ^ ((x&7)<<3)
        const int log2X = (seg == 0) ? 10 : 11;
        const float scale = (seg == 0) ? QSCALE : 1.0f;
        ushort* out = (seg == 0) ? aq : ak;
        const int xm = (1 << log2X) - 1;
#pragma unroll
        for (int i = 0; i < 4; ++i)
#pragma unroll
            for (int j = 0; j < 4; ++j) {
                const int col = n0 + wn + j * 16 + cc;
                const int h = col >> 6, dd = col & 63;
#pragma unroll
                for (int r = 0; r < 4; ++r) {
                    const int mr = m0 + wm + i * 16 + cr + r;
                    const int bb = mr >> log2X;
                    const int x = mr & xm;
                    out[(((size_t)(bb * N_HEADS + h) << log2X) + x) * 64 +
                        (dd ^ ((x & 7) << 3))] = f2bf(acc[i][j][r] * scale);
                }
            }
    } else {  // V^T layout: [bh][dd][2048], s swizzled within 64-blocks
#pragma unroll
        for (int i = 0; i < 4; ++i)
#pragma unroll
            for (int j = 0; j < 4; ++j) {
                const int col = n0 + wn + j * 16 + cc;
                const int h = col >> 6, dd = col & 63;
                const int sb = m0 + wm + i * 16 + cr;
                const int bb = sb >> 11;
                const int sx = sb & 2047;
                ushort4 hv;
#pragma unroll
                for (int r = 0; r < 4; ++r)
                    ((ushort*)&hv)[r] = f2bf(acc[i][j][r]);
                const size_t pos =
                    ((size_t)(bb * N_HEADS + h) * 64 + dd) * 2048 +
                    (sx & ~63) + ((sx & 63) ^ ((dd & 7) << 3));
                *reinterpret_cast<ushort4*>(&avt[pos]) = hv;
            }
    }
}

// ---------------------------------------------------------------------------
// O-projection GEMM: out = AO[M,K] * wo[N,K]^T, 2-pass (A_hi*(W_hi+W_lo)).
// Dropped A_lo*W_hi term: ~1e-4-class on the thresholded output (budgeted).
// ---------------------------------------------------------------------------
__global__ __launch_bounds__(256, 2) void gemm_oproj(
    const ushort* __restrict__ Ahi, const ushort* __restrict__ Whi,
    const ushort* __restrict__ Wlo, float* __restrict__ Cf, int M, int N,
    int K) {
    __shared__ ushort sA[BM * BK];
    __shared__ ushort sB[2][BN * BK];

    const int tid = threadIdx.x;
    const int lane = tid & 63;
    const int w = tid >> 6;
    const int m0 = blockIdx.y * BM;
    const int n0 = blockIdx.x * BN;
    const int wm = (w >> 1) * 64;
    const int wn = (w & 1) * 64;

    int srow[2], skq[2];
#pragma unroll
    for (int c = 0; c < 2; ++c) {
        const int row = (w * 2 + c) * 16 + (lane >> 2);
        srow[c] = row;
        skq[c] = (((lane & 3) ^ ((row >> 1) & 3)) << 3);
    }

    f32x4 acc[4][4];
#pragma unroll
    for (int i = 0; i < 4; ++i)
#pragma unroll
        for (int j = 0; j < 4; ++j) acc[i][j] = (f32x4)0.0f;

    const int lr = lane & 15;
    const int kq = lane >> 4;

    for (int k0 = 0; k0 < K; k0 += BK) {
#pragma unroll
        for (int c = 0; c < 2; ++c) {
            const size_t ga = (size_t)(m0 + srow[c]) * K + k0 + skq[c];
            const size_t gb = (size_t)(n0 + srow[c]) * K + k0 + skq[c];
            const int loff = (w * 2 + c) * 512;
            GLD_LDS16(Ahi + ga, &sA[loff]);
            GLD_LDS16(Whi + gb, &sB[0][loff]);
            GLD_LDS16(Wlo + gb, &sB[1][loff]);
        }
        __syncthreads();

        bf16x8 afh[4], bfh[4], bfl[4];
#pragma unroll
        for (int f = 0; f < 4; ++f) {
            const int arow = wm + f * 16 + lr;
            afh[f] = *reinterpret_cast<const bf16x8*>(
                &sA[arow * 32 + ((kq ^ ((arow >> 1) & 3)) << 3)]);
            const int brow = wn + f * 16 + lr;
            const int boff = brow * 32 + ((kq ^ ((brow >> 1) & 3)) << 3);
            bfh[f] = *reinterpret_cast<const bf16x8*>(&sB[0][boff]);
            bfl[f] = *reinterpret_cast<const bf16x8*>(&sB[1][boff]);
        }
#pragma unroll
        for (int i = 0; i < 4; ++i)
#pragma unroll
            for (int j = 0; j < 4; ++j) {
                acc[i][j] = __builtin_amdgcn_mfma_f32_16x16x32_bf16(
                    afh[i], bfh[j], acc[i][j], 0, 0, 0);
                acc[i][j] = __builtin_amdgcn_mfma_f32_16x16x32_bf16(
                    afh[i], bfl[j], acc[i][j], 0, 0, 0);
            }
        __syncthreads();
    }

    const int cr = (lane >> 4) << 2;
    const int cc = lane & 15;
#pragma unroll
    for (int i = 0; i < 4; ++i)
#pragma unroll
        for (int j = 0; j < 4; ++j) {
            float* cp = &Cf[(size_t)(m0 + wm + i * 16 + cr) * N + n0 + wn +
                            j * 16 + cc];
#pragma unroll
            for (int r = 0; r < 4; ++r) cp[(size_t)r * N] = acc[i][j][r];
        }
}

// ---------------------------------------------------------------------------
// MFMA flash attention, max-free softmax (unchanged from round 9 except
// hi-only output). Per-lane partial l reduced once in epilogue; all staging
// addresses pointer-increments; all LDS offsets precomputed.
// ---------------------------------------------------------------------------
__global__ __launch_bounds__(256, 4) void attn_mfma(
    const ushort* __restrict__ Qhi, const ushort* __restrict__ Khi,
    const ushort* __restrict__ Vhi, ushort* __restrict__ Ohi) {
    constexpr int T = 1024, S = 2048, NT = S / 64;
    __shared__ ushort sK[2][4096];  // [buf][s*64+dd]  (hi)
    __shared__ ushort sV[2][4096];  // [buf][dd*64+s]  (hi)
    __shared__ ushort sPb[4096];    // 4 x 2KB wave-private P buffers

    const int tid = threadIdx.x;
    const int lane = tid & 63;
    const int w = tid >> 6;
    const int id = blockIdx.x;
    const int wid = (id & 7) * 128 + (id >> 3);
    const int t0 = (wid & 15) * 64;
    const int bh = wid >> 4;
    const int lr = lane & 15;
    const int g = lane >> 4;
    const int swz = (lr & 7) << 3;

    const size_t qbase = ((size_t)bh * T + t0) * 64;
    const size_t kbase = (size_t)bh * S * 64;
    const size_t vbase = (size_t)bh * 64;

    // per-lane staging pointers (advance by constants per tile)
    int loff[2];
    const ushort* kp[2];
    const ushort* vp[2];
#pragma unroll
    for (int i = 0; i < 2; ++i) {
        loff[i] = i * 2048 + w * 512 + lane * 8;
        kp[i] = Khi + kbase + loff[i];
        vp[i] = Vhi + (vbase + (loff[i] >> 6)) * S + (loff[i] & 63);
    }

    // precomputed LDS offsets (K-read == V-read form), P write/read offsets
    int rdoff[4][2], pwoff[4], proff[2];
#pragma unroll
    for (int j = 0; j < 4; ++j) {
#pragma unroll
        for (int kk = 0; kk < 2; ++kk)
            rdoff[j][kk] = (j * 16 + lr) * 64 + ((kk * 32 + g * 8) ^ swz);
        pwoff[j] = lr * 64 + ((j * 16 + g * 4) ^ swz);
    }
#pragma unroll
    for (int kk = 0; kk < 2; ++kk)
        proff[kk] = lr * 64 + ((kk * 32 + g * 8) ^ swz);

    // prologue: Q-hi -> sK[1]; first K/V tile -> buf 0
#pragma unroll
    for (int i = 0; i < 2; ++i) GLD_LDS16(Qhi + qbase + loff[i], &sK[1][loff[i]]);
#pragma unroll
    for (int i = 0; i < 2; ++i) {
        GLD_LDS16(kp[i], &sK[0][loff[i]]);
        GLD_LDS16(vp[i], &sV[0][loff[i]]);
        kp[i] += 4096;
        vp[i] += 64;
    }
    __syncthreads();

    bf16x8 qf[2];
#pragma unroll
    for (int kk = 0; kk < 2; ++kk)
        qf[kk] = *reinterpret_cast<const bf16x8*>(
            &sK[1][(w * 16 + lr) * 64 + ((kk * 32 + g * 8) ^ swz)]);
    __syncthreads();  // all Q reads done before buf1 gets overwritten

    ushort* sP = &sPb[w * 1024];  // wave-private

    f32x4 oacc[4];
#pragma unroll
    for (int jd = 0; jd < 4; ++jd) oacc[jd] = (f32x4)0.0f;
    float lpart = 0.0f;  // per-lane partial denominator (own 16 s-slots)

    for (int t = 0; t < NT; ++t) {
        const int bi = t & 1;
        if (t + 1 < NT) {
#pragma unroll
            for (int i = 0; i < 2; ++i) {
                GLD_LDS16(kp[i], &sK[bi ^ 1][loff[i]]);
                GLD_LDS16(vp[i], &sV[bi ^ 1][loff[i]]);
                kp[i] += 4096;
                vp[i] += 64;
            }
        }

        // ---- QK^T swapped, 1-pass: k_hi * q_hi ----
        f32x4 sacc[4];
        __builtin_amdgcn_s_setprio(1);
#pragma unroll
        for (int j = 0; j < 4; ++j) {
            sacc[j] = (f32x4)0.0f;
#pragma unroll
            for (int kk = 0; kk < 2; ++kk) {
                const bf16x8 kh = *reinterpret_cast<const bf16x8*>(
                    &sK[bi][rdoff[j][kk]]);
                sacc[j] = __builtin_amdgcn_mfma_f32_16x16x32_bf16(
                    kh, qf[kk], sacc[j], 0, 0, 0);
            }
        }
        __builtin_amdgcn_s_setprio(0);

        // ---- max-free softmax: p = exp2(logit); partial l; pack bf16 ----
        uint32_t wpk[4][2];
#pragma unroll
        for (int j = 0; j < 4; ++j) {
            const float p0 = exp2f(sacc[j][0]);
            const float p1 = exp2f(sacc[j][1]);
            const float p2 = exp2f(sacc[j][2]);
            const float p3 = exp2f(sacc[j][3]);
            lpart += (p0 + p1) + (p2 + p3);
            wpk[j][0] = cvt_pk_bf16(p0, p1);
            wpk[j][1] = cvt_pk_bf16(p2, p3);
        }

#pragma unroll
        for (int j = 0; j < 4; ++j)
            *reinterpret_cast<uint2*>(&sP[pwoff[j]]) =
                make_uint2(wpk[j][0], wpk[j][1]);
        asm volatile("s_waitcnt lgkmcnt(0)" ::: "memory");
        __builtin_amdgcn_sched_barrier(0);

        // ---- PV, 1-pass ----
        bf16x8 pf[2];
#pragma unroll
        for (int kk = 0; kk < 2; ++kk)
            pf[kk] = *reinterpret_cast<const bf16x8*>(&sP[proff[kk]]);
        __builtin_amdgcn_s_setprio(1);
#pragma unroll
        for (int jd = 0; jd < 4; ++jd) {
#pragma unroll
            for (int kk = 0; kk < 2; ++kk) {
                const bf16x8 vh = *reinterpret_cast<const bf16x8*>(
                    &sV[bi][rdoff[jd][kk]]);
                oacc[jd] = __builtin_amdgcn_mfma_f32_16x16x32_bf16(
                    pf[kk], vh, oacc[jd], 0, 0, 0);
            }
        }
        __builtin_amdgcn_s_setprio(0);
        __syncthreads();  // drains next tile's loads; protects dbuf reuse
    }

    // ---- epilogue: reduce l across g-groups, write O hi-only ----
    float l = lpart;
    l += __shfl_xor(l, 16);
    l += __shfl_xor(l, 32);

    const int b = bh >> 4, h = bh & 15;
    float linv[4];
#pragma unroll
    for (int r = 0; r < 4; ++r) linv[r] = 1.0f / __shfl(l, g * 4 + r);
#pragma unroll
    for (int r = 0; r < 4; ++r) {
        const int q = t0 + w * 16 + g * 4 + r;
        const size_t rowb = ((size_t)(b * T + q)) * 1024 + h * 64;
#pragma unroll
        for (int jd = 0; jd < 4; ++jd)
            Ohi[rowb + jd * 16 + lr] = f2bf(oacc[jd][r] * linv[r]);
    }
}

// ---------------------------------------------------------------------------
extern "C" void kernel_launch(void* const* d_in, const int* in_sizes, int n_in,
                              void* d_out, int out_size, void* d_ws, size_t ws_size,
                              hipStream_t stream) {
    const int B = 4, T = 1024, S = 2048, D = 1024;

    const float* query = (const float*)d_in[0];
    const float* keyv  = (const float*)d_in[1];
    const float* wq    = (const float*)d_in[2];
    const float* wk    = (const float*)d_in[3];
    const float* wv    = (const float*)d_in[4];
    const float* wo    = (const float*)d_in[5];
    float* out = (float*)d_out;

    const size_t nQ = (size_t)B * T * D;  // 4M
    const size_t nK = (size_t)B * S * D;  // 8M
    const size_t nW = (size_t)D * D;      // 1M

    uint8_t* p = (uint8_t*)d_ws;
    ushort* inq_h = (ushort*)p;  p += nQ * 2;   // 8 MB
    ushort* inkv_h = (ushort*)p; p += nK * 2;   // 16 MB
    ushort* wqh = (ushort*)p;    p += nW * 2;
    ushort* wkh = (ushort*)p;    p += nW * 2;
    ushort* wvh = (ushort*)p;    p += nW * 2;
    ushort* woh = (ushort*)p;    p += nW * 2;
    ushort* wol = (ushort*)p;    p += nW * 2;   // 10 MB
    ushort* aq_h = (ushort*)p;   p += nQ * 2;   // 8 MB (hi only)
    ushort* ak_h = (ushort*)p;   p += nK * 2;   // 16 MB (hi only)
    ushort* avt_h = (ushort*)p;  p += nK * 2;   // 16 MB (hi only)
    ushort* ao_h = (ushort*)p;   p += nQ * 2;   // 8 MB (hi only)
    // total 82 MB

    const dim3 blk(256);

    // 1) all input/weight splits, one launch
    split_all<<<dim3(512, 6), blk, 0, stream>>>(
        query, keyv, wq, wk, wv, wo, inq_h, inkv_h, wqh, wkh, wvh, woh, wol);

    // 2) Q/K/V projections, one batched 1-pass launch (fused attn layouts)
    qkv_proj<<<dim3(1280), blk, 0, stream>>>(inq_h, inkv_h, wqh, wkh, wvh,
                                             aq_h, ak_h, avt_h);

    // 3) attention (1-D XCD-grouped grid; writes hi-only O)
    attn_mfma<<<dim3((T / 64) * B * N_HEADS), blk, 0, stream>>>(
        aq_h, ak_h, avt_h, ao_h);

    // 4) output projection, 2-pass
    gemm_oproj<<<dim3(D / BN, (B * T) / BM), blk, 0, stream>>>(
        ao_h, woh, wol, out, B * T, D, D);
}

// Round 11
// 161.061 us; speedup vs baseline: 7.7191x; 1.0758x over previous
//
#include <hip/hip_runtime.h>
#include <cstdint>
#include <cstddef>

#define N_HEADS 16

typedef __attribute__((ext_vector_type(4))) float f32x4;
typedef __attribute__((ext_vector_type(8))) short bf16x8;

// ---------------------------------------------------------------------------
// fp32 -> (hi, lo) bf16 split helpers (RTN-even, no NaN inputs).
// ---------------------------------------------------------------------------
static __device__ inline ushort f2bf(float x) {
    uint32_t u = __float_as_uint(x);
    uint32_t r = (u + 0x7fffu + ((u >> 16) & 1u)) >> 16;
    return (ushort)r;
}
static __device__ inline float bf2f(ushort h) {
    return __uint_as_float(((uint32_t)h) << 16);
}
static __device__ inline uint32_t cvt_pk_bf16(float lo, float hi) {
    uint32_t r;
    asm("v_cvt_pk_bf16_f32 %0, %1, %2" : "=v"(r) : "v"(lo), "v"(hi));
    return r;
}
// Raw v_exp_f32 (2^x). Inputs are bounded (|x| < ~30) so the OCML denorm
// fixup path is unnecessary; correctness-safe per learn_hip m214-v48.
static __device__ inline float exp2_raw(float x) {
    float r;
    asm("v_exp_f32 %0, %1" : "=v"(r) : "v"(x));
    return r;
}

// ---------------------------------------------------------------------------
// One launch for ALL splits. blockIdx.y segments:
// 0: query -> hi   1: keyv -> hi
// 2: wq -> hi      3: wk -> hi    4: wv -> hi    5: wo -> hi+lo
// ---------------------------------------------------------------------------
__global__ __launch_bounds__(256) void split_all(
    const float* __restrict__ query, const float* __restrict__ keyv,
    const float* __restrict__ wq, const float* __restrict__ wk,
    const float* __restrict__ wv, const float* __restrict__ wo,
    ushort* __restrict__ inq_h, ushort* __restrict__ inkv_h,
    ushort* __restrict__ wqh, ushort* __restrict__ wkh,
    ushort* __restrict__ wvh, ushort* __restrict__ woh,
    ushort* __restrict__ wol) {
    const float* x;
    ushort* hi;
    ushort* lo = nullptr;
    int n4;
    switch (blockIdx.y) {
        case 0: x = query; hi = inq_h;           n4 = 1048576; break;
        case 1: x = keyv;  hi = inkv_h;          n4 = 2097152; break;
        case 2: x = wq;    hi = wqh;             n4 = 262144;  break;
        case 3: x = wk;    hi = wkh;             n4 = 262144;  break;
        case 4: x = wv;    hi = wvh;             n4 = 262144;  break;
        default: x = wo;   hi = woh; lo = wol;   n4 = 262144;  break;
    }
    const int stride = gridDim.x * blockDim.x;
    const bool wlo = (lo != nullptr);
    for (int i = blockIdx.x * blockDim.x + threadIdx.x; i < n4; i += stride) {
        const float4 v = reinterpret_cast<const float4*>(x)[i];
        ushort4 h;
        h.x = f2bf(v.x); h.y = f2bf(v.y); h.z = f2bf(v.z); h.w = f2bf(v.w);
        reinterpret_cast<ushort4*>(hi)[i] = h;
        if (wlo) {
            ushort4 l;
            l.x = f2bf(v.x - bf2f(h.x)); l.y = f2bf(v.y - bf2f(h.y));
            l.z = f2bf(v.z - bf2f(h.z)); l.w = f2bf(v.w - bf2f(h.w));
            reinterpret_cast<ushort4*>(lo)[i] = l;
        }
    }
}

#define BM 128
#define BN 128
#define BK 32

#define GLD_LDS16(gp, lp)                                                  \
    __builtin_amdgcn_global_load_lds(                                      \
        (const __attribute__((address_space(1))) void*)(gp),               \
        (__attribute__((address_space(3))) void*)(lp), 16, 0, 0)

// ---------------------------------------------------------------------------
// Batched Q/K/V projection, single launch (1280 blocks), all 1-pass hi*hi:
//   [0,256)   seg 0: Q = inq_h  @ wq^T, scaled -> attn Q layout [bh][x][64]
//   [256,768) seg 1: K = inkv_h @ wk^T -> attn K layout
//   [768,1280)seg 2: V = inkv_h @ wv^T -> attn V^T layout [bh][dd][2048]
// Per-segment bijective XCD-grouping for A-panel L2 residency.
// ---------------------------------------------------------------------------
__global__ __launch_bounds__(256, 2) void qkv_proj(
    const ushort* __restrict__ Aq, const ushort* __restrict__ Akv,
    const ushort* __restrict__ Wqh, const ushort* __restrict__ Wkh,
    const ushort* __restrict__ Wvh, ushort* __restrict__ aq,
    ushort* __restrict__ ak, ushort* __restrict__ avt) {
    constexpr int K = 1024;
    constexpr float QSCALE = 0.18033688011112042f;  // 0.125 * log2(e)
    __shared__ ushort sA[BM * BK];
    __shared__ ushort sB[BN * BK];

    const int bid = blockIdx.x;
    int seg, local, nrow;
    if (bid < 256)      { seg = 0; local = bid;       nrow = 32; }
    else if (bid < 768) { seg = 1; local = bid - 256; nrow = 64; }
    else                { seg = 2; local = bid - 768; nrow = 64; }
    // XCD-grouped bijection within segment (segment size % 8 == 0).
    local = (local & 7) * nrow + (local >> 3);
    const int n0 = (local & 7) * BN;
    const int m0 = (local >> 3) * BM;

    const ushort* A  = (seg == 0) ? Aq : Akv;
    const ushort* Wh = (seg == 0) ? Wqh : (seg == 1 ? Wkh : Wvh);

    const int tid = threadIdx.x;
    const int lane = tid & 63;
    const int w = tid >> 6;
    const int wm = (w >> 1) * 64;
    const int wn = (w & 1) * 64;

    int srow[2], skq[2];
#pragma unroll
    for (int c = 0; c < 2; ++c) {
        const int row = (w * 2 + c) * 16 + (lane >> 2);
        srow[c] = row;
        skq[c] = (((lane & 3) ^ ((row >> 1) & 3)) << 3);
    }

    f32x4 acc[4][4];
#pragma unroll
    for (int i = 0; i < 4; ++i)
#pragma unroll
        for (int j = 0; j < 4; ++j) acc[i][j] = (f32x4)0.0f;

    const int lr = lane & 15;
    const int kq = lane >> 4;

    for (int k0 = 0; k0 < K; k0 += BK) {
#pragma unroll
        for (int c = 0; c < 2; ++c) {
            const size_t ga = (size_t)(m0 + srow[c]) * K + k0 + skq[c];
            const size_t gb = (size_t)(n0 + srow[c]) * K + k0 + skq[c];
            const int loff = (w * 2 + c) * 512;
            GLD_LDS16(A + ga, &sA[loff]);
            GLD_LDS16(Wh + gb, &sB[loff]);
        }
        __syncthreads();

        bf16x8 afh[4], bfh[4];
#pragma unroll
        for (int f = 0; f < 4; ++f) {
            const int arow = wm + f * 16 + lr;
            afh[f] = *reinterpret_cast<const bf16x8*>(
                &sA[arow * 32 + ((kq ^ ((arow >> 1) & 3)) << 3)]);
            const int brow = wn + f * 16 + lr;
            bfh[f] = *reinterpret_cast<const bf16x8*>(
                &sB[brow * 32 + ((kq ^ ((brow >> 1) & 3)) << 3)]);
        }
#pragma unroll
        for (int i = 0; i < 4; ++i)
#pragma unroll
            for (int j = 0; j < 4; ++j)
                acc[i][j] = __builtin_amdgcn_mfma_f32_16x16x32_bf16(
                    afh[i], bfh[j], acc[i][j], 0, 0, 0);
        __syncthreads();
    }

    const int cr = (lane >> 4) << 2;
    const int cc = lane & 15;

    if (seg < 2) {  // Q / K layout: [bh][x][64] hi-only, dd ^ ((x&7)<<3)
        const int log2X = (seg == 0) ? 10 : 11;
        const float scale = (seg == 0) ? QSCALE : 1.0f;
        ushort* out = (seg == 0) ? aq : ak;
        const int xm = (1 << log2X) - 1;
#pragma unroll
        for (int i = 0; i < 4; ++i)
#pragma unroll
            for (int j = 0; j < 4; ++j) {
                const int col = n0 + wn + j * 16 + cc;
                const int h = col >> 6, dd = col & 63;
#pragma unroll
                for (int r = 0; r < 4; ++r) {
                    const int mr = m0 + wm + i * 16 + cr + r;
                    const int bb = mr >> log2X;
                    const int x = mr & xm;
                    out[(((size_t)(bb * N_HEADS + h) << log2X) + x) * 64 +
                        (dd ^ ((x & 7) << 3))] = f2bf(acc[i][j][r] * scale);
                }
            }
    } else {  // V^T layout: [bh][dd][2048], s swizzled within 64-blocks
#pragma unroll
        for (int i = 0; i < 4; ++i)
#pragma unroll
            for (int j = 0; j < 4; ++j) {
                const int col = n0 + wn + j * 16 + cc;
                const int h = col >> 6, dd = col & 63;
                const int sb = m0 + wm + i * 16 + cr;
                const int bb = sb >> 11;
                const int sx = sb & 2047;
                ushort4 hv;
#pragma unroll
                for (int r = 0; r < 4; ++r)
                    ((ushort*)&hv)[r] = f2bf(acc[i][j][r]);
                const size_t pos =
                    ((size_t)(bb * N_HEADS + h) * 64 + dd) * 2048 +
                    (sx & ~63) + ((sx & 63) ^ ((dd & 7) << 3));
                *reinterpret_cast<ushort4*>(&avt[pos]) = hv;
            }
    }
}

// ---------------------------------------------------------------------------
// O-projection GEMM: out = AO[M,K] * wo[N,K]^T, 2-pass (A_hi*(W_hi+W_lo)).
// ---------------------------------------------------------------------------
__global__ __launch_bounds__(256, 2) void gemm_oproj(
    const ushort* __restrict__ Ahi, const ushort* __restrict__ Whi,
    const ushort* __restrict__ Wlo, float* __restrict__ Cf, int M, int N,
    int K) {
    __shared__ ushort sA[BM * BK];
    __shared__ ushort sB[2][BN * BK];

    const int tid = threadIdx.x;
    const int lane = tid & 63;
    const int w = tid >> 6;
    const int m0 = blockIdx.y * BM;
    const int n0 = blockIdx.x * BN;
    const int wm = (w >> 1) * 64;
    const int wn = (w & 1) * 64;

    int srow[2], skq[2];
#pragma unroll
    for (int c = 0; c < 2; ++c) {
        const int row = (w * 2 + c) * 16 + (lane >> 2);
        srow[c] = row;
        skq[c] = (((lane & 3) ^ ((row >> 1) & 3)) << 3);
    }

    f32x4 acc[4][4];
#pragma unroll
    for (int i = 0; i < 4; ++i)
#pragma unroll
        for (int j = 0; j < 4; ++j) acc[i][j] = (f32x4)0.0f;

    const int lr = lane & 15;
    const int kq = lane >> 4;

    for (int k0 = 0; k0 < K; k0 += BK) {
#pragma unroll
        for (int c = 0; c < 2; ++c) {
            const size_t ga = (size_t)(m0 + srow[c]) * K + k0 + skq[c];
            const size_t gb = (size_t)(n0 + srow[c]) * K + k0 + skq[c];
            const int loff = (w * 2 + c) * 512;
            GLD_LDS16(Ahi + ga, &sA[loff]);
            GLD_LDS16(Whi + gb, &sB[0][loff]);
            GLD_LDS16(Wlo + gb, &sB[1][loff]);
        }
        __syncthreads();

        bf16x8 afh[4], bfh[4], bfl[4];
#pragma unroll
        for (int f = 0; f < 4; ++f) {
            const int arow = wm + f * 16 + lr;
            afh[f] = *reinterpret_cast<const bf16x8*>(
                &sA[arow * 32 + ((kq ^ ((arow >> 1) & 3)) << 3)]);
            const int brow = wn + f * 16 + lr;
            const int boff = brow * 32 + ((kq ^ ((brow >> 1) & 3)) << 3);
            bfh[f] = *reinterpret_cast<const bf16x8*>(&sB[0][boff]);
            bfl[f] = *reinterpret_cast<const bf16x8*>(&sB[1][boff]);
        }
#pragma unroll
        for (int i = 0; i < 4; ++i)
#pragma unroll
            for (int j = 0; j < 4; ++j) {
                acc[i][j] = __builtin_amdgcn_mfma_f32_16x16x32_bf16(
                    afh[i], bfh[j], acc[i][j], 0, 0, 0);
                acc[i][j] = __builtin_amdgcn_mfma_f32_16x16x32_bf16(
                    afh[i], bfl[j], acc[i][j], 0, 0, 0);
            }
        __syncthreads();
    }

    const int cr = (lane >> 4) << 2;
    const int cc = lane & 15;
#pragma unroll
    for (int i = 0; i < 4; ++i)
#pragma unroll
        for (int j = 0; j < 4; ++j) {
            float* cp = &Cf[(size_t)(m0 + wm + i * 16 + cr) * N + n0 + wn +
                            j * 16 + cc];
#pragma unroll
            for (int r = 0; r < 4; ++r) cp[(size_t)r * N] = acc[i][j][r];
        }
}

// ---------------------------------------------------------------------------
// MFMA flash attention, max-free softmax. Round 11: raw v_exp_f32 (strips
// OCML denorm-fixup VALU) and zero4 C-in for the first QK MFMA of each
// chain (kills per-tile accumulator zero-init movs).
// ---------------------------------------------------------------------------
__global__ __launch_bounds__(256, 4) void attn_mfma(
    const ushort* __restrict__ Qhi, const ushort* __restrict__ Khi,
    const ushort* __restrict__ Vhi, ushort* __restrict__ Ohi) {
    constexpr int T = 1024, S = 2048, NT = S / 64;
    __shared__ ushort sK[2][4096];  // [buf][s*64+dd]  (hi)
    __shared__ ushort sV[2][4096];  // [buf][dd*64+s]  (hi)
    __shared__ ushort sPb[4096];    // 4 x 2KB wave-private P buffers

    const int tid = threadIdx.x;
    const int lane = tid & 63;
    const int w = tid >> 6;
    const int id = blockIdx.x;
    const int wid = (id & 7) * 128 + (id >> 3);
    const int t0 = (wid & 15) * 64;
    const int bh = wid >> 4;
    const int lr = lane & 15;
    const int g = lane >> 4;
    const int swz = (lr & 7) << 3;

    const size_t qbase = ((size_t)bh * T + t0) * 64;
    const size_t kbase = (size_t)bh * S * 64;
    const size_t vbase = (size_t)bh * 64;

    // per-lane staging pointers (advance by constants per tile)
    int loff[2];
    const ushort* kp[2];
    const ushort* vp[2];
#pragma unroll
    for (int i = 0; i < 2; ++i) {
        loff[i] = i * 2048 + w * 512 + lane * 8;
        kp[i] = Khi + kbase + loff[i];
        vp[i] = Vhi + (vbase + (loff[i] >> 6)) * S + (loff[i] & 63);
    }

    // precomputed LDS offsets (K-read == V-read form), P write/read offsets
    int rdoff[4][2], pwoff[4], proff[2];
#pragma unroll
    for (int j = 0; j < 4; ++j) {
#pragma unroll
        for (int kk = 0; kk < 2; ++kk)
            rdoff[j][kk] = (j * 16 + lr) * 64 + ((kk * 32 + g * 8) ^ swz);
        pwoff[j] = lr * 64 + ((j * 16 + g * 4) ^ swz);
    }
#pragma unroll
    for (int kk = 0; kk < 2; ++kk)
        proff[kk] = lr * 64 + ((kk * 32 + g * 8) ^ swz);

    // prologue: Q-hi -> sK[1]; first K/V tile -> buf 0
#pragma unroll
    for (int i = 0; i < 2; ++i) GLD_LDS16(Qhi + qbase + loff[i], &sK[1][loff[i]]);
#pragma unroll
    for (int i = 0; i < 2; ++i) {
        GLD_LDS16(kp[i], &sK[0][loff[i]]);
        GLD_LDS16(vp[i], &sV[0][loff[i]]);
        kp[i] += 4096;
        vp[i] += 64;
    }
    __syncthreads();

    bf16x8 qf[2];
#pragma unroll
    for (int kk = 0; kk < 2; ++kk)
        qf[kk] = *reinterpret_cast<const bf16x8*>(
            &sK[1][(w * 16 + lr) * 64 + ((kk * 32 + g * 8) ^ swz)]);
    __syncthreads();  // all Q reads done before buf1 gets overwritten

    ushort* sP = &sPb[w * 1024];  // wave-private

    f32x4 oacc[4];
#pragma unroll
    for (int jd = 0; jd < 4; ++jd) oacc[jd] = (f32x4)0.0f;
    const f32x4 zero4 = (f32x4)0.0f;  // persistent C-in for QK chain starts
    float lpart = 0.0f;  // per-lane partial denominator (own 16 s-slots)

    for (int t = 0; t < NT; ++t) {
        const int bi = t & 1;
        if (t + 1 < NT) {
#pragma unroll
            for (int i = 0; i < 2; ++i) {
                GLD_LDS16(kp[i], &sK[bi ^ 1][loff[i]]);
                GLD_LDS16(vp[i], &sV[bi ^ 1][loff[i]]);
                kp[i] += 4096;
                vp[i] += 64;
            }
        }

        // ---- QK^T swapped, 1-pass: k_hi * q_hi (C-in = zero4) ----
        f32x4 sacc[4];
        __builtin_amdgcn_s_setprio(1);
#pragma unroll
        for (int j = 0; j < 4; ++j) {
            const bf16x8 kh0 = *reinterpret_cast<const bf16x8*>(
                &sK[bi][rdoff[j][0]]);
            const bf16x8 kh1 = *reinterpret_cast<const bf16x8*>(
                &sK[bi][rdoff[j][1]]);
            sacc[j] = __builtin_amdgcn_mfma_f32_16x16x32_bf16(
                kh0, qf[0], zero4, 0, 0, 0);
            sacc[j] = __builtin_amdgcn_mfma_f32_16x16x32_bf16(
                kh1, qf[1], sacc[j], 0, 0, 0);
        }
        __builtin_amdgcn_s_setprio(0);

        // ---- max-free softmax: p = exp2(logit); partial l; pack bf16 ----
        uint32_t wpk[4][2];
#pragma unroll
        for (int j = 0; j < 4; ++j) {
            const float p0 = exp2_raw(sacc[j][0]);
            const float p1 = exp2_raw(sacc[j][1]);
            const float p2 = exp2_raw(sacc[j][2]);
            const float p3 = exp2_raw(sacc[j][3]);
            lpart += (p0 + p1) + (p2 + p3);
            wpk[j][0] = cvt_pk_bf16(p0, p1);
            wpk[j][1] = cvt_pk_bf16(p2, p3);
        }

#pragma unroll
        for (int j = 0; j < 4; ++j)
            *reinterpret_cast<uint2*>(&sP[pwoff[j]]) =
                make_uint2(wpk[j][0], wpk[j][1]);
        asm volatile("s_waitcnt lgkmcnt(0)" ::: "memory");
        __builtin_amdgcn_sched_barrier(0);

        // ---- PV, 1-pass ----
        bf16x8 pf[2];
#pragma unroll
        for (int kk = 0; kk < 2; ++kk)
            pf[kk] = *reinterpret_cast<const bf16x8*>(&sP[proff[kk]]);
        __builtin_amdgcn_s_setprio(1);
#pragma unroll
        for (int jd = 0; jd < 4; ++jd) {
#pragma unroll
            for (int kk = 0; kk < 2; ++kk) {
                const bf16x8 vh = *reinterpret_cast<const bf16x8*>(
                    &sV[bi][rdoff[jd][kk]]);
                oacc[jd] = __builtin_amdgcn_mfma_f32_16x16x32_bf16(
                    pf[kk], vh, oacc[jd], 0, 0, 0);
            }
        }
        __builtin_amdgcn_s_setprio(0);
        __syncthreads();  // drains next tile's loads; protects dbuf reuse
    }

    // ---- epilogue: reduce l across g-groups, write O hi-only ----
    float l = lpart;
    l += __shfl_xor(l, 16);
    l += __shfl_xor(l, 32);

    const int b = bh >> 4, h = bh & 15;
    float linv[4];
#pragma unroll
    for (int r = 0; r < 4; ++r) linv[r] = 1.0f / __shfl(l, g * 4 + r);
#pragma unroll
    for (int r = 0; r < 4; ++r) {
        const int q = t0 + w * 16 + g * 4 + r;
        const size_t rowb = ((size_t)(b * T + q)) * 1024 + h * 64;
#pragma unroll
        for (int jd = 0; jd < 4; ++jd)
            Ohi[rowb + jd * 16 + lr] = f2bf(oacc[jd][r] * linv[r]);
    }
}

// ---------------------------------------------------------------------------
extern "C" void kernel_launch(void* const* d_in, const int* in_sizes, int n_in,
                              void* d_out, int out_size, void* d_ws, size_t ws_size,
                              hipStream_t stream) {
    const int B = 4, T = 1024, S = 2048, D = 1024;

    const float* query = (const float*)d_in[0];
    const float* keyv  = (const float*)d_in[1];
    const float* wq    = (const float*)d_in[2];
    const float* wk    = (const float*)d_in[3];
    const float* wv    = (const float*)d_in[4];
    const float* wo    = (const float*)d_in[5];
    float* out = (float*)d_out;

    const size_t nQ = (size_t)B * T * D;  // 4M
    const size_t nK = (size_t)B * S * D;  // 8M
    const size_t nW = (size_t)D * D;      // 1M

    uint8_t* p = (uint8_t*)d_ws;
    ushort* inq_h = (ushort*)p;  p += nQ * 2;   // 8 MB
    ushort* inkv_h = (ushort*)p; p += nK * 2;   // 16 MB
    ushort* wqh = (ushort*)p;    p += nW * 2;
    ushort* wkh = (ushort*)p;    p += nW * 2;
    ushort* wvh = (ushort*)p;    p += nW * 2;
    ushort* woh = (ushort*)p;    p += nW * 2;
    ushort* wol = (ushort*)p;    p += nW * 2;   // 10 MB
    ushort* aq_h = (ushort*)p;   p += nQ * 2;   // 8 MB (hi only)
    ushort* ak_h = (ushort*)p;   p += nK * 2;   // 16 MB (hi only)
    ushort* avt_h = (ushort*)p;  p += nK * 2;   // 16 MB (hi only)
    ushort* ao_h = (ushort*)p;   p += nQ * 2;   // 8 MB (hi only)
    // total 82 MB

    const dim3 blk(256);

    // 1) all input/weight splits, one launch
    split_all<<<dim3(512, 6), blk, 0, stream>>>(
        query, keyv, wq, wk, wv, wo, inq_h, inkv_h, wqh, wkh, wvh, woh, wol);

    // 2) Q/K/V projections, one batched 1-pass launch (fused attn layouts)
    qkv_proj<<<dim3(1280), blk, 0, stream>>>(inq_h, inkv_h, wqh, wkh, wvh,
                                             aq_h, ak_h, avt_h);

    // 3) attention (1-D XCD-grouped grid; writes hi-only O)
    attn_mfma<<<dim3((T / 64) * B * N_HEADS), blk, 0, stream>>>(
        aq_h, ak_h, avt_h, ao_h);

    // 4) output projection, 2-pass
    gemm_oproj<<<dim3(D / BN, (B * T) / BM), blk, 0, stream>>>(
        ao_h, woh, wol, out, B * T, D, D);
}